// Round 1
// baseline (280.923 us; speedup 1.0000x reference)
//
#include <hip/hip_runtime.h>

// Problem constants: B=16, H=W=32 -> L=1024, C=512, G=32, nh=8, d=64
#define Bn 16
#define Ln 1024
#define Cn 512
#define Mn (Bn*Ln)     // 16384
#define N3n 1536

typedef unsigned short u16;
typedef __attribute__((ext_vector_type(8))) short short8;
typedef __attribute__((ext_vector_type(4))) float f32x4;

typedef const __attribute__((address_space(1))) void* gas_p;
typedef __attribute__((address_space(3))) void* las_p;

__device__ inline void gl_lds16(const void* g, void* l) {
  __builtin_amdgcn_global_load_lds((gas_p)g, (las_p)l, 16, 0, 0);
}

__device__ inline u16 f2bf(float f) {
  union { float f; unsigned u; } v; v.f = f;
  unsigned r = v.u + 0x7FFFu + ((v.u >> 16) & 1u);
  return (u16)(r >> 16);
}

__device__ inline f32x4 mfma16(short8 a, short8 b, f32x4 c) {
  return __builtin_amdgcn_mfma_f32_16x16x32_bf16(a, b, c, 0, 0, 0);
}

// ---------------- K1: GroupNorm stats (mean, rstd per (b,g)) ----------------
__global__ __launch_bounds__(256) void k_gnstats(const float* __restrict__ x,
                                                 float* __restrict__ stats) {
  int bid = blockIdx.x;            // b*32+g
  int b = bid >> 5, g = bid & 31;
  const float* base = x + (size_t)b * (Ln * Cn) + g * 16;
  int tid = threadIdx.x;
  float s1 = 0.f, s2 = 0.f;
  // 1024 rows x 16 ch = 4096 float4
  for (int i = 0; i < 16; ++i) {
    int s = i * 256 + tid;
    int l = s >> 2, cq = s & 3;
    float4 v = *(const float4*)(base + (size_t)l * Cn + cq * 4);
    s1 += v.x + v.y + v.z + v.w;
    s2 += v.x * v.x + v.y * v.y + v.z * v.z + v.w * v.w;
  }
  for (int off = 32; off > 0; off >>= 1) {
    s1 += __shfl_down(s1, off);
    s2 += __shfl_down(s2, off);
  }
  __shared__ float rb[8];
  int w = tid >> 6, lane = tid & 63;
  if (lane == 0) { rb[w] = s1; rb[4 + w] = s2; }
  __syncthreads();
  if (tid == 0) {
    float a = rb[0] + rb[1] + rb[2] + rb[3];
    float q = rb[4] + rb[5] + rb[6] + rb[7];
    float mean = a * (1.f / 16384.f);
    float var = q * (1.f / 16384.f) - mean * mean;
    stats[bid * 2] = mean;
    stats[bid * 2 + 1] = rsqrtf(var + 1e-5f);
  }
}

// ---------------- K2: GN apply + cast to bf16 ----------------
__global__ __launch_bounds__(256) void k_gnapply(const float* __restrict__ x,
                                                 const float* __restrict__ stats,
                                                 const float* __restrict__ gamma,
                                                 const float* __restrict__ beta,
                                                 u16* __restrict__ gn) {
  int idx = blockIdx.x * 256 + threadIdx.x;
  size_t e = (size_t)idx << 2;
  int m = (int)(e >> 9), c = (int)(e & 511);
  int b = m >> 10, g = c >> 4;
  float mean = stats[(b * 32 + g) * 2];
  float rstd = stats[(b * 32 + g) * 2 + 1];
  float4 xv = *(const float4*)(x + e);
  float4 gv = *(const float4*)(gamma + c);
  float4 bv = *(const float4*)(beta + c);
  ushort4 o;
  o.x = f2bf((xv.x - mean) * rstd * gv.x + bv.x);
  o.y = f2bf((xv.y - mean) * rstd * gv.y + bv.y);
  o.z = f2bf((xv.z - mean) * rstd * gv.z + bv.z);
  o.w = f2bf((xv.w - mean) * rstd * gv.w + bv.w);
  *(ushort4*)(gn + e) = o;
}

// ---------------- K3: transpose+cast weights to [N][K] bf16 ----------------
__global__ __launch_bounds__(256) void k_wtrans(const float* __restrict__ wqkv,
                                                const float* __restrict__ wout,
                                                u16* __restrict__ wqkvT,
                                                u16* __restrict__ woutT) {
  int id = blockIdx.x * 256 + threadIdx.x;
  if (id < Cn * N3n) {
    int k = id & 511, n = id >> 9;
    wqkvT[id] = f2bf(wqkv[(size_t)k * N3n + n]);
  } else {
    int id2 = id - Cn * N3n;
    int k = id2 & 511, n = id2 >> 9;
    woutT[id2] = f2bf(wout[(size_t)k * Cn + n]);
  }
}

// ---------------- K4: QKV GEMM [16384,512]@[512,1536] -> q,k,vT bf16 ----------------
__global__ __launch_bounds__(256) void k_qkv(const u16* __restrict__ gn,
                                             const u16* __restrict__ wT,
                                             const float* __restrict__ bias,
                                             u16* __restrict__ qb,
                                             u16* __restrict__ kb,
                                             u16* __restrict__ vT) {
  __shared__ __attribute__((aligned(16))) u16 As[128 * 64];
  __shared__ __attribute__((aligned(16))) u16 Bs[128 * 64];
  int bid = blockIdx.x;
  int tn = bid % 12, tm = bid / 12;
  int m0 = tm * 128, n0 = tn * 128;
  int tid = threadIdx.x;
  int w = tid >> 6, lane = tid & 63, lr = lane & 15, lg = lane >> 4;
  int wr = w >> 1, wc = w & 1;
  const f32x4 fzero = {0.f, 0.f, 0.f, 0.f};
  f32x4 acc[4][4];
#pragma unroll
  for (int mi = 0; mi < 4; ++mi)
#pragma unroll
    for (int ni = 0; ni < 4; ++ni) acc[mi][ni] = fzero;
  char* Asb = (char*)As;
  char* Bsb = (char*)Bs;
  for (int kt = 0; kt < 8; ++kt) {
    int k0 = kt * 64;
    __syncthreads();
#pragma unroll
    for (int i = 0; i < 4; ++i) {
      int s = i * 256 + tid;
      int r = s >> 3, c = s & 7;
      gl_lds16(gn + ((size_t)(m0 + r) * 512 + k0 + ((c ^ (r & 7)) << 3)),
               Asb + ((s & ~63) << 4));
    }
#pragma unroll
    for (int i = 0; i < 4; ++i) {
      int s = i * 256 + tid;
      int r = s >> 3, c = s & 7;
      gl_lds16(wT + ((size_t)(n0 + r) * 512 + k0 + ((c ^ (r & 7)) << 3)),
               Bsb + ((s & ~63) << 4));
    }
    __syncthreads();
#pragma unroll
    for (int ks = 0; ks < 2; ++ks) {
      short8 af[4], bf[4];
#pragma unroll
      for (int mi = 0; mi < 4; ++mi) {
        int row = wr * 64 + mi * 16 + lr;
        int ck = ks * 4 + lg;
        af[mi] = *(const short8*)(Asb + row * 128 + ((ck ^ (lr & 7)) << 4));
      }
#pragma unroll
      for (int ni = 0; ni < 4; ++ni) {
        int row = wc * 64 + ni * 16 + lr;
        int ck = ks * 4 + lg;
        bf[ni] = *(const short8*)(Bsb + row * 128 + ((ck ^ (lr & 7)) << 4));
      }
#pragma unroll
      for (int mi = 0; mi < 4; ++mi)
#pragma unroll
        for (int ni = 0; ni < 4; ++ni)
          acc[mi][ni] = mfma16(af[mi], bf[ni], acc[mi][ni]);
    }
  }
  // epilogue: scatter into q [BH][L][64], k [BH][L][64], vT [BH][64][L]
#pragma unroll
  for (int mi = 0; mi < 4; ++mi) {
#pragma unroll
    for (int ni = 0; ni < 4; ++ni) {
      int n = n0 + wc * 64 + ni * 16 + lr;
      float bn = bias[n];
      int which = n >> 9, nn = n & 511;
      int h = nn >> 6, dd = nn & 63;
#pragma unroll
      for (int rr = 0; rr < 4; ++rr) {
        int m = m0 + wr * 64 + mi * 16 + lg * 4 + rr;
        float v = acc[mi][ni][rr] + bn;
        int bb = m >> 10, li = m & 1023;
        if (which == 0)
          qb[((size_t)(bb * 8 + h) * 1024 + li) * 64 + dd] = f2bf(v);
        else if (which == 1)
          kb[((size_t)(bb * 8 + h) * 1024 + li) * 64 + dd] = f2bf(v);
        else
          vT[((size_t)(bb * 8 + h) * 64 + dd) * 1024 + li] = f2bf(v);
      }
    }
  }
}

// ---------------- K5: flash attention per (b,h,128-row q tile) ----------------
__global__ __launch_bounds__(256) void k_attn(const u16* __restrict__ qb,
                                              const u16* __restrict__ kb,
                                              const u16* __restrict__ vT,
                                              u16* __restrict__ ob) {
  __shared__ __attribute__((aligned(16))) u16 Ks[64 * 64];
  __shared__ __attribute__((aligned(16))) u16 Vs[64 * 64];
  __shared__ __attribute__((aligned(16))) u16 Ps[4 * 32 * 72];
  int bid = blockIdx.x;
  int qt = bid & 7, bh = bid >> 3;
  const u16* qh = qb + (size_t)bh * 65536;
  const u16* kh = kb + (size_t)bh * 65536;
  const u16* vh = vT + (size_t)bh * 65536;
  int tid = threadIdx.x, w = tid >> 6, lane = tid & 63, lr = lane & 15, lg = lane >> 4;
  int q0 = qt * 128;
  const f32x4 fzero = {0.f, 0.f, 0.f, 0.f};

  short8 aq[2][2];
#pragma unroll
  for (int mi = 0; mi < 2; ++mi)
#pragma unroll
    for (int ks = 0; ks < 2; ++ks)
      aq[mi][ks] = *(const short8*)(qh + (size_t)(q0 + w * 32 + mi * 16 + lr) * 64 +
                                    ks * 32 + lg * 8);
  f32x4 accO[2][4];
  float mst[2][4], lst[2][4];
#pragma unroll
  for (int mi = 0; mi < 2; ++mi) {
#pragma unroll
    for (int nd = 0; nd < 4; ++nd) accO[mi][nd] = fzero;
#pragma unroll
    for (int rr = 0; rr < 4; ++rr) { mst[mi][rr] = -1e30f; lst[mi][rr] = 0.f; }
  }
  char* Ksb = (char*)Ks;
  char* Vsb = (char*)Vs;
  char* Pwb = (char*)(Ps + w * 2304);

  for (int jt = 0; jt < 16; ++jt) {
    int j0 = jt * 64;
    __syncthreads();
#pragma unroll
    for (int i = 0; i < 2; ++i) {
      int s = i * 256 + tid;
      int r = s >> 3, c = s & 7;
      gl_lds16(kh + ((size_t)(j0 + r) * 64 + ((c ^ (r & 7)) << 3)),
               Ksb + ((s & ~63) << 4));
    }
#pragma unroll
    for (int i = 0; i < 2; ++i) {
      int s = i * 256 + tid;
      int r = s >> 3, c = s & 7;
      gl_lds16(vh + ((size_t)r * 1024 + j0 + ((c ^ (r & 7)) << 3)),
               Vsb + ((s & ~63) << 4));
    }
    __syncthreads();

    // S = Q K^T  (32 rows x 64 cols per wave)
    f32x4 sc[2][4];
#pragma unroll
    for (int mi = 0; mi < 2; ++mi)
#pragma unroll
      for (int nj = 0; nj < 4; ++nj) sc[mi][nj] = fzero;
    short8 bk[4][2];
#pragma unroll
    for (int nj = 0; nj < 4; ++nj)
#pragma unroll
      for (int ks = 0; ks < 2; ++ks) {
        int row = nj * 16 + lr;
        bk[nj][ks] = *(const short8*)(Ksb + row * 128 + (((ks * 4 + lg) ^ (lr & 7)) << 4));
      }
#pragma unroll
    for (int ks = 0; ks < 2; ++ks)
#pragma unroll
      for (int mi = 0; mi < 2; ++mi)
#pragma unroll
        for (int nj = 0; nj < 4; ++nj)
          sc[mi][nj] = mfma16(aq[mi][ks], bk[nj][ks], sc[mi][nj]);

    // scale 1/8 (q,k each carry 1/sqrt(sqrt(64)) in the reference)
#pragma unroll
    for (int mi = 0; mi < 2; ++mi)
#pragma unroll
      for (int nj = 0; nj < 4; ++nj)
#pragma unroll
        for (int rr = 0; rr < 4; ++rr) sc[mi][nj][rr] *= 0.125f;

    // online softmax
#pragma unroll
    for (int mi = 0; mi < 2; ++mi) {
      float tm[4], al[4], rs[4];
#pragma unroll
      for (int rr = 0; rr < 4; ++rr)
        tm[rr] = fmaxf(fmaxf(sc[mi][0][rr], sc[mi][1][rr]),
                       fmaxf(sc[mi][2][rr], sc[mi][3][rr]));
#pragma unroll
      for (int rr = 0; rr < 4; ++rr) {
#pragma unroll
        for (int off = 1; off < 16; off <<= 1)
          tm[rr] = fmaxf(tm[rr], __shfl_xor(tm[rr], off));
      }
#pragma unroll
      for (int rr = 0; rr < 4; ++rr) {
        float mn = fmaxf(mst[mi][rr], tm[rr]);
        al[rr] = __expf(mst[mi][rr] - mn);
        mst[mi][rr] = mn;
        rs[rr] = 0.f;
      }
#pragma unroll
      for (int nj = 0; nj < 4; ++nj)
#pragma unroll
        for (int rr = 0; rr < 4; ++rr) {
          float p = __expf(sc[mi][nj][rr] - mst[mi][rr]);
          sc[mi][nj][rr] = p;
          rs[rr] += p;
        }
#pragma unroll
      for (int rr = 0; rr < 4; ++rr) {
#pragma unroll
        for (int off = 1; off < 16; off <<= 1) rs[rr] += __shfl_xor(rs[rr], off);
      }
#pragma unroll
      for (int rr = 0; rr < 4; ++rr) lst[mi][rr] = lst[mi][rr] * al[rr] + rs[rr];
#pragma unroll
      for (int nd = 0; nd < 4; ++nd)
#pragma unroll
        for (int rr = 0; rr < 4; ++rr) accO[mi][nd][rr] *= al[rr];
      // P -> LDS (per-wave region, padded rows: 72 elems = 144 B)
      int prow = mi * 16 + lg * 4;
#pragma unroll
      for (int nj = 0; nj < 4; ++nj)
#pragma unroll
        for (int rr = 0; rr < 4; ++rr)
          *(u16*)(Pwb + (size_t)(prow + rr) * 144 + (nj * 16 + lr) * 2) =
              f2bf(sc[mi][nj][rr]);
    }

    // O += P @ V
    short8 bv[4][2];
#pragma unroll
    for (int nd = 0; nd < 4; ++nd)
#pragma unroll
      for (int ks = 0; ks < 2; ++ks) {
        int row = nd * 16 + lr;
        bv[nd][ks] = *(const short8*)(Vsb + row * 128 + (((ks * 4 + lg) ^ (lr & 7)) << 4));
      }
    short8 ap[2][2];
#pragma unroll
    for (int mi = 0; mi < 2; ++mi)
#pragma unroll
      for (int ks = 0; ks < 2; ++ks)
        ap[mi][ks] = *(const short8*)(Pwb + (size_t)(mi * 16 + lr) * 144 + ks * 64 + lg * 16);
#pragma unroll
    for (int ks = 0; ks < 2; ++ks)
#pragma unroll
      for (int mi = 0; mi < 2; ++mi)
#pragma unroll
        for (int nd = 0; nd < 4; ++nd)
          accO[mi][nd] = mfma16(ap[mi][ks], bv[nd][ks], accO[mi][nd]);
  }

  // epilogue: O /= l, write [B][L][C] bf16 with c = h*64+dd
  int b = bh >> 3, h = bh & 7;
#pragma unroll
  for (int mi = 0; mi < 2; ++mi) {
    float inv[4];
#pragma unroll
    for (int rr = 0; rr < 4; ++rr) inv[rr] = 1.f / lst[mi][rr];
#pragma unroll
    for (int nd = 0; nd < 4; ++nd)
#pragma unroll
      for (int rr = 0; rr < 4; ++rr) {
        int row = q0 + w * 32 + mi * 16 + lg * 4 + rr;
        int col = h * 64 + nd * 16 + lr;
        ob[(size_t)(b * 1024 + row) * 512 + col] = f2bf(accO[mi][nd][rr] * inv[rr]);
      }
  }
}

// ---------------- K6: out-proj GEMM + bias + residual (fp32 out) ----------------
__global__ __launch_bounds__(256) void k_out(const u16* __restrict__ ob,
                                             const u16* __restrict__ wT,
                                             const float* __restrict__ bias,
                                             const float* __restrict__ x,
                                             float* __restrict__ out) {
  __shared__ __attribute__((aligned(16))) u16 As[128 * 64];
  __shared__ __attribute__((aligned(16))) u16 Bs[128 * 64];
  int bid = blockIdx.x;
  int tn = bid & 3, tm = bid >> 2;
  int m0 = tm * 128, n0 = tn * 128;
  int tid = threadIdx.x;
  int w = tid >> 6, lane = tid & 63, lr = lane & 15, lg = lane >> 4;
  int wr = w >> 1, wc = w & 1;
  const f32x4 fzero = {0.f, 0.f, 0.f, 0.f};
  f32x4 acc[4][4];
#pragma unroll
  for (int mi = 0; mi < 4; ++mi)
#pragma unroll
    for (int ni = 0; ni < 4; ++ni) acc[mi][ni] = fzero;
  char* Asb = (char*)As;
  char* Bsb = (char*)Bs;
  for (int kt = 0; kt < 8; ++kt) {
    int k0 = kt * 64;
    __syncthreads();
#pragma unroll
    for (int i = 0; i < 4; ++i) {
      int s = i * 256 + tid;
      int r = s >> 3, c = s & 7;
      gl_lds16(ob + ((size_t)(m0 + r) * 512 + k0 + ((c ^ (r & 7)) << 3)),
               Asb + ((s & ~63) << 4));
    }
#pragma unroll
    for (int i = 0; i < 4; ++i) {
      int s = i * 256 + tid;
      int r = s >> 3, c = s & 7;
      gl_lds16(wT + ((size_t)(n0 + r) * 512 + k0 + ((c ^ (r & 7)) << 3)),
               Bsb + ((s & ~63) << 4));
    }
    __syncthreads();
#pragma unroll
    for (int ks = 0; ks < 2; ++ks) {
      short8 af[4], bf[4];
#pragma unroll
      for (int mi = 0; mi < 4; ++mi) {
        int row = wr * 64 + mi * 16 + lr;
        int ck = ks * 4 + lg;
        af[mi] = *(const short8*)(Asb + row * 128 + ((ck ^ (lr & 7)) << 4));
      }
#pragma unroll
      for (int ni = 0; ni < 4; ++ni) {
        int row = wc * 64 + ni * 16 + lr;
        int ck = ks * 4 + lg;
        bf[ni] = *(const short8*)(Bsb + row * 128 + ((ck ^ (lr & 7)) << 4));
      }
#pragma unroll
      for (int mi = 0; mi < 4; ++mi)
#pragma unroll
        for (int ni = 0; ni < 4; ++ni)
          acc[mi][ni] = mfma16(af[mi], bf[ni], acc[mi][ni]);
    }
  }
#pragma unroll
  for (int mi = 0; mi < 4; ++mi) {
#pragma unroll
    for (int ni = 0; ni < 4; ++ni) {
      int n = n0 + wc * 64 + ni * 16 + lr;
      float bn = bias[n];
#pragma unroll
      for (int rr = 0; rr < 4; ++rr) {
        int m = m0 + wr * 64 + mi * 16 + lg * 4 + rr;
        size_t off = (size_t)m * 512 + n;
        out[off] = x[off] + acc[mi][ni][rr] + bn;
      }
    }
  }
}

extern "C" void kernel_launch(void* const* d_in, const int* in_sizes, int n_in,
                              void* d_out, int out_size, void* d_ws, size_t ws_size,
                              hipStream_t stream) {
  const float* x = (const float*)d_in[0];
  // d_in[1] = timesteps (unused by the reference computation)
  const float* gamma = (const float*)d_in[2];
  const float* beta = (const float*)d_in[3];
  const float* wqkv = (const float*)d_in[4];
  const float* bqkv = (const float*)d_in[5];
  const float* wout = (const float*)d_in[6];
  const float* bout = (const float*)d_in[7];
  float* out = (float*)d_out;

  char* ws = (char*)d_ws;
  float* stats = (float*)ws;                                   //   4096 B
  u16* gn = (u16*)(ws + 4096);                                 // 16 MB  [M][512]
  u16* wqkvT = (u16*)(ws + 4096 + 16777216);                   // 1.5 MB [1536][512]
  u16* woutT = (u16*)(ws + 4096 + 16777216 + 1572864);         // 0.5 MB [512][512]
  u16* qb = (u16*)(ws + 4096 + 16777216 + 1572864 + 524288);   // 16 MB  [BH][L][64]
  u16* kb = qb + 8388608;                                      // 16 MB  [BH][L][64]
  u16* vT = kb + 8388608;                                      // 16 MB  [BH][64][L]
  u16* ob = vT + 8388608;                                      // 16 MB  [M][512]

  k_gnstats<<<512, 256, 0, stream>>>(x, stats);
  k_gnapply<<<8192, 256, 0, stream>>>(x, stats, gamma, beta, gn);
  k_wtrans<<<4096, 256, 0, stream>>>(wqkv, wout, wqkvT, woutT);
  k_qkv<<<1536, 256, 0, stream>>>(gn, wqkvT, bqkv, qb, kb, vT);
  k_attn<<<1024, 256, 0, stream>>>(qb, kb, vT, ob);
  k_out<<<512, 256, 0, stream>>>(ob, woutT, bout, x, out);
}

// Round 2
// 239.343 us; speedup vs baseline: 1.1737x; 1.1737x over previous
//
#include <hip/hip_runtime.h>

// Problem constants: B=16, H=W=32 -> L=1024, C=512, G=32, nh=8, d=64
#define Bn 16
#define Ln 1024
#define Cn 512
#define Mn (Bn*Ln)     // 16384
#define N3n 1536

typedef unsigned short u16;
typedef __attribute__((ext_vector_type(8))) short short8;
typedef __attribute__((ext_vector_type(4))) float f32x4;

typedef const __attribute__((address_space(1))) void* gas_p;
typedef __attribute__((address_space(3))) void* las_p;

__device__ inline void gl_lds16(const void* g, void* l) {
  __builtin_amdgcn_global_load_lds((gas_p)g, (las_p)l, 16, 0, 0);
}

__device__ inline u16 f2bf(float f) {
  union { float f; unsigned u; } v; v.f = f;
  unsigned r = v.u + 0x7FFFu + ((v.u >> 16) & 1u);
  return (u16)(r >> 16);
}

__device__ inline f32x4 mfma16(short8 a, short8 b, f32x4 c) {
  return __builtin_amdgcn_mfma_f32_16x16x32_bf16(a, b, c, 0, 0, 0);
}

// ---------------- K1: GroupNorm stats (mean, rstd per (b,g)) ----------------
__global__ __launch_bounds__(256) void k_gnstats(const float* __restrict__ x,
                                                 float* __restrict__ stats) {
  int bid = blockIdx.x;            // b*32+g
  int b = bid >> 5, g = bid & 31;
  const float* base = x + (size_t)b * (Ln * Cn) + g * 16;
  int tid = threadIdx.x;
  float s1 = 0.f, s2 = 0.f;
  // 1024 rows x 16 ch = 4096 float4
  for (int i = 0; i < 16; ++i) {
    int s = i * 256 + tid;
    int l = s >> 2, cq = s & 3;
    float4 v = *(const float4*)(base + (size_t)l * Cn + cq * 4);
    s1 += v.x + v.y + v.z + v.w;
    s2 += v.x * v.x + v.y * v.y + v.z * v.z + v.w * v.w;
  }
  for (int off = 32; off > 0; off >>= 1) {
    s1 += __shfl_down(s1, off);
    s2 += __shfl_down(s2, off);
  }
  __shared__ float rb[8];
  int w = tid >> 6, lane = tid & 63;
  if (lane == 0) { rb[w] = s1; rb[4 + w] = s2; }
  __syncthreads();
  if (tid == 0) {
    float a = rb[0] + rb[1] + rb[2] + rb[3];
    float q = rb[4] + rb[5] + rb[6] + rb[7];
    float mean = a * (1.f / 16384.f);
    float var = q * (1.f / 16384.f) - mean * mean;
    stats[bid * 2] = mean;
    stats[bid * 2 + 1] = rsqrtf(var + 1e-5f);
  }
}

// ---------------- K2: GN apply + cast to bf16 ----------------
__global__ __launch_bounds__(256) void k_gnapply(const float* __restrict__ x,
                                                 const float* __restrict__ stats,
                                                 const float* __restrict__ gamma,
                                                 const float* __restrict__ beta,
                                                 u16* __restrict__ gn) {
  int idx = blockIdx.x * 256 + threadIdx.x;
  size_t e = (size_t)idx << 2;
  int m = (int)(e >> 9), c = (int)(e & 511);
  int b = m >> 10, g = c >> 4;
  float mean = stats[(b * 32 + g) * 2];
  float rstd = stats[(b * 32 + g) * 2 + 1];
  float4 xv = *(const float4*)(x + e);
  float4 gv = *(const float4*)(gamma + c);
  float4 bv = *(const float4*)(beta + c);
  ushort4 o;
  o.x = f2bf((xv.x - mean) * rstd * gv.x + bv.x);
  o.y = f2bf((xv.y - mean) * rstd * gv.y + bv.y);
  o.z = f2bf((xv.z - mean) * rstd * gv.z + bv.z);
  o.w = f2bf((xv.w - mean) * rstd * gv.w + bv.w);
  *(ushort4*)(gn + e) = o;
}

// ---------------- K3: transpose+cast weights to [N][K] bf16 ----------------
__global__ __launch_bounds__(256) void k_wtrans(const float* __restrict__ wqkv,
                                                const float* __restrict__ wout,
                                                u16* __restrict__ wqkvT,
                                                u16* __restrict__ woutT) {
  int id = blockIdx.x * 256 + threadIdx.x;
  if (id < Cn * N3n) {
    int k = id & 511, n = id >> 9;
    wqkvT[id] = f2bf(wqkv[(size_t)k * N3n + n]);
  } else {
    int id2 = id - Cn * N3n;
    int k = id2 & 511, n = id2 >> 9;
    woutT[id2] = f2bf(wout[(size_t)k * Cn + n]);
  }
}

// ---------------- K4: QKV GEMM [16384,512]@[512,1536] -> q,k,vT bf16 ----------------
__global__ __launch_bounds__(256) void k_qkv(const u16* __restrict__ gn,
                                             const u16* __restrict__ wT,
                                             const float* __restrict__ bias,
                                             u16* __restrict__ qb,
                                             u16* __restrict__ kb,
                                             u16* __restrict__ vT) {
  __shared__ __attribute__((aligned(16))) u16 As[128 * 64];
  __shared__ __attribute__((aligned(16))) u16 Bs[128 * 64];
  int bid = blockIdx.x;
  int tn = bid % 12, tm = bid / 12;
  int m0 = tm * 128, n0 = tn * 128;
  int tid = threadIdx.x;
  int w = tid >> 6, lane = tid & 63, lr = lane & 15, lg = lane >> 4;
  int wr = w >> 1, wc = w & 1;
  const f32x4 fzero = {0.f, 0.f, 0.f, 0.f};
  f32x4 acc[4][4];
#pragma unroll
  for (int mi = 0; mi < 4; ++mi)
#pragma unroll
    for (int ni = 0; ni < 4; ++ni) acc[mi][ni] = fzero;
  char* Asb = (char*)As;
  char* Bsb = (char*)Bs;
  for (int kt = 0; kt < 8; ++kt) {
    int k0 = kt * 64;
    __syncthreads();
#pragma unroll
    for (int i = 0; i < 4; ++i) {
      int s = i * 256 + tid;
      int r = s >> 3, c = s & 7;
      gl_lds16(gn + ((size_t)(m0 + r) * 512 + k0 + ((c ^ (r & 7)) << 3)),
               Asb + ((s & ~63) << 4));
    }
#pragma unroll
    for (int i = 0; i < 4; ++i) {
      int s = i * 256 + tid;
      int r = s >> 3, c = s & 7;
      gl_lds16(wT + ((size_t)(n0 + r) * 512 + k0 + ((c ^ (r & 7)) << 3)),
               Bsb + ((s & ~63) << 4));
    }
    __syncthreads();
#pragma unroll
    for (int ks = 0; ks < 2; ++ks) {
      short8 af[4], bf[4];
#pragma unroll
      for (int mi = 0; mi < 4; ++mi) {
        int row = wr * 64 + mi * 16 + lr;
        int ck = ks * 4 + lg;
        af[mi] = *(const short8*)(Asb + row * 128 + ((ck ^ (lr & 7)) << 4));
      }
#pragma unroll
      for (int ni = 0; ni < 4; ++ni) {
        int row = wc * 64 + ni * 16 + lr;
        int ck = ks * 4 + lg;
        bf[ni] = *(const short8*)(Bsb + row * 128 + ((ck ^ (lr & 7)) << 4));
      }
#pragma unroll
      for (int mi = 0; mi < 4; ++mi)
#pragma unroll
        for (int ni = 0; ni < 4; ++ni)
          acc[mi][ni] = mfma16(af[mi], bf[ni], acc[mi][ni]);
    }
  }
  // epilogue: scatter into q [BH][L][64], k [BH][L][64], vT [BH][64][L]
#pragma unroll
  for (int mi = 0; mi < 4; ++mi) {
#pragma unroll
    for (int ni = 0; ni < 4; ++ni) {
      int n = n0 + wc * 64 + ni * 16 + lr;
      float bn = bias[n];
      int which = n >> 9, nn = n & 511;
      int h = nn >> 6, dd = nn & 63;
#pragma unroll
      for (int rr = 0; rr < 4; ++rr) {
        int m = m0 + wr * 64 + mi * 16 + lg * 4 + rr;
        float v = acc[mi][ni][rr] + bn;
        int bb = m >> 10, li = m & 1023;
        if (which == 0)
          qb[((size_t)(bb * 8 + h) * 1024 + li) * 64 + dd] = f2bf(v);
        else if (which == 1)
          kb[((size_t)(bb * 8 + h) * 1024 + li) * 64 + dd] = f2bf(v);
        else
          vT[((size_t)(bb * 8 + h) * 64 + dd) * 1024 + li] = f2bf(v);
      }
    }
  }
}

// ---------------- K5: flash attention, no-barrier, K/V direct from L2 ----------------
__global__ __launch_bounds__(256) void k_attn(const u16* __restrict__ qb,
                                              const u16* __restrict__ kb,
                                              const u16* __restrict__ vT,
                                              u16* __restrict__ ob) {
  __shared__ __attribute__((aligned(16))) u16 Ps[4 * 32 * 72];  // per-wave P buffer
  int bid = blockIdx.x;
  // XCD-bijective swizzle: all 8 q-tiles of a head keep bid%8 constant -> same XCD L2
  int xq = bid & 7, kk = bid >> 3;
  int bh = ((kk & 15) << 3) | xq;
  int qt = kk >> 4;
  const u16* qh = qb + (size_t)bh * 65536;
  const u16* kh = kb + (size_t)bh * 65536;
  const u16* vh = vT + (size_t)bh * 65536;
  int tid = threadIdx.x, w = tid >> 6, lane = tid & 63, lr = lane & 15, lg = lane >> 4;
  int q0 = qt * 128;
  const f32x4 fzero = {0.f, 0.f, 0.f, 0.f};

  // Q fragments (A-operand), resident in registers for the whole kernel
  short8 aq[2][2];
#pragma unroll
  for (int mi = 0; mi < 2; ++mi)
#pragma unroll
    for (int ks = 0; ks < 2; ++ks)
      aq[mi][ks] = *(const short8*)(qh + (size_t)(q0 + w * 32 + mi * 16 + lr) * 64 +
                                    ks * 32 + lg * 8);
  f32x4 accO[2][4];
  float mst[2][4], lst[2][4];
#pragma unroll
  for (int mi = 0; mi < 2; ++mi) {
#pragma unroll
    for (int nd = 0; nd < 4; ++nd) accO[mi][nd] = fzero;
#pragma unroll
    for (int rr = 0; rr < 4; ++rr) { mst[mi][rr] = -1e30f; lst[mi][rr] = 0.f; }
  }
  char* Pwb = (char*)(Ps + w * 2304);

#pragma unroll 1
  for (int jt = 0; jt < 16; ++jt) {
    int j0 = jt * 64;

    // K fragments direct from global (L2-resident; 16B contiguous per lane)
    short8 bk[4][2];
#pragma unroll
    for (int nj = 0; nj < 4; ++nj)
#pragma unroll
      for (int ks = 0; ks < 2; ++ks)
        bk[nj][ks] = *(const short8*)(kh + (size_t)(j0 + nj * 16 + lr) * 64 +
                                      ks * 32 + lg * 8);

    // S = Q K^T  (32 rows x 64 cols per wave)
    f32x4 sc[2][4];
#pragma unroll
    for (int mi = 0; mi < 2; ++mi)
#pragma unroll
      for (int nj = 0; nj < 4; ++nj) sc[mi][nj] = fzero;
#pragma unroll
    for (int ks = 0; ks < 2; ++ks)
#pragma unroll
      for (int mi = 0; mi < 2; ++mi)
#pragma unroll
        for (int nj = 0; nj < 4; ++nj)
          sc[mi][nj] = mfma16(aq[mi][ks], bk[nj][ks], sc[mi][nj]);

    // scale 1/8 (q,k each carry 1/sqrt(sqrt(64)) in the reference)
#pragma unroll
    for (int mi = 0; mi < 2; ++mi)
#pragma unroll
      for (int nj = 0; nj < 4; ++nj)
#pragma unroll
        for (int rr = 0; rr < 4; ++rr) sc[mi][nj][rr] *= 0.125f;

    // online softmax (rows live in lr-lanes x rr-regs; reduce over nj + 16 lanes)
#pragma unroll
    for (int mi = 0; mi < 2; ++mi) {
      float tm[4], al[4], rs[4];
#pragma unroll
      for (int rr = 0; rr < 4; ++rr)
        tm[rr] = fmaxf(fmaxf(sc[mi][0][rr], sc[mi][1][rr]),
                       fmaxf(sc[mi][2][rr], sc[mi][3][rr]));
#pragma unroll
      for (int rr = 0; rr < 4; ++rr) {
#pragma unroll
        for (int off = 1; off < 16; off <<= 1)
          tm[rr] = fmaxf(tm[rr], __shfl_xor(tm[rr], off));
      }
#pragma unroll
      for (int rr = 0; rr < 4; ++rr) {
        float mn = fmaxf(mst[mi][rr], tm[rr]);
        al[rr] = __expf(mst[mi][rr] - mn);
        mst[mi][rr] = mn;
        rs[rr] = 0.f;
      }
#pragma unroll
      for (int nj = 0; nj < 4; ++nj)
#pragma unroll
        for (int rr = 0; rr < 4; ++rr) {
          float p = __expf(sc[mi][nj][rr] - mst[mi][rr]);
          sc[mi][nj][rr] = p;
          rs[rr] += p;
        }
#pragma unroll
      for (int rr = 0; rr < 4; ++rr) {
#pragma unroll
        for (int off = 1; off < 16; off <<= 1) rs[rr] += __shfl_xor(rs[rr], off);
      }
#pragma unroll
      for (int rr = 0; rr < 4; ++rr) lst[mi][rr] = lst[mi][rr] * al[rr] + rs[rr];
#pragma unroll
      for (int nd = 0; nd < 4; ++nd)
#pragma unroll
        for (int rr = 0; rr < 4; ++rr) accO[mi][nd][rr] *= al[rr];
    }

    // V fragments direct from global — issue BEFORE the P LDS round-trip to
    // hide L2 latency under the ds_write/ds_read chain
    short8 bv[4][2];
#pragma unroll
    for (int nd = 0; nd < 4; ++nd)
#pragma unroll
      for (int ks = 0; ks < 2; ++ks)
        bv[nd][ks] = *(const short8*)(vh + (size_t)(nd * 16 + lr) * 1024 + j0 +
                                      ks * 32 + lg * 8);

    // P -> LDS (per-wave region, padded rows: 72 elems = 144 B); no barrier needed
#pragma unroll
    for (int mi = 0; mi < 2; ++mi) {
      int prow = mi * 16 + lg * 4;
#pragma unroll
      for (int nj = 0; nj < 4; ++nj)
#pragma unroll
        for (int rr = 0; rr < 4; ++rr)
          *(u16*)(Pwb + (size_t)(prow + rr) * 144 + (nj * 16 + lr) * 2) =
              f2bf(sc[mi][nj][rr]);
    }

    // O += P @ V
    short8 ap[2][2];
#pragma unroll
    for (int mi = 0; mi < 2; ++mi)
#pragma unroll
      for (int ks = 0; ks < 2; ++ks)
        ap[mi][ks] = *(const short8*)(Pwb + (size_t)(mi * 16 + lr) * 144 + ks * 64 + lg * 16);
#pragma unroll
    for (int ks = 0; ks < 2; ++ks)
#pragma unroll
      for (int mi = 0; mi < 2; ++mi)
#pragma unroll
        for (int nd = 0; nd < 4; ++nd)
          accO[mi][nd] = mfma16(ap[mi][ks], bv[nd][ks], accO[mi][nd]);
  }

  // epilogue: O /= l, write [B][L][C] bf16 with c = h*64+dd
  int b = bh >> 3, h = bh & 7;
#pragma unroll
  for (int mi = 0; mi < 2; ++mi) {
    float inv[4];
#pragma unroll
    for (int rr = 0; rr < 4; ++rr) inv[rr] = 1.f / lst[mi][rr];
#pragma unroll
    for (int nd = 0; nd < 4; ++nd)
#pragma unroll
      for (int rr = 0; rr < 4; ++rr) {
        int row = q0 + w * 32 + mi * 16 + lg * 4 + rr;
        int col = h * 64 + nd * 16 + lr;
        ob[(size_t)(b * 1024 + row) * 512 + col] = f2bf(accO[mi][nd][rr] * inv[rr]);
      }
  }
}

// ---------------- K6: out-proj GEMM + bias + residual (fp32 out) ----------------
__global__ __launch_bounds__(256) void k_out(const u16* __restrict__ ob,
                                             const u16* __restrict__ wT,
                                             const float* __restrict__ bias,
                                             const float* __restrict__ x,
                                             float* __restrict__ out) {
  __shared__ __attribute__((aligned(16))) u16 As[128 * 64];
  __shared__ __attribute__((aligned(16))) u16 Bs[128 * 64];
  int bid = blockIdx.x;
  int tn = bid & 3, tm = bid >> 2;
  int m0 = tm * 128, n0 = tn * 128;
  int tid = threadIdx.x;
  int w = tid >> 6, lane = tid & 63, lr = lane & 15, lg = lane >> 4;
  int wr = w >> 1, wc = w & 1;
  const f32x4 fzero = {0.f, 0.f, 0.f, 0.f};
  f32x4 acc[4][4];
#pragma unroll
  for (int mi = 0; mi < 4; ++mi)
#pragma unroll
    for (int ni = 0; ni < 4; ++ni) acc[mi][ni] = fzero;
  char* Asb = (char*)As;
  char* Bsb = (char*)Bs;
  for (int kt = 0; kt < 8; ++kt) {
    int k0 = kt * 64;
    __syncthreads();
#pragma unroll
    for (int i = 0; i < 4; ++i) {
      int s = i * 256 + tid;
      int r = s >> 3, c = s & 7;
      gl_lds16(ob + ((size_t)(m0 + r) * 512 + k0 + ((c ^ (r & 7)) << 3)),
               Asb + ((s & ~63) << 4));
    }
#pragma unroll
    for (int i = 0; i < 4; ++i) {
      int s = i * 256 + tid;
      int r = s >> 3, c = s & 7;
      gl_lds16(wT + ((size_t)(n0 + r) * 512 + k0 + ((c ^ (r & 7)) << 3)),
               Bsb + ((s & ~63) << 4));
    }
    __syncthreads();
#pragma unroll
    for (int ks = 0; ks < 2; ++ks) {
      short8 af[4], bf[4];
#pragma unroll
      for (int mi = 0; mi < 4; ++mi) {
        int row = wr * 64 + mi * 16 + lr;
        int ck = ks * 4 + lg;
        af[mi] = *(const short8*)(Asb + row * 128 + ((ck ^ (lr & 7)) << 4));
      }
#pragma unroll
      for (int ni = 0; ni < 4; ++ni) {
        int row = wc * 64 + ni * 16 + lr;
        int ck = ks * 4 + lg;
        bf[ni] = *(const short8*)(Bsb + row * 128 + ((ck ^ (lr & 7)) << 4));
      }
#pragma unroll
      for (int mi = 0; mi < 4; ++mi)
#pragma unroll
        for (int ni = 0; ni < 4; ++ni)
          acc[mi][ni] = mfma16(af[mi], bf[ni], acc[mi][ni]);
    }
  }
#pragma unroll
  for (int mi = 0; mi < 4; ++mi) {
#pragma unroll
    for (int ni = 0; ni < 4; ++ni) {
      int n = n0 + wc * 64 + ni * 16 + lr;
      float bn = bias[n];
#pragma unroll
      for (int rr = 0; rr < 4; ++rr) {
        int m = m0 + wr * 64 + mi * 16 + lg * 4 + rr;
        size_t off = (size_t)m * 512 + n;
        out[off] = x[off] + acc[mi][ni][rr] + bn;
      }
    }
  }
}

extern "C" void kernel_launch(void* const* d_in, const int* in_sizes, int n_in,
                              void* d_out, int out_size, void* d_ws, size_t ws_size,
                              hipStream_t stream) {
  const float* x = (const float*)d_in[0];
  // d_in[1] = timesteps (unused by the reference computation)
  const float* gamma = (const float*)d_in[2];
  const float* beta = (const float*)d_in[3];
  const float* wqkv = (const float*)d_in[4];
  const float* bqkv = (const float*)d_in[5];
  const float* wout = (const float*)d_in[6];
  const float* bout = (const float*)d_in[7];
  float* out = (float*)d_out;

  char* ws = (char*)d_ws;
  float* stats = (float*)ws;                                   //   4096 B
  u16* gn = (u16*)(ws + 4096);                                 // 16 MB  [M][512]
  u16* wqkvT = (u16*)(ws + 4096 + 16777216);                   // 1.5 MB [1536][512]
  u16* woutT = (u16*)(ws + 4096 + 16777216 + 1572864);         // 0.5 MB [512][512]
  u16* qb = (u16*)(ws + 4096 + 16777216 + 1572864 + 524288);   // 16 MB  [BH][L][64]
  u16* kb = qb + 8388608;                                      // 16 MB  [BH][L][64]
  u16* vT = kb + 8388608;                                      // 16 MB  [BH][64][L]
  u16* ob = vT + 8388608;                                      // 16 MB  [M][512]

  k_gnstats<<<512, 256, 0, stream>>>(x, stats);
  k_gnapply<<<8192, 256, 0, stream>>>(x, stats, gamma, beta, gn);
  k_wtrans<<<4096, 256, 0, stream>>>(wqkv, wout, wqkvT, woutT);
  k_qkv<<<1536, 256, 0, stream>>>(gn, wqkvT, bqkv, qb, kb, vT);
  k_attn<<<1024, 256, 0, stream>>>(qb, kb, vT, ob);
  k_out<<<512, 256, 0, stream>>>(ob, woutT, bout, x, out);
}

// Round 3
// 237.331 us; speedup vs baseline: 1.1837x; 1.0085x over previous
//
#include <hip/hip_runtime.h>

// Problem constants: B=16, H=W=32 -> L=1024, C=512, G=32, nh=8, d=64
#define Bn 16
#define Ln 1024
#define Cn 512
#define Mn (Bn*Ln)     // 16384
#define N3n 1536

typedef unsigned short u16;
typedef __attribute__((ext_vector_type(8))) short short8;
typedef __attribute__((ext_vector_type(4))) float f32x4;

typedef const __attribute__((address_space(1))) void* gas_p;
typedef __attribute__((address_space(3))) void* las_p;

__device__ inline void gl_lds16(const void* g, void* l) {
  __builtin_amdgcn_global_load_lds((gas_p)g, (las_p)l, 16, 0, 0);
}

__device__ inline u16 f2bf(float f) {
  union { float f; unsigned u; } v; v.f = f;
  unsigned r = v.u + 0x7FFFu + ((v.u >> 16) & 1u);
  return (u16)(r >> 16);
}

__device__ inline f32x4 mfma16(short8 a, short8 b, f32x4 c) {
  return __builtin_amdgcn_mfma_f32_16x16x32_bf16(a, b, c, 0, 0, 0);
}

// ---------------- K1: GroupNorm stats (mean, rstd per (b,g)) ----------------
__global__ __launch_bounds__(256) void k_gnstats(const float* __restrict__ x,
                                                 float* __restrict__ stats) {
  int bid = blockIdx.x;            // b*32+g
  int b = bid >> 5, g = bid & 31;
  const float* base = x + (size_t)b * (Ln * Cn) + g * 16;
  int tid = threadIdx.x;
  float s1 = 0.f, s2 = 0.f;
  for (int i = 0; i < 16; ++i) {
    int s = i * 256 + tid;
    int l = s >> 2, cq = s & 3;
    float4 v = *(const float4*)(base + (size_t)l * Cn + cq * 4);
    s1 += v.x + v.y + v.z + v.w;
    s2 += v.x * v.x + v.y * v.y + v.z * v.z + v.w * v.w;
  }
  for (int off = 32; off > 0; off >>= 1) {
    s1 += __shfl_down(s1, off);
    s2 += __shfl_down(s2, off);
  }
  __shared__ float rb[8];
  int w = tid >> 6, lane = tid & 63;
  if (lane == 0) { rb[w] = s1; rb[4 + w] = s2; }
  __syncthreads();
  if (tid == 0) {
    float a = rb[0] + rb[1] + rb[2] + rb[3];
    float q = rb[4] + rb[5] + rb[6] + rb[7];
    float mean = a * (1.f / 16384.f);
    float var = q * (1.f / 16384.f) - mean * mean;
    stats[bid * 2] = mean;
    stats[bid * 2 + 1] = rsqrtf(var + 1e-5f);
  }
}

// ---------------- K2: GN apply + cast to bf16 ----------------
__global__ __launch_bounds__(256) void k_gnapply(const float* __restrict__ x,
                                                 const float* __restrict__ stats,
                                                 const float* __restrict__ gamma,
                                                 const float* __restrict__ beta,
                                                 u16* __restrict__ gn) {
  int idx = blockIdx.x * 256 + threadIdx.x;
  size_t e = (size_t)idx << 2;
  int m = (int)(e >> 9), c = (int)(e & 511);
  int b = m >> 10, g = c >> 4;
  float mean = stats[(b * 32 + g) * 2];
  float rstd = stats[(b * 32 + g) * 2 + 1];
  float4 xv = *(const float4*)(x + e);
  float4 gv = *(const float4*)(gamma + c);
  float4 bv = *(const float4*)(beta + c);
  ushort4 o;
  o.x = f2bf((xv.x - mean) * rstd * gv.x + bv.x);
  o.y = f2bf((xv.y - mean) * rstd * gv.y + bv.y);
  o.z = f2bf((xv.z - mean) * rstd * gv.z + bv.z);
  o.w = f2bf((xv.w - mean) * rstd * gv.w + bv.w);
  *(ushort4*)(gn + e) = o;
}

// ---------------- K3: transpose+cast weights to [N][K] bf16 ----------------
__global__ __launch_bounds__(256) void k_wtrans(const float* __restrict__ wqkv,
                                                const float* __restrict__ wout,
                                                u16* __restrict__ wqkvT,
                                                u16* __restrict__ woutT) {
  int id = blockIdx.x * 256 + threadIdx.x;
  if (id < Cn * N3n) {
    int k = id & 511, n = id >> 9;
    wqkvT[id] = f2bf(wqkv[(size_t)k * N3n + n]);
  } else {
    int id2 = id - Cn * N3n;
    int k = id2 & 511, n = id2 >> 9;
    woutT[id2] = f2bf(wout[(size_t)k * Cn + n]);
  }
}

// ---------------- K4: QKV GEMM [16384,512]@[512,1536] -> q,k,vT bf16 ----------------
__global__ __launch_bounds__(256) void k_qkv(const u16* __restrict__ gn,
                                             const u16* __restrict__ wT,
                                             const float* __restrict__ bias,
                                             u16* __restrict__ qb,
                                             u16* __restrict__ kb,
                                             u16* __restrict__ vT) {
  __shared__ __attribute__((aligned(16))) u16 As[128 * 64];
  __shared__ __attribute__((aligned(16))) u16 Bs[128 * 64];
  int bid = blockIdx.x;
  int tn = bid % 12, tm = bid / 12;
  int m0 = tm * 128, n0 = tn * 128;
  int tid = threadIdx.x;
  int w = tid >> 6, lane = tid & 63, lr = lane & 15, lg = lane >> 4;
  int wr = w >> 1, wc = w & 1;
  const f32x4 fzero = {0.f, 0.f, 0.f, 0.f};
  f32x4 acc[4][4];
#pragma unroll
  for (int mi = 0; mi < 4; ++mi)
#pragma unroll
    for (int ni = 0; ni < 4; ++ni) acc[mi][ni] = fzero;
  char* Asb = (char*)As;
  char* Bsb = (char*)Bs;
  for (int kt = 0; kt < 8; ++kt) {
    int k0 = kt * 64;
    __syncthreads();
#pragma unroll
    for (int i = 0; i < 4; ++i) {
      int s = i * 256 + tid;
      int r = s >> 3, c = s & 7;
      gl_lds16(gn + ((size_t)(m0 + r) * 512 + k0 + ((c ^ (r & 7)) << 3)),
               Asb + ((s & ~63) << 4));
    }
#pragma unroll
    for (int i = 0; i < 4; ++i) {
      int s = i * 256 + tid;
      int r = s >> 3, c = s & 7;
      gl_lds16(wT + ((size_t)(n0 + r) * 512 + k0 + ((c ^ (r & 7)) << 3)),
               Bsb + ((s & ~63) << 4));
    }
    __syncthreads();
#pragma unroll
    for (int ks = 0; ks < 2; ++ks) {
      short8 af[4], bf[4];
#pragma unroll
      for (int mi = 0; mi < 4; ++mi) {
        int row = wr * 64 + mi * 16 + lr;
        int ck = ks * 4 + lg;
        af[mi] = *(const short8*)(Asb + row * 128 + ((ck ^ (lr & 7)) << 4));
      }
#pragma unroll
      for (int ni = 0; ni < 4; ++ni) {
        int row = wc * 64 + ni * 16 + lr;
        int ck = ks * 4 + lg;
        bf[ni] = *(const short8*)(Bsb + row * 128 + ((ck ^ (lr & 7)) << 4));
      }
#pragma unroll
      for (int mi = 0; mi < 4; ++mi)
#pragma unroll
        for (int ni = 0; ni < 4; ++ni)
          acc[mi][ni] = mfma16(af[mi], bf[ni], acc[mi][ni]);
    }
  }
  // epilogue: scatter into q [BH][L][64], k [BH][L][64], vT [BH][64][L]
#pragma unroll
  for (int mi = 0; mi < 4; ++mi) {
#pragma unroll
    for (int ni = 0; ni < 4; ++ni) {
      int n = n0 + wc * 64 + ni * 16 + lr;
      float bn = bias[n];
      int which = n >> 9, nn = n & 511;
      int h = nn >> 6, dd = nn & 63;
#pragma unroll
      for (int rr = 0; rr < 4; ++rr) {
        int m = m0 + wr * 64 + mi * 16 + lg * 4 + rr;
        float v = acc[mi][ni][rr] + bn;
        int bb = m >> 10, li = m & 1023;
        if (which == 0)
          qb[((size_t)(bb * 8 + h) * 1024 + li) * 64 + dd] = f2bf(v);
        else if (which == 1)
          kb[((size_t)(bb * 8 + h) * 1024 + li) * 64 + dd] = f2bf(v);
        else
          vT[((size_t)(bb * 8 + h) * 64 + dd) * 1024 + li] = f2bf(v);
      }
    }
  }
}

// ---------------- K5: flash attention, swapped QK^T, wide P round-trip ----------------
__global__ __launch_bounds__(256) void k_attn(const u16* __restrict__ qb,
                                              const u16* __restrict__ kb,
                                              const u16* __restrict__ vT,
                                              u16* __restrict__ ob) {
  // per-wave P buffer: [32 q][64 k] bf16 = 4 KB, XOR-swizzled rows
  __shared__ __attribute__((aligned(16))) u16 Ps[4 * 32 * 64];
  int bid = blockIdx.x;
  // XCD-bijective swizzle: all 8 q-tiles of a head keep bid%8 constant
  int xq = bid & 7, kk = bid >> 3;
  int bh = ((kk & 15) << 3) | xq;
  int qt = kk >> 4;
  const u16* qh = qb + (size_t)bh * 65536;
  const u16* kh = kb + (size_t)bh * 65536;
  const u16* vh = vT + (size_t)bh * 65536;
  int tid = threadIdx.x, w = tid >> 6, lane = tid & 63, lr = lane & 15, lg = lane >> 4;
  int q0 = qt * 128;
  const f32x4 fzero = {0.f, 0.f, 0.f, 0.f};

  // Q fragments (B-operand of swapped QK^T): lane holds col q=lr, d-slice lg*8
  short8 qf[2][2];
#pragma unroll
  for (int mi = 0; mi < 2; ++mi)
#pragma unroll
    for (int ks = 0; ks < 2; ++ks)
      qf[mi][ks] = *(const short8*)(qh + (size_t)(q0 + w * 32 + mi * 16 + lr) * 64 +
                                    ks * 32 + lg * 8);
  f32x4 accO[2][4];
  float mst[2], lst[2];
#pragma unroll
  for (int mi = 0; mi < 2; ++mi) {
#pragma unroll
    for (int nd = 0; nd < 4; ++nd) accO[mi][nd] = fzero;
    mst[mi] = -1e30f; lst[mi] = 0.f;
  }
  char* Pwb = (char*)(Ps + w * 2048);   // 32 rows x 128 B

#pragma unroll 1
  for (int jt = 0; jt < 16; ++jt) {
    int j0 = jt * 64;

    // K fragments (A-operand): lane holds k-row lr, d-slice lg*8 (L2-resident)
    short8 kf[4][2];
#pragma unroll
    for (int nj = 0; nj < 4; ++nj)
#pragma unroll
      for (int ks = 0; ks < 2; ++ks)
        kf[nj][ks] = *(const short8*)(kh + (size_t)(j0 + nj * 16 + lr) * 64 +
                                      ks * 32 + lg * 8);

    // S^T = K Q^T: sc[mi][nj] has col=q(lr), row=k(nj*16+lg*4+rr)
    f32x4 sc[2][4];
#pragma unroll
    for (int mi = 0; mi < 2; ++mi)
#pragma unroll
      for (int nj = 0; nj < 4; ++nj) sc[mi][nj] = fzero;
#pragma unroll
    for (int ks = 0; ks < 2; ++ks)
#pragma unroll
      for (int mi = 0; mi < 2; ++mi)
#pragma unroll
        for (int nj = 0; nj < 4; ++nj)
          sc[mi][nj] = mfma16(kf[nj][ks], qf[mi][ks], sc[mi][nj]);

    // V fragments (B-operand of PV) — independent of softmax, issue early
    short8 bv[4][2];
#pragma unroll
    for (int nd = 0; nd < 4; ++nd)
#pragma unroll
      for (int ks = 0; ks < 2; ++ks)
        bv[nd][ks] = *(const short8*)(vh + (size_t)(nd * 16 + lr) * 1024 + j0 +
                                      ks * 32 + lg * 8);

    // online softmax: each lane holds 16 raw scores of q-row lr (quarter of 64 cols)
#pragma unroll
    for (int mi = 0; mi < 2; ++mi) {
      float mloc = sc[mi][0][0];
#pragma unroll
      for (int nj = 0; nj < 4; ++nj)
#pragma unroll
        for (int rr = 0; rr < 4; ++rr) mloc = fmaxf(mloc, sc[mi][nj][rr]);
      mloc = fmaxf(mloc, __shfl_xor(mloc, 16));
      mloc = fmaxf(mloc, __shfl_xor(mloc, 32));
      float mn = fmaxf(mst[mi], mloc);
      float al = __expf((mst[mi] - mn) * 0.125f);
      mst[mi] = mn;
      float nm = -mn * 0.125f;
      float rs = 0.f;
#pragma unroll
      for (int nj = 0; nj < 4; ++nj)
#pragma unroll
        for (int rr = 0; rr < 4; ++rr) {
          float p = __expf(__builtin_fmaf(sc[mi][nj][rr], 0.125f, nm));
          sc[mi][nj][rr] = p;
          rs += p;
        }
      rs += __shfl_xor(rs, 16);
      rs += __shfl_xor(rs, 32);
      lst[mi] = lst[mi] * al + rs;

      // broadcast al (lr-indexed) to accO rows (lg*4+rr-indexed), rescale O
#pragma unroll
      for (int rr = 0; rr < 4; ++rr) {
        float ab = __shfl(al, (lane & 48) | ((lane >> 4) & 3) * 4 + rr);
#pragma unroll
        for (int nd = 0; nd < 4; ++nd) accO[mi][nd][rr] *= ab;
      }

      // pack 4 consecutive-k bf16 and write P[q][k] row as ds_write_b64
#pragma unroll
      for (int nj = 0; nj < 4; ++nj) {
        unsigned p01 = (unsigned)f2bf(sc[mi][nj][0]) | ((unsigned)f2bf(sc[mi][nj][1]) << 16);
        unsigned p23 = (unsigned)f2bf(sc[mi][nj][2]) | ((unsigned)f2bf(sc[mi][nj][3]) << 16);
        int row = mi * 16 + lr;
        int byte = row * 128 + (nj * 16 + lg * 4) * 2;
        byte ^= (row & 7) << 4;
        uint2 pv; pv.x = p01; pv.y = p23;
        *(uint2*)(Pwb + byte) = pv;
      }
    }

    // O += P @ V : A-fragment of P from LDS (conflict-free b128 with XOR swizzle)
    short8 ap[2][2];
#pragma unroll
    for (int mi = 0; mi < 2; ++mi)
#pragma unroll
      for (int ks = 0; ks < 2; ++ks) {
        int row = mi * 16 + lr;
        int byte = row * 128 + (ks * 32 + lg * 8) * 2;
        byte ^= (row & 7) << 4;
        ap[mi][ks] = *(const short8*)(Pwb + byte);
      }
#pragma unroll
    for (int ks = 0; ks < 2; ++ks)
#pragma unroll
      for (int mi = 0; mi < 2; ++mi)
#pragma unroll
        for (int nd = 0; nd < 4; ++nd)
          accO[mi][nd] = mfma16(ap[mi][ks], bv[nd][ks], accO[mi][nd]);
  }

  // epilogue: O /= l (broadcast 1/lst from lr-lanes to accO rows), write bf16
  int b = bh >> 3, h = bh & 7;
#pragma unroll
  for (int mi = 0; mi < 2; ++mi) {
    float il = 1.f / lst[mi];
#pragma unroll
    for (int rr = 0; rr < 4; ++rr) {
      float ib = __shfl(il, (lane & 48) | ((lane >> 4) & 3) * 4 + rr);
      int row = q0 + w * 32 + mi * 16 + (lg & 3) * 4 + rr;
#pragma unroll
      for (int nd = 0; nd < 4; ++nd) {
        int col = h * 64 + nd * 16 + lr;
        ob[(size_t)(b * 1024 + row) * 512 + col] = f2bf(accO[mi][nd][rr] * ib);
      }
    }
  }
}

// ---------------- K6: out-proj GEMM + bias + residual (fp32 out) ----------------
__global__ __launch_bounds__(256) void k_out(const u16* __restrict__ ob,
                                             const u16* __restrict__ wT,
                                             const float* __restrict__ bias,
                                             const float* __restrict__ x,
                                             float* __restrict__ out) {
  __shared__ __attribute__((aligned(16))) u16 As[128 * 64];
  __shared__ __attribute__((aligned(16))) u16 Bs[128 * 64];
  int bid = blockIdx.x;
  int tn = bid & 3, tm = bid >> 2;
  int m0 = tm * 128, n0 = tn * 128;
  int tid = threadIdx.x;
  int w = tid >> 6, lane = tid & 63, lr = lane & 15, lg = lane >> 4;
  int wr = w >> 1, wc = w & 1;
  const f32x4 fzero = {0.f, 0.f, 0.f, 0.f};
  f32x4 acc[4][4];
#pragma unroll
  for (int mi = 0; mi < 4; ++mi)
#pragma unroll
    for (int ni = 0; ni < 4; ++ni) acc[mi][ni] = fzero;
  char* Asb = (char*)As;
  char* Bsb = (char*)Bs;
  for (int kt = 0; kt < 8; ++kt) {
    int k0 = kt * 64;
    __syncthreads();
#pragma unroll
    for (int i = 0; i < 4; ++i) {
      int s = i * 256 + tid;
      int r = s >> 3, c = s & 7;
      gl_lds16(ob + ((size_t)(m0 + r) * 512 + k0 + ((c ^ (r & 7)) << 3)),
               Asb + ((s & ~63) << 4));
    }
#pragma unroll
    for (int i = 0; i < 4; ++i) {
      int s = i * 256 + tid;
      int r = s >> 3, c = s & 7;
      gl_lds16(wT + ((size_t)(n0 + r) * 512 + k0 + ((c ^ (r & 7)) << 3)),
               Bsb + ((s & ~63) << 4));
    }
    __syncthreads();
#pragma unroll
    for (int ks = 0; ks < 2; ++ks) {
      short8 af[4], bf[4];
#pragma unroll
      for (int mi = 0; mi < 4; ++mi) {
        int row = wr * 64 + mi * 16 + lr;
        int ck = ks * 4 + lg;
        af[mi] = *(const short8*)(Asb + row * 128 + ((ck ^ (lr & 7)) << 4));
      }
#pragma unroll
      for (int ni = 0; ni < 4; ++ni) {
        int row = wc * 64 + ni * 16 + lr;
        int ck = ks * 4 + lg;
        bf[ni] = *(const short8*)(Bsb + row * 128 + ((ck ^ (lr & 7)) << 4));
      }
#pragma unroll
      for (int mi = 0; mi < 4; ++mi)
#pragma unroll
        for (int ni = 0; ni < 4; ++ni)
          acc[mi][ni] = mfma16(af[mi], bf[ni], acc[mi][ni]);
    }
  }
#pragma unroll
  for (int mi = 0; mi < 4; ++mi) {
#pragma unroll
    for (int ni = 0; ni < 4; ++ni) {
      int n = n0 + wc * 64 + ni * 16 + lr;
      float bn = bias[n];
#pragma unroll
      for (int rr = 0; rr < 4; ++rr) {
        int m = m0 + wr * 64 + mi * 16 + lg * 4 + rr;
        size_t off = (size_t)m * 512 + n;
        out[off] = x[off] + acc[mi][ni][rr] + bn;
      }
    }
  }
}

extern "C" void kernel_launch(void* const* d_in, const int* in_sizes, int n_in,
                              void* d_out, int out_size, void* d_ws, size_t ws_size,
                              hipStream_t stream) {
  const float* x = (const float*)d_in[0];
  // d_in[1] = timesteps (unused by the reference computation)
  const float* gamma = (const float*)d_in[2];
  const float* beta = (const float*)d_in[3];
  const float* wqkv = (const float*)d_in[4];
  const float* bqkv = (const float*)d_in[5];
  const float* wout = (const float*)d_in[6];
  const float* bout = (const float*)d_in[7];
  float* out = (float*)d_out;

  char* ws = (char*)d_ws;
  float* stats = (float*)ws;                                   //   4096 B
  u16* gn = (u16*)(ws + 4096);                                 // 16 MB  [M][512]
  u16* wqkvT = (u16*)(ws + 4096 + 16777216);                   // 1.5 MB [1536][512]
  u16* woutT = (u16*)(ws + 4096 + 16777216 + 1572864);         // 0.5 MB [512][512]
  u16* qb = (u16*)(ws + 4096 + 16777216 + 1572864 + 524288);   // 16 MB  [BH][L][64]
  u16* kb = qb + 8388608;                                      // 16 MB  [BH][L][64]
  u16* vT = kb + 8388608;                                      // 16 MB  [BH][64][L]
  u16* ob = vT + 8388608;                                      // 16 MB  [M][512]

  k_gnstats<<<512, 256, 0, stream>>>(x, stats);
  k_gnapply<<<8192, 256, 0, stream>>>(x, stats, gamma, beta, gn);
  k_wtrans<<<4096, 256, 0, stream>>>(wqkv, wout, wqkvT, woutT);
  k_qkv<<<1536, 256, 0, stream>>>(gn, wqkvT, bqkv, qb, kb, vT);
  k_attn<<<1024, 256, 0, stream>>>(qb, kb, vT, ob);
  k_out<<<512, 256, 0, stream>>>(ob, woutT, bout, x, out);
}

// Round 4
// 186.729 us; speedup vs baseline: 1.5044x; 1.2710x over previous
//
#include <hip/hip_runtime.h>

// Problem constants: B=16, H=W=32 -> L=1024, C=512, G=32, nh=8, d=64
#define Bn 16
#define Ln 1024
#define Cn 512
#define Mn (Bn*Ln)     // 16384
#define N3n 1536

typedef unsigned short u16;
typedef __attribute__((ext_vector_type(8))) short short8;
typedef __attribute__((ext_vector_type(4))) float f32x4;

typedef const __attribute__((address_space(1))) void* gas_p;
typedef __attribute__((address_space(3))) void* las_p;

__device__ inline void gl_lds16(const void* g, void* l) {
  __builtin_amdgcn_global_load_lds((gas_p)g, (las_p)l, 16, 0, 0);
}

__device__ inline u16 f2bf(float f) {
  union { float f; unsigned u; } v; v.f = f;
  unsigned r = v.u + 0x7FFFu + ((v.u >> 16) & 1u);
  return (u16)(r >> 16);
}

__device__ inline f32x4 mfma16(short8 a, short8 b, f32x4 c) {
  return __builtin_amdgcn_mfma_f32_16x16x32_bf16(a, b, c, 0, 0, 0);
}

// ---------------- K1: GroupNorm stats (mean, rstd per (b,g)) ----------------
__global__ __launch_bounds__(256) void k_gnstats(const float* __restrict__ x,
                                                 float* __restrict__ stats) {
  int bid = blockIdx.x;            // b*32+g
  int b = bid >> 5, g = bid & 31;
  const float* base = x + (size_t)b * (Ln * Cn) + g * 16;
  int tid = threadIdx.x;
  float s1 = 0.f, s2 = 0.f;
  for (int i = 0; i < 16; ++i) {
    int s = i * 256 + tid;
    int l = s >> 2, cq = s & 3;
    float4 v = *(const float4*)(base + (size_t)l * Cn + cq * 4);
    s1 += v.x + v.y + v.z + v.w;
    s2 += v.x * v.x + v.y * v.y + v.z * v.z + v.w * v.w;
  }
  for (int off = 32; off > 0; off >>= 1) {
    s1 += __shfl_down(s1, off);
    s2 += __shfl_down(s2, off);
  }
  __shared__ float rb[8];
  int w = tid >> 6, lane = tid & 63;
  if (lane == 0) { rb[w] = s1; rb[4 + w] = s2; }
  __syncthreads();
  if (tid == 0) {
    float a = rb[0] + rb[1] + rb[2] + rb[3];
    float q = rb[4] + rb[5] + rb[6] + rb[7];
    float mean = a * (1.f / 16384.f);
    float var = q * (1.f / 16384.f) - mean * mean;
    stats[bid * 2] = mean;
    stats[bid * 2 + 1] = rsqrtf(var + 1e-5f);
  }
}

// ---------------- K2: GN apply + cast to bf16 ----------------
__global__ __launch_bounds__(256) void k_gnapply(const float* __restrict__ x,
                                                 const float* __restrict__ stats,
                                                 const float* __restrict__ gamma,
                                                 const float* __restrict__ beta,
                                                 u16* __restrict__ gn) {
  int idx = blockIdx.x * 256 + threadIdx.x;
  size_t e = (size_t)idx << 2;
  int m = (int)(e >> 9), c = (int)(e & 511);
  int b = m >> 10, g = c >> 4;
  float mean = stats[(b * 32 + g) * 2];
  float rstd = stats[(b * 32 + g) * 2 + 1];
  float4 xv = *(const float4*)(x + e);
  float4 gv = *(const float4*)(gamma + c);
  float4 bv = *(const float4*)(beta + c);
  ushort4 o;
  o.x = f2bf((xv.x - mean) * rstd * gv.x + bv.x);
  o.y = f2bf((xv.y - mean) * rstd * gv.y + bv.y);
  o.z = f2bf((xv.z - mean) * rstd * gv.z + bv.z);
  o.w = f2bf((xv.w - mean) * rstd * gv.w + bv.w);
  *(ushort4*)(gn + e) = o;
}

// ---------------- K3: transpose+cast weights to [N][K] bf16 ----------------
__global__ __launch_bounds__(256) void k_wtrans(const float* __restrict__ wqkv,
                                                const float* __restrict__ wout,
                                                u16* __restrict__ wqkvT,
                                                u16* __restrict__ woutT) {
  int id = blockIdx.x * 256 + threadIdx.x;
  if (id < Cn * N3n) {
    int k = id & 511, n = id >> 9;
    wqkvT[id] = f2bf(wqkv[(size_t)k * N3n + n]);
  } else {
    int id2 = id - Cn * N3n;
    int k = id2 & 511, n = id2 >> 9;
    woutT[id2] = f2bf(wout[(size_t)k * Cn + n]);
  }
}

// ---------------- K4: QKV GEMM [16384,512]@[512,1536] -> q,k,vT bf16 ----------------
__global__ __launch_bounds__(256) void k_qkv(const u16* __restrict__ gn,
                                             const u16* __restrict__ wT,
                                             const float* __restrict__ bias,
                                             u16* __restrict__ qb,
                                             u16* __restrict__ kb,
                                             u16* __restrict__ vT) {
  __shared__ __attribute__((aligned(16))) u16 As[128 * 64];
  __shared__ __attribute__((aligned(16))) u16 Bs[128 * 64];
  int bid = blockIdx.x;
  int tn = bid % 12, tm = bid / 12;
  int m0 = tm * 128, n0 = tn * 128;
  int tid = threadIdx.x;
  int w = tid >> 6, lane = tid & 63, lr = lane & 15, lg = lane >> 4;
  int wr = w >> 1, wc = w & 1;
  const f32x4 fzero = {0.f, 0.f, 0.f, 0.f};
  f32x4 acc[4][4];
#pragma unroll
  for (int mi = 0; mi < 4; ++mi)
#pragma unroll
    for (int ni = 0; ni < 4; ++ni) acc[mi][ni] = fzero;
  char* Asb = (char*)As;
  char* Bsb = (char*)Bs;
  for (int kt = 0; kt < 8; ++kt) {
    int k0 = kt * 64;
    __syncthreads();
#pragma unroll
    for (int i = 0; i < 4; ++i) {
      int s = i * 256 + tid;
      int r = s >> 3, c = s & 7;
      gl_lds16(gn + ((size_t)(m0 + r) * 512 + k0 + ((c ^ (r & 7)) << 3)),
               Asb + ((s & ~63) << 4));
    }
#pragma unroll
    for (int i = 0; i < 4; ++i) {
      int s = i * 256 + tid;
      int r = s >> 3, c = s & 7;
      gl_lds16(wT + ((size_t)(n0 + r) * 512 + k0 + ((c ^ (r & 7)) << 3)),
               Bsb + ((s & ~63) << 4));
    }
    __syncthreads();
#pragma unroll
    for (int ks = 0; ks < 2; ++ks) {
      short8 af[4], bf[4];
#pragma unroll
      for (int mi = 0; mi < 4; ++mi) {
        int row = wr * 64 + mi * 16 + lr;
        int ck = ks * 4 + lg;
        af[mi] = *(const short8*)(Asb + row * 128 + ((ck ^ (lr & 7)) << 4));
      }
#pragma unroll
      for (int ni = 0; ni < 4; ++ni) {
        int row = wc * 64 + ni * 16 + lr;
        int ck = ks * 4 + lg;
        bf[ni] = *(const short8*)(Bsb + row * 128 + ((ck ^ (lr & 7)) << 4));
      }
#pragma unroll
      for (int mi = 0; mi < 4; ++mi)
#pragma unroll
        for (int ni = 0; ni < 4; ++ni)
          acc[mi][ni] = mfma16(af[mi], bf[ni], acc[mi][ni]);
    }
  }
  // epilogue: scatter into q [BH][L][64], k [BH][L][64], vT [BH][64][L]
#pragma unroll
  for (int mi = 0; mi < 4; ++mi) {
#pragma unroll
    for (int ni = 0; ni < 4; ++ni) {
      int n = n0 + wc * 64 + ni * 16 + lr;
      float bn = bias[n];
      int which = n >> 9, nn = n & 511;
      int h = nn >> 6, dd = nn & 63;
#pragma unroll
      for (int rr = 0; rr < 4; ++rr) {
        int m = m0 + wr * 64 + mi * 16 + lg * 4 + rr;
        float v = acc[mi][ni][rr] + bn;
        int bb = m >> 10, li = m & 1023;
        if (which == 0)
          qb[((size_t)(bb * 8 + h) * 1024 + li) * 64 + dd] = f2bf(v);
        else if (which == 1)
          kb[((size_t)(bb * 8 + h) * 1024 + li) * 64 + dd] = f2bf(v);
        else
          vT[((size_t)(bb * 8 + h) * 64 + dd) * 1024 + li] = f2bf(v);
      }
    }
  }
}

// ---------------- K5: flash attention, 8-wave block, LDS-shared K/V, 2-phase pipeline ----------------
__global__ __launch_bounds__(512, 4) void k_attn(const u16* __restrict__ qb,
                                                 const u16* __restrict__ kb,
                                                 const u16* __restrict__ vT,
                                                 u16* __restrict__ ob) {
  __shared__ __attribute__((aligned(16))) u16 Ks[2 * 64 * 64];  // 16 KB dbuf
  __shared__ __attribute__((aligned(16))) u16 Vs[2 * 64 * 64];  // 16 KB dbuf
  __shared__ __attribute__((aligned(16))) u16 Ps[8 * 32 * 64];  // 32 KB per-wave P
  int bid = blockIdx.x;
  // XCD-bijective swizzle: all 4 q-tiles of a head keep bid%8 constant
  int xq = bid & 7, kk = bid >> 3;              // bid in [0,512)
  int bh = ((kk & 15) << 3) | xq;               // [0,128)
  int qt = kk >> 4;                             // [0,4)
  const u16* qh = qb + (size_t)bh * 65536;
  const u16* kh = kb + (size_t)bh * 65536;
  const u16* vh = vT + (size_t)bh * 65536;
  int tid = threadIdx.x, w = tid >> 6, lane = tid & 63, lr = lane & 15, lg = lane >> 4;
  int q0 = qt * 256 + w * 32;
  const f32x4 fzero = {0.f, 0.f, 0.f, 0.f};

  // Q fragments (B-operand of swapped QK^T): lane holds col q=lr, d-slice lg*8
  short8 qf[2][2];
#pragma unroll
  for (int mi = 0; mi < 2; ++mi)
#pragma unroll
    for (int ks = 0; ks < 2; ++ks)
      qf[mi][ks] = *(const short8*)(qh + (size_t)(q0 + mi * 16 + lr) * 64 +
                                    ks * 32 + lg * 8);
  f32x4 accO[2][4];
  float mst[2], lst[2];
#pragma unroll
  for (int mi = 0; mi < 2; ++mi) {
#pragma unroll
    for (int nd = 0; nd < 4; ++nd) accO[mi][nd] = fzero;
    mst[mi] = -1e30f; lst[mi] = 0.f;
  }
  char* Pwb = (char*)(Ps + w * 2048);   // 32 rows x 128 B per wave

  int sr = tid >> 3, sc8 = tid & 7;     // staging: row, 16B-chunk (512 thr = 64x8)
  size_t koff = (size_t)sr * 64 + ((sc8 ^ (sr & 7)) << 3);
  size_t voff = (size_t)sr * 1024 + ((sc8 ^ (sr & 7)) << 3);
  int ldst = (tid & ~63) << 4;          // wave-uniform LDS dest base

  // prologue: stage tile 0 into buf 0
  gl_lds16(kh + koff, (char*)Ks + ldst);
  gl_lds16(vh + voff, (char*)Vs + ldst);
  __syncthreads();

#pragma unroll 1
  for (int jt = 0; jt < 16; ++jt) {
    int cur = jt & 1;
    char* Ksb = (char*)Ks + cur * 8192;
    char* Vsb = (char*)Vs + cur * 8192;
    // stage next tile into the other buffer (issued before compute)
    if (jt < 15) {
      int nb = cur ^ 1;
      gl_lds16(kh + (size_t)(jt + 1) * 64 * 64 + koff, (char*)Ks + nb * 8192 + ldst);
      gl_lds16(vh + (size_t)(jt + 1) * 64 + voff, (char*)Vs + nb * 8192 + ldst);
    }

    // K fragments (A-operand): row = k-pos, from LDS
    short8 kf[4][2];
#pragma unroll
    for (int nj = 0; nj < 4; ++nj)
#pragma unroll
      for (int ks = 0; ks < 2; ++ks) {
        int row = nj * 16 + lr;
        kf[nj][ks] = *(const short8*)(Ksb + row * 128 + (((ks * 4 + lg) ^ (row & 7)) << 4));
      }

    // S^T = K Q^T: sc[mi][nj] has col=q(lr), row=k(nj*16+lg*4+rr)
    f32x4 sc[2][4];
#pragma unroll
    for (int mi = 0; mi < 2; ++mi)
#pragma unroll
      for (int nj = 0; nj < 4; ++nj) sc[mi][nj] = fzero;
#pragma unroll
    for (int ks = 0; ks < 2; ++ks)
#pragma unroll
      for (int mi = 0; mi < 2; ++mi)
#pragma unroll
        for (int nj = 0; nj < 4; ++nj)
          sc[mi][nj] = mfma16(kf[nj][ks], qf[mi][ks], sc[mi][nj]);

    // online softmax: each lane holds 16 raw scores of q-row lr
#pragma unroll
    for (int mi = 0; mi < 2; ++mi) {
      float mloc = sc[mi][0][0];
#pragma unroll
      for (int nj = 0; nj < 4; ++nj)
#pragma unroll
        for (int rr = 0; rr < 4; ++rr) mloc = fmaxf(mloc, sc[mi][nj][rr]);
      mloc = fmaxf(mloc, __shfl_xor(mloc, 16));
      mloc = fmaxf(mloc, __shfl_xor(mloc, 32));
      float mn = fmaxf(mst[mi], mloc);
      float al = __expf((mst[mi] - mn) * 0.125f);
      mst[mi] = mn;
      float nm = -mn * 0.125f;
      float rs = 0.f;
#pragma unroll
      for (int nj = 0; nj < 4; ++nj)
#pragma unroll
        for (int rr = 0; rr < 4; ++rr) {
          float p = __expf(__builtin_fmaf(sc[mi][nj][rr], 0.125f, nm));
          sc[mi][nj][rr] = p;
          rs += p;
        }
      rs += __shfl_xor(rs, 16);
      rs += __shfl_xor(rs, 32);
      lst[mi] = lst[mi] * al + rs;

      // broadcast al (lr-indexed) to accO rows (lg*4+rr-indexed), rescale O
#pragma unroll
      for (int rr = 0; rr < 4; ++rr) {
        float ab = __shfl(al, (lane & 48) | ((lane >> 4) & 3) * 4 + rr);
#pragma unroll
        for (int nd = 0; nd < 4; ++nd) accO[mi][nd][rr] *= ab;
      }

      // pack 4 consecutive-k bf16 and write P[q][k] row as ds_write_b64
#pragma unroll
      for (int nj = 0; nj < 4; ++nj) {
        unsigned p01 = (unsigned)f2bf(sc[mi][nj][0]) | ((unsigned)f2bf(sc[mi][nj][1]) << 16);
        unsigned p23 = (unsigned)f2bf(sc[mi][nj][2]) | ((unsigned)f2bf(sc[mi][nj][3]) << 16);
        int row = mi * 16 + lr;
        int byte = row * 128 + (nj * 16 + lg * 4) * 2;
        byte ^= (row & 7) << 4;
        uint2 pv; pv.x = p01; pv.y = p23;
        *(uint2*)(Pwb + byte) = pv;
      }
    }

    // V fragments (B-operand of PV) from LDS
    short8 bv[4][2];
#pragma unroll
    for (int nd = 0; nd < 4; ++nd)
#pragma unroll
      for (int ks = 0; ks < 2; ++ks) {
        int row = nd * 16 + lr;
        bv[nd][ks] = *(const short8*)(Vsb + row * 128 + (((ks * 4 + lg) ^ (row & 7)) << 4));
      }

    // O += P @ V : A-fragment of P from LDS (XOR-swizzled b128)
    short8 ap[2][2];
#pragma unroll
    for (int mi = 0; mi < 2; ++mi)
#pragma unroll
      for (int ks = 0; ks < 2; ++ks) {
        int row = mi * 16 + lr;
        int byte = row * 128 + (ks * 32 + lg * 8) * 2;
        byte ^= (row & 7) << 4;
        ap[mi][ks] = *(const short8*)(Pwb + byte);
      }
#pragma unroll
    for (int ks = 0; ks < 2; ++ks)
#pragma unroll
      for (int mi = 0; mi < 2; ++mi)
#pragma unroll
        for (int nd = 0; nd < 4; ++nd)
          accO[mi][nd] = mfma16(ap[mi][ks], bv[nd][ks], accO[mi][nd]);

    // publish: own staged loads landed (syncthreads drains vmcnt) + all waves done with cur
    __syncthreads();
  }

  // epilogue: O /= l (broadcast 1/lst from lr-lanes to accO rows), write bf16
  int b = bh >> 3, h = bh & 7;
#pragma unroll
  for (int mi = 0; mi < 2; ++mi) {
    float il = 1.f / lst[mi];
#pragma unroll
    for (int rr = 0; rr < 4; ++rr) {
      float ib = __shfl(il, (lane & 48) | ((lane >> 4) & 3) * 4 + rr);
      int row = q0 + mi * 16 + lg * 4 + rr;
#pragma unroll
      for (int nd = 0; nd < 4; ++nd) {
        int col = h * 64 + nd * 16 + lr;
        ob[(size_t)(b * 1024 + row) * 512 + col] = f2bf(accO[mi][nd][rr] * ib);
      }
    }
  }
}

// ---------------- K6: out-proj GEMM + bias + residual (fp32 out) ----------------
__global__ __launch_bounds__(256) void k_out(const u16* __restrict__ ob,
                                             const u16* __restrict__ wT,
                                             const float* __restrict__ bias,
                                             const float* __restrict__ x,
                                             float* __restrict__ out) {
  __shared__ __attribute__((aligned(16))) u16 As[128 * 64];
  __shared__ __attribute__((aligned(16))) u16 Bs[128 * 64];
  int bid = blockIdx.x;
  int tn = bid & 3, tm = bid >> 2;
  int m0 = tm * 128, n0 = tn * 128;
  int tid = threadIdx.x;
  int w = tid >> 6, lane = tid & 63, lr = lane & 15, lg = lane >> 4;
  int wr = w >> 1, wc = w & 1;
  const f32x4 fzero = {0.f, 0.f, 0.f, 0.f};
  f32x4 acc[4][4];
#pragma unroll
  for (int mi = 0; mi < 4; ++mi)
#pragma unroll
    for (int ni = 0; ni < 4; ++ni) acc[mi][ni] = fzero;
  char* Asb = (char*)As;
  char* Bsb = (char*)Bs;
  for (int kt = 0; kt < 8; ++kt) {
    int k0 = kt * 64;
    __syncthreads();
#pragma unroll
    for (int i = 0; i < 4; ++i) {
      int s = i * 256 + tid;
      int r = s >> 3, c = s & 7;
      gl_lds16(ob + ((size_t)(m0 + r) * 512 + k0 + ((c ^ (r & 7)) << 3)),
               Asb + ((s & ~63) << 4));
    }
#pragma unroll
    for (int i = 0; i < 4; ++i) {
      int s = i * 256 + tid;
      int r = s >> 3, c = s & 7;
      gl_lds16(wT + ((size_t)(n0 + r) * 512 + k0 + ((c ^ (r & 7)) << 3)),
               Bsb + ((s & ~63) << 4));
    }
    __syncthreads();
#pragma unroll
    for (int ks = 0; ks < 2; ++ks) {
      short8 af[4], bf[4];
#pragma unroll
      for (int mi = 0; mi < 4; ++mi) {
        int row = wr * 64 + mi * 16 + lr;
        int ck = ks * 4 + lg;
        af[mi] = *(const short8*)(Asb + row * 128 + ((ck ^ (lr & 7)) << 4));
      }
#pragma unroll
      for (int ni = 0; ni < 4; ++ni) {
        int row = wc * 64 + ni * 16 + lr;
        int ck = ks * 4 + lg;
        bf[ni] = *(const short8*)(Bsb + row * 128 + ((ck ^ (lr & 7)) << 4));
      }
#pragma unroll
      for (int mi = 0; mi < 4; ++mi)
#pragma unroll
        for (int ni = 0; ni < 4; ++ni)
          acc[mi][ni] = mfma16(af[mi], bf[ni], acc[mi][ni]);
    }
  }
#pragma unroll
  for (int mi = 0; mi < 4; ++mi) {
#pragma unroll
    for (int ni = 0; ni < 4; ++ni) {
      int n = n0 + wc * 64 + ni * 16 + lr;
      float bn = bias[n];
#pragma unroll
      for (int rr = 0; rr < 4; ++rr) {
        int m = m0 + wr * 64 + mi * 16 + lg * 4 + rr;
        size_t off = (size_t)m * 512 + n;
        out[off] = x[off] + acc[mi][ni][rr] + bn;
      }
    }
  }
}

extern "C" void kernel_launch(void* const* d_in, const int* in_sizes, int n_in,
                              void* d_out, int out_size, void* d_ws, size_t ws_size,
                              hipStream_t stream) {
  const float* x = (const float*)d_in[0];
  // d_in[1] = timesteps (unused by the reference computation)
  const float* gamma = (const float*)d_in[2];
  const float* beta = (const float*)d_in[3];
  const float* wqkv = (const float*)d_in[4];
  const float* bqkv = (const float*)d_in[5];
  const float* wout = (const float*)d_in[6];
  const float* bout = (const float*)d_in[7];
  float* out = (float*)d_out;

  char* ws = (char*)d_ws;
  float* stats = (float*)ws;                                   //   4096 B
  u16* gn = (u16*)(ws + 4096);                                 // 16 MB  [M][512]
  u16* wqkvT = (u16*)(ws + 4096 + 16777216);                   // 1.5 MB [1536][512]
  u16* woutT = (u16*)(ws + 4096 + 16777216 + 1572864);         // 0.5 MB [512][512]
  u16* qb = (u16*)(ws + 4096 + 16777216 + 1572864 + 524288);   // 16 MB  [BH][L][64]
  u16* kb = qb + 8388608;                                      // 16 MB  [BH][L][64]
  u16* vT = kb + 8388608;                                      // 16 MB  [BH][64][L]
  u16* ob = vT + 8388608;                                      // 16 MB  [M][512]

  k_gnstats<<<512, 256, 0, stream>>>(x, stats);
  k_gnapply<<<8192, 256, 0, stream>>>(x, stats, gamma, beta, gn);
  k_wtrans<<<4096, 256, 0, stream>>>(wqkv, wout, wqkvT, woutT);
  k_qkv<<<1536, 256, 0, stream>>>(gn, wqkvT, bqkv, qb, kb, vT);
  k_attn<<<512, 512, 0, stream>>>(qb, kb, vT, ob);
  k_out<<<512, 256, 0, stream>>>(ob, woutT, bout, x, out);
}

// Round 5
// 186.099 us; speedup vs baseline: 1.5095x; 1.0034x over previous
//
#include <hip/hip_runtime.h>

// Problem constants: B=16, H=W=32 -> L=1024, C=512, G=32, nh=8, d=64
#define Bn 16
#define Ln 1024
#define Cn 512
#define Mn (Bn*Ln)     // 16384
#define N3n 1536

typedef unsigned short u16;
typedef __attribute__((ext_vector_type(8))) short short8;
typedef __attribute__((ext_vector_type(4))) float f32x4;

typedef const __attribute__((address_space(1))) void* gas_p;
typedef __attribute__((address_space(3))) void* las_p;

__device__ inline void gl_lds16(const void* g, void* l) {
  __builtin_amdgcn_global_load_lds((gas_p)g, (las_p)l, 16, 0, 0);
}

__device__ inline u16 f2bf(float f) {
  union { float f; unsigned u; } v; v.f = f;
  unsigned r = v.u + 0x7FFFu + ((v.u >> 16) & 1u);
  return (u16)(r >> 16);
}

__device__ inline f32x4 mfma16(short8 a, short8 b, f32x4 c) {
  return __builtin_amdgcn_mfma_f32_16x16x32_bf16(a, b, c, 0, 0, 0);
}

// ---------------- K1: GroupNorm stats (mean, rstd per (b,g)) ----------------
__global__ __launch_bounds__(256) void k_gnstats(const float* __restrict__ x,
                                                 float* __restrict__ stats) {
  int bid = blockIdx.x;            // b*32+g
  int b = bid >> 5, g = bid & 31;
  const float* base = x + (size_t)b * (Ln * Cn) + g * 16;
  int tid = threadIdx.x;
  float s1 = 0.f, s2 = 0.f;
  for (int i = 0; i < 16; ++i) {
    int s = i * 256 + tid;
    int l = s >> 2, cq = s & 3;
    float4 v = *(const float4*)(base + (size_t)l * Cn + cq * 4);
    s1 += v.x + v.y + v.z + v.w;
    s2 += v.x * v.x + v.y * v.y + v.z * v.z + v.w * v.w;
  }
  for (int off = 32; off > 0; off >>= 1) {
    s1 += __shfl_down(s1, off);
    s2 += __shfl_down(s2, off);
  }
  __shared__ float rb[8];
  int w = tid >> 6, lane = tid & 63;
  if (lane == 0) { rb[w] = s1; rb[4 + w] = s2; }
  __syncthreads();
  if (tid == 0) {
    float a = rb[0] + rb[1] + rb[2] + rb[3];
    float q = rb[4] + rb[5] + rb[6] + rb[7];
    float mean = a * (1.f / 16384.f);
    float var = q * (1.f / 16384.f) - mean * mean;
    stats[bid * 2] = mean;
    stats[bid * 2 + 1] = rsqrtf(var + 1e-5f);
  }
}

// ---------------- K2: GN apply + cast to bf16 ----------------
__global__ __launch_bounds__(256) void k_gnapply(const float* __restrict__ x,
                                                 const float* __restrict__ stats,
                                                 const float* __restrict__ gamma,
                                                 const float* __restrict__ beta,
                                                 u16* __restrict__ gn) {
  int idx = blockIdx.x * 256 + threadIdx.x;
  size_t e = (size_t)idx << 2;
  int m = (int)(e >> 9), c = (int)(e & 511);
  int b = m >> 10, g = c >> 4;
  float mean = stats[(b * 32 + g) * 2];
  float rstd = stats[(b * 32 + g) * 2 + 1];
  float4 xv = *(const float4*)(x + e);
  float4 gv = *(const float4*)(gamma + c);
  float4 bv = *(const float4*)(beta + c);
  ushort4 o;
  o.x = f2bf((xv.x - mean) * rstd * gv.x + bv.x);
  o.y = f2bf((xv.y - mean) * rstd * gv.y + bv.y);
  o.z = f2bf((xv.z - mean) * rstd * gv.z + bv.z);
  o.w = f2bf((xv.w - mean) * rstd * gv.w + bv.w);
  *(ushort4*)(gn + e) = o;
}

// ---------------- K3: transpose+cast weights to [N][K] bf16 ----------------
__global__ __launch_bounds__(256) void k_wtrans(const float* __restrict__ wqkv,
                                                const float* __restrict__ wout,
                                                u16* __restrict__ wqkvT,
                                                u16* __restrict__ woutT) {
  int id = blockIdx.x * 256 + threadIdx.x;
  if (id < Cn * N3n) {
    int k = id & 511, n = id >> 9;
    wqkvT[id] = f2bf(wqkv[(size_t)k * N3n + n]);
  } else {
    int id2 = id - Cn * N3n;
    int k = id2 & 511, n = id2 >> 9;
    woutT[id2] = f2bf(wout[(size_t)k * Cn + n]);
  }
}

// ---------------- K4: QKV GEMM, 2-phase dbuf pipeline -> q,k,vT bf16 ----------------
__global__ __launch_bounds__(256) void k_qkv(const u16* __restrict__ gn,
                                             const u16* __restrict__ wT,
                                             const float* __restrict__ bias,
                                             u16* __restrict__ qb,
                                             u16* __restrict__ kb,
                                             u16* __restrict__ vT) {
  __shared__ __attribute__((aligned(16))) u16 As[2 * 128 * 64];  // 32 KB dbuf
  __shared__ __attribute__((aligned(16))) u16 Bs[2 * 128 * 64];  // 32 KB dbuf
  // XCD-chunk swizzle: each XCD gets 192 consecutive work ids = 16 m-rows x 12 n
  int bid = blockIdx.x;
  int wg = (bid & 7) * 192 + (bid >> 3);
  int tn = wg % 12, tm = wg / 12;
  int m0 = tm * 128, n0 = tn * 128;
  int tid = threadIdx.x;
  int w = tid >> 6, lane = tid & 63, lr = lane & 15, lg = lane >> 4;
  int wr = w >> 1, wc = w & 1;
  const f32x4 fzero = {0.f, 0.f, 0.f, 0.f};
  f32x4 acc[4][4];
#pragma unroll
  for (int mi = 0; mi < 4; ++mi)
#pragma unroll
    for (int ni = 0; ni < 4; ++ni) acc[mi][ni] = fzero;

  int sr = tid >> 1, sc8 = tid & 1;     // 256 thr: 128 rows x 2 wave-chunks... (see below)
  // staging pattern (as before): s = i*256+tid -> r=s>>3, c=s&7; dest wave-chunked
  // prologue: stage kt=0 into buf 0
#pragma unroll
  for (int i = 0; i < 4; ++i) {
    int s = i * 256 + tid;
    int r = s >> 3, c = s & 7;
    gl_lds16(gn + ((size_t)(m0 + r) * 512 + ((c ^ (r & 7)) << 3)),
             (char*)As + ((s & ~63) << 4));
    gl_lds16(wT + ((size_t)(n0 + r) * 512 + ((c ^ (r & 7)) << 3)),
             (char*)Bs + ((s & ~63) << 4));
  }
  __syncthreads();

  for (int kt = 0; kt < 8; ++kt) {
    int cur = kt & 1;
    char* Asb = (char*)As + cur * 16384;
    char* Bsb = (char*)Bs + cur * 16384;
    if (kt < 7) {
      int nb = cur ^ 1, k0n = (kt + 1) * 64;
#pragma unroll
      for (int i = 0; i < 4; ++i) {
        int s = i * 256 + tid;
        int r = s >> 3, c = s & 7;
        gl_lds16(gn + ((size_t)(m0 + r) * 512 + k0n + ((c ^ (r & 7)) << 3)),
                 (char*)As + nb * 16384 + ((s & ~63) << 4));
        gl_lds16(wT + ((size_t)(n0 + r) * 512 + k0n + ((c ^ (r & 7)) << 3)),
                 (char*)Bs + nb * 16384 + ((s & ~63) << 4));
      }
    }
#pragma unroll
    for (int ks = 0; ks < 2; ++ks) {
      short8 af[4], bf[4];
#pragma unroll
      for (int mi = 0; mi < 4; ++mi) {
        int row = wr * 64 + mi * 16 + lr;
        int ck = ks * 4 + lg;
        af[mi] = *(const short8*)(Asb + row * 128 + ((ck ^ (lr & 7)) << 4));
      }
#pragma unroll
      for (int ni = 0; ni < 4; ++ni) {
        int row = wc * 64 + ni * 16 + lr;
        int ck = ks * 4 + lg;
        bf[ni] = *(const short8*)(Bsb + row * 128 + ((ck ^ (lr & 7)) << 4));
      }
#pragma unroll
      for (int mi = 0; mi < 4; ++mi)
#pragma unroll
        for (int ni = 0; ni < 4; ++ni)
          acc[mi][ni] = mfma16(af[mi], bf[ni], acc[mi][ni]);
    }
    __syncthreads();
  }
  // epilogue: scatter into q [BH][L][64], k [BH][L][64], vT [BH][64][L]
#pragma unroll
  for (int mi = 0; mi < 4; ++mi) {
#pragma unroll
    for (int ni = 0; ni < 4; ++ni) {
      int n = n0 + wc * 64 + ni * 16 + lr;
      float bn = bias[n];
      int which = n >> 9, nn = n & 511;
      int h = nn >> 6, dd = nn & 63;
#pragma unroll
      for (int rr = 0; rr < 4; ++rr) {
        int m = m0 + wr * 64 + mi * 16 + lg * 4 + rr;
        float v = acc[mi][ni][rr] + bn;
        int bb = m >> 10, li = m & 1023;
        if (which == 0)
          qb[((size_t)(bb * 8 + h) * 1024 + li) * 64 + dd] = f2bf(v);
        else if (which == 1)
          kb[((size_t)(bb * 8 + h) * 1024 + li) * 64 + dd] = f2bf(v);
        else
          vT[((size_t)(bb * 8 + h) * 64 + dd) * 1024 + li] = f2bf(v);
      }
    }
  }
}

// ---------------- K5: flash attention, 8-wave block, LDS-shared K/V, 2-phase pipeline ----------------
__global__ __launch_bounds__(512, 4) void k_attn(const u16* __restrict__ qb,
                                                 const u16* __restrict__ kb,
                                                 const u16* __restrict__ vT,
                                                 u16* __restrict__ ob) {
  __shared__ __attribute__((aligned(16))) u16 Ks[2 * 64 * 64];  // 16 KB dbuf
  __shared__ __attribute__((aligned(16))) u16 Vs[2 * 64 * 64];  // 16 KB dbuf
  __shared__ __attribute__((aligned(16))) u16 Ps[8 * 32 * 64];  // 32 KB per-wave P
  int bid = blockIdx.x;
  // XCD-bijective swizzle: all 4 q-tiles of a head keep bid%8 constant
  int xq = bid & 7, kk = bid >> 3;              // bid in [0,512)
  int bh = ((kk & 15) << 3) | xq;               // [0,128)
  int qt = kk >> 4;                             // [0,4)
  const u16* qh = qb + (size_t)bh * 65536;
  const u16* kh = kb + (size_t)bh * 65536;
  const u16* vh = vT + (size_t)bh * 65536;
  int tid = threadIdx.x, w = tid >> 6, lane = tid & 63, lr = lane & 15, lg = lane >> 4;
  int q0 = qt * 256 + w * 32;
  const f32x4 fzero = {0.f, 0.f, 0.f, 0.f};

  // Q fragments (B-operand of swapped QK^T): lane holds col q=lr, d-slice lg*8
  short8 qf[2][2];
#pragma unroll
  for (int mi = 0; mi < 2; ++mi)
#pragma unroll
    for (int ks = 0; ks < 2; ++ks)
      qf[mi][ks] = *(const short8*)(qh + (size_t)(q0 + mi * 16 + lr) * 64 +
                                    ks * 32 + lg * 8);
  f32x4 accO[2][4];
  float mst[2], lst[2];
#pragma unroll
  for (int mi = 0; mi < 2; ++mi) {
#pragma unroll
    for (int nd = 0; nd < 4; ++nd) accO[mi][nd] = fzero;
    mst[mi] = -1e30f; lst[mi] = 0.f;
  }
  char* Pwb = (char*)(Ps + w * 2048);   // 32 rows x 128 B per wave

  int sr = tid >> 3, sc8 = tid & 7;     // staging: row, 16B-chunk (512 thr = 64x8)
  size_t koff = (size_t)sr * 64 + ((sc8 ^ (sr & 7)) << 3);
  size_t voff = (size_t)sr * 1024 + ((sc8 ^ (sr & 7)) << 3);
  int ldst = (tid & ~63) << 4;          // wave-uniform LDS dest base

  // prologue: stage tile 0 into buf 0
  gl_lds16(kh + koff, (char*)Ks + ldst);
  gl_lds16(vh + voff, (char*)Vs + ldst);
  __syncthreads();

#pragma unroll 1
  for (int jt = 0; jt < 16; ++jt) {
    int cur = jt & 1;
    char* Ksb = (char*)Ks + cur * 8192;
    char* Vsb = (char*)Vs + cur * 8192;
    // stage next tile into the other buffer (issued before compute)
    if (jt < 15) {
      int nb = cur ^ 1;
      gl_lds16(kh + (size_t)(jt + 1) * 64 * 64 + koff, (char*)Ks + nb * 8192 + ldst);
      gl_lds16(vh + (size_t)(jt + 1) * 64 + voff, (char*)Vs + nb * 8192 + ldst);
    }

    // K fragments (A-operand): row = k-pos, from LDS
    short8 kf[4][2];
#pragma unroll
    for (int nj = 0; nj < 4; ++nj)
#pragma unroll
      for (int ks = 0; ks < 2; ++ks) {
        int row = nj * 16 + lr;
        kf[nj][ks] = *(const short8*)(Ksb + row * 128 + (((ks * 4 + lg) ^ (row & 7)) << 4));
      }

    // S^T = K Q^T: sc[mi][nj] has col=q(lr), row=k(nj*16+lg*4+rr)
    f32x4 sc[2][4];
#pragma unroll
    for (int mi = 0; mi < 2; ++mi)
#pragma unroll
      for (int nj = 0; nj < 4; ++nj) sc[mi][nj] = fzero;
#pragma unroll
    for (int ks = 0; ks < 2; ++ks)
#pragma unroll
      for (int mi = 0; mi < 2; ++mi)
#pragma unroll
        for (int nj = 0; nj < 4; ++nj)
          sc[mi][nj] = mfma16(kf[nj][ks], qf[mi][ks], sc[mi][nj]);

    // online softmax: each lane holds 16 raw scores of q-row lr
#pragma unroll
    for (int mi = 0; mi < 2; ++mi) {
      float mloc = sc[mi][0][0];
#pragma unroll
      for (int nj = 0; nj < 4; ++nj)
#pragma unroll
        for (int rr = 0; rr < 4; ++rr) mloc = fmaxf(mloc, sc[mi][nj][rr]);
      mloc = fmaxf(mloc, __shfl_xor(mloc, 16));
      mloc = fmaxf(mloc, __shfl_xor(mloc, 32));
      float mn = fmaxf(mst[mi], mloc);
      float al = __expf((mst[mi] - mn) * 0.125f);
      mst[mi] = mn;
      float nm = -mn * 0.125f;
      float rs = 0.f;
#pragma unroll
      for (int nj = 0; nj < 4; ++nj)
#pragma unroll
        for (int rr = 0; rr < 4; ++rr) {
          float p = __expf(__builtin_fmaf(sc[mi][nj][rr], 0.125f, nm));
          sc[mi][nj][rr] = p;
          rs += p;
        }
      rs += __shfl_xor(rs, 16);
      rs += __shfl_xor(rs, 32);
      lst[mi] = lst[mi] * al + rs;

      // broadcast al (lr-indexed) to accO rows (lg*4+rr-indexed), rescale O
#pragma unroll
      for (int rr = 0; rr < 4; ++rr) {
        float ab = __shfl(al, (lane & 48) | ((lane >> 4) & 3) * 4 + rr);
#pragma unroll
        for (int nd = 0; nd < 4; ++nd) accO[mi][nd][rr] *= ab;
      }

      // pack 4 consecutive-k bf16 and write P[q][k] row as ds_write_b64
#pragma unroll
      for (int nj = 0; nj < 4; ++nj) {
        unsigned p01 = (unsigned)f2bf(sc[mi][nj][0]) | ((unsigned)f2bf(sc[mi][nj][1]) << 16);
        unsigned p23 = (unsigned)f2bf(sc[mi][nj][2]) | ((unsigned)f2bf(sc[mi][nj][3]) << 16);
        int row = mi * 16 + lr;
        int byte = row * 128 + (nj * 16 + lg * 4) * 2;
        byte ^= (row & 7) << 4;
        uint2 pv; pv.x = p01; pv.y = p23;
        *(uint2*)(Pwb + byte) = pv;
      }
    }

    // V fragments (B-operand of PV) from LDS
    short8 bv[4][2];
#pragma unroll
    for (int nd = 0; nd < 4; ++nd)
#pragma unroll
      for (int ks = 0; ks < 2; ++ks) {
        int row = nd * 16 + lr;
        bv[nd][ks] = *(const short8*)(Vsb + row * 128 + (((ks * 4 + lg) ^ (row & 7)) << 4));
      }

    // O += P @ V : A-fragment of P from LDS (XOR-swizzled b128)
    short8 ap[2][2];
#pragma unroll
    for (int mi = 0; mi < 2; ++mi)
#pragma unroll
      for (int ks = 0; ks < 2; ++ks) {
        int row = mi * 16 + lr;
        int byte = row * 128 + (ks * 32 + lg * 8) * 2;
        byte ^= (row & 7) << 4;
        ap[mi][ks] = *(const short8*)(Pwb + byte);
      }
#pragma unroll
    for (int ks = 0; ks < 2; ++ks)
#pragma unroll
      for (int mi = 0; mi < 2; ++mi)
#pragma unroll
        for (int nd = 0; nd < 4; ++nd)
          accO[mi][nd] = mfma16(ap[mi][ks], bv[nd][ks], accO[mi][nd]);

    // publish: own staged loads landed (syncthreads drains vmcnt) + all waves done with cur
    __syncthreads();
  }

  // epilogue: O /= l (broadcast 1/lst from lr-lanes to accO rows), write bf16
  int b = bh >> 3, h = bh & 7;
#pragma unroll
  for (int mi = 0; mi < 2; ++mi) {
    float il = 1.f / lst[mi];
#pragma unroll
    for (int rr = 0; rr < 4; ++rr) {
      float ib = __shfl(il, (lane & 48) | ((lane >> 4) & 3) * 4 + rr);
      int row = q0 + mi * 16 + lg * 4 + rr;
#pragma unroll
      for (int nd = 0; nd < 4; ++nd) {
        int col = h * 64 + nd * 16 + lr;
        ob[(size_t)(b * 1024 + row) * 512 + col] = f2bf(accO[mi][nd][rr] * ib);
      }
    }
  }
}

// ---------------- K6: out-proj GEMM + bias + residual, 2-phase dbuf (fp32 out) ----------------
__global__ __launch_bounds__(256) void k_out(const u16* __restrict__ ob,
                                             const u16* __restrict__ wT,
                                             const float* __restrict__ bias,
                                             const float* __restrict__ x,
                                             float* __restrict__ out) {
  __shared__ __attribute__((aligned(16))) u16 As[2 * 128 * 64];
  __shared__ __attribute__((aligned(16))) u16 Bs[2 * 128 * 64];
  // XCD-chunk swizzle: each XCD gets 64 consecutive work ids = 16 m-rows x 4 n
  int bid = blockIdx.x;
  int wg = (bid & 7) * 64 + (bid >> 3);
  int tn = wg & 3, tm = wg >> 2;
  int m0 = tm * 128, n0 = tn * 128;
  int tid = threadIdx.x;
  int w = tid >> 6, lane = tid & 63, lr = lane & 15, lg = lane >> 4;
  int wr = w >> 1, wc = w & 1;
  const f32x4 fzero = {0.f, 0.f, 0.f, 0.f};
  f32x4 acc[4][4];
#pragma unroll
  for (int mi = 0; mi < 4; ++mi)
#pragma unroll
    for (int ni = 0; ni < 4; ++ni) acc[mi][ni] = fzero;

  // prologue: stage kt=0 into buf 0
#pragma unroll
  for (int i = 0; i < 4; ++i) {
    int s = i * 256 + tid;
    int r = s >> 3, c = s & 7;
    gl_lds16(ob + ((size_t)(m0 + r) * 512 + ((c ^ (r & 7)) << 3)),
             (char*)As + ((s & ~63) << 4));
    gl_lds16(wT + ((size_t)(n0 + r) * 512 + ((c ^ (r & 7)) << 3)),
             (char*)Bs + ((s & ~63) << 4));
  }
  __syncthreads();

  for (int kt = 0; kt < 8; ++kt) {
    int cur = kt & 1;
    char* Asb = (char*)As + cur * 16384;
    char* Bsb = (char*)Bs + cur * 16384;
    if (kt < 7) {
      int nb = cur ^ 1, k0n = (kt + 1) * 64;
#pragma unroll
      for (int i = 0; i < 4; ++i) {
        int s = i * 256 + tid;
        int r = s >> 3, c = s & 7;
        gl_lds16(ob + ((size_t)(m0 + r) * 512 + k0n + ((c ^ (r & 7)) << 3)),
                 (char*)As + nb * 16384 + ((s & ~63) << 4));
        gl_lds16(wT + ((size_t)(n0 + r) * 512 + k0n + ((c ^ (r & 7)) << 3)),
                 (char*)Bs + nb * 16384 + ((s & ~63) << 4));
      }
    }
#pragma unroll
    for (int ks = 0; ks < 2; ++ks) {
      short8 af[4], bf[4];
#pragma unroll
      for (int mi = 0; mi < 4; ++mi) {
        int row = wr * 64 + mi * 16 + lr;
        int ck = ks * 4 + lg;
        af[mi] = *(const short8*)(Asb + row * 128 + ((ck ^ (lr & 7)) << 4));
      }
#pragma unroll
      for (int ni = 0; ni < 4; ++ni) {
        int row = wc * 64 + ni * 16 + lr;
        int ck = ks * 4 + lg;
        bf[ni] = *(const short8*)(Bsb + row * 128 + ((ck ^ (lr & 7)) << 4));
      }
#pragma unroll
      for (int mi = 0; mi < 4; ++mi)
#pragma unroll
        for (int ni = 0; ni < 4; ++ni)
          acc[mi][ni] = mfma16(af[mi], bf[ni], acc[mi][ni]);
    }
    __syncthreads();
  }
#pragma unroll
  for (int mi = 0; mi < 4; ++mi) {
#pragma unroll
    for (int ni = 0; ni < 4; ++ni) {
      int n = n0 + wc * 64 + ni * 16 + lr;
      float bn = bias[n];
#pragma unroll
      for (int rr = 0; rr < 4; ++rr) {
        int m = m0 + wr * 64 + mi * 16 + lg * 4 + rr;
        size_t off = (size_t)m * 512 + n;
        out[off] = x[off] + acc[mi][ni][rr] + bn;
      }
    }
  }
}

extern "C" void kernel_launch(void* const* d_in, const int* in_sizes, int n_in,
                              void* d_out, int out_size, void* d_ws, size_t ws_size,
                              hipStream_t stream) {
  const float* x = (const float*)d_in[0];
  // d_in[1] = timesteps (unused by the reference computation)
  const float* gamma = (const float*)d_in[2];
  const float* beta = (const float*)d_in[3];
  const float* wqkv = (const float*)d_in[4];
  const float* bqkv = (const float*)d_in[5];
  const float* wout = (const float*)d_in[6];
  const float* bout = (const float*)d_in[7];
  float* out = (float*)d_out;

  char* ws = (char*)d_ws;
  float* stats = (float*)ws;                                   //   4096 B
  u16* gn = (u16*)(ws + 4096);                                 // 16 MB  [M][512]
  u16* wqkvT = (u16*)(ws + 4096 + 16777216);                   // 1.5 MB [1536][512]
  u16* woutT = (u16*)(ws + 4096 + 16777216 + 1572864);         // 0.5 MB [512][512]
  u16* qb = (u16*)(ws + 4096 + 16777216 + 1572864 + 524288);   // 16 MB  [BH][L][64]
  u16* kb = qb + 8388608;                                      // 16 MB  [BH][L][64]
  u16* vT = kb + 8388608;                                      // 16 MB  [BH][64][L]
  u16* ob = vT + 8388608;                                      // 16 MB  [M][512]

  k_gnstats<<<512, 256, 0, stream>>>(x, stats);
  k_gnapply<<<8192, 256, 0, stream>>>(x, stats, gamma, beta, gn);
  k_wtrans<<<4096, 256, 0, stream>>>(wqkv, wout, wqkvT, woutT);
  k_qkv<<<1536, 256, 0, stream>>>(gn, wqkvT, bqkv, qb, kb, vT);
  k_attn<<<512, 512, 0, stream>>>(qb, kb, vT, ob);
  k_out<<<512, 256, 0, stream>>>(ob, woutT, bout, x, out);
}

// Round 7
// 151.242 us; speedup vs baseline: 1.8574x; 1.2305x over previous
//
#include <hip/hip_runtime.h>

// Problem constants: B=16, H=W=32 -> L=1024, C=512, G=32, nh=8, d=64
#define Bn 16
#define Ln 1024
#define Cn 512
#define Mn (Bn*Ln)     // 16384
#define N3n 1536

typedef unsigned short u16;
typedef __attribute__((ext_vector_type(8))) short short8;
typedef __attribute__((ext_vector_type(4))) float f32x4;

typedef const __attribute__((address_space(1))) void* gas_p;
typedef __attribute__((address_space(3))) void* las_p;

__device__ inline void gl_lds16(const void* g, void* l) {
  __builtin_amdgcn_global_load_lds((gas_p)g, (las_p)l, 16, 0, 0);
}

__device__ inline u16 f2bf(float f) {
  union { float f; unsigned u; } v; v.f = f;
  unsigned r = v.u + 0x7FFFu + ((v.u >> 16) & 1u);
  return (u16)(r >> 16);
}

__device__ inline f32x4 mfma16(short8 a, short8 b, f32x4 c) {
  return __builtin_amdgcn_mfma_f32_16x16x32_bf16(a, b, c, 0, 0, 0);
}

// ---------------- K1: GroupNorm stats (mean, rstd per (b,g)) ----------------
__global__ __launch_bounds__(256) void k_gnstats(const float* __restrict__ x,
                                                 float* __restrict__ stats) {
  int bid = blockIdx.x;            // b*32+g
  int b = bid >> 5, g = bid & 31;
  const float* base = x + (size_t)b * (Ln * Cn) + g * 16;
  int tid = threadIdx.x;
  float s1 = 0.f, s2 = 0.f;
  for (int i = 0; i < 16; ++i) {
    int s = i * 256 + tid;
    int l = s >> 2, cq = s & 3;
    float4 v = *(const float4*)(base + (size_t)l * Cn + cq * 4);
    s1 += v.x + v.y + v.z + v.w;
    s2 += v.x * v.x + v.y * v.y + v.z * v.z + v.w * v.w;
  }
  for (int off = 32; off > 0; off >>= 1) {
    s1 += __shfl_down(s1, off);
    s2 += __shfl_down(s2, off);
  }
  __shared__ float rb[8];
  int w = tid >> 6, lane = tid & 63;
  if (lane == 0) { rb[w] = s1; rb[4 + w] = s2; }
  __syncthreads();
  if (tid == 0) {
    float a = rb[0] + rb[1] + rb[2] + rb[3];
    float q = rb[4] + rb[5] + rb[6] + rb[7];
    float mean = a * (1.f / 16384.f);
    float var = q * (1.f / 16384.f) - mean * mean;
    stats[bid * 2] = mean;
    stats[bid * 2 + 1] = rsqrtf(var + 1e-5f);
  }
}

// ---------------- K2: GN apply + cast to bf16 ----------------
__global__ __launch_bounds__(256) void k_gnapply(const float* __restrict__ x,
                                                 const float* __restrict__ stats,
                                                 const float* __restrict__ gamma,
                                                 const float* __restrict__ beta,
                                                 u16* __restrict__ gn) {
  int idx = blockIdx.x * 256 + threadIdx.x;
  size_t e = (size_t)idx << 2;
  int m = (int)(e >> 9), c = (int)(e & 511);
  int b = m >> 10, g = c >> 4;
  float mean = stats[(b * 32 + g) * 2];
  float rstd = stats[(b * 32 + g) * 2 + 1];
  float4 xv = *(const float4*)(x + e);
  float4 gv = *(const float4*)(gamma + c);
  float4 bv = *(const float4*)(beta + c);
  ushort4 o;
  o.x = f2bf((xv.x - mean) * rstd * gv.x + bv.x);
  o.y = f2bf((xv.y - mean) * rstd * gv.y + bv.y);
  o.z = f2bf((xv.z - mean) * rstd * gv.z + bv.z);
  o.w = f2bf((xv.w - mean) * rstd * gv.w + bv.w);
  *(ushort4*)(gn + e) = o;
}

// ---------------- K3: transpose+cast weights to [N][K] bf16 ----------------
__global__ __launch_bounds__(256) void k_wtrans(const float* __restrict__ wqkv,
                                                const float* __restrict__ wout,
                                                u16* __restrict__ wqkvT,
                                                u16* __restrict__ woutT) {
  int id = blockIdx.x * 256 + threadIdx.x;
  if (id < Cn * N3n) {
    int k = id & 511, n = id >> 9;
    wqkvT[id] = f2bf(wqkv[(size_t)k * N3n + n]);
  } else {
    int id2 = id - Cn * N3n;
    int k = id2 & 511, n = id2 >> 9;
    woutT[id2] = f2bf(wout[(size_t)k * Cn + n]);
  }
}

// ---------------- K4: QKV GEMM, 2-phase dbuf + LDS-transposed vT epilogue ----------------
__global__ __launch_bounds__(256) void k_qkv(const u16* __restrict__ gn,
                                             const u16* __restrict__ wT,
                                             const float* __restrict__ bias,
                                             u16* __restrict__ qb,
                                             u16* __restrict__ kb,
                                             u16* __restrict__ vT) {
  // staging: A dbuf 32 KB @0, B dbuf 32 KB @32768; v-epilogue reuses as f32 [128][130]
  __shared__ __attribute__((aligned(16))) char smem[66560];
  // XCD-chunk swizzle: each XCD gets 192 consecutive work ids
  int bid = blockIdx.x;
  int wg = (bid & 7) * 192 + (bid >> 3);
  int tn = wg % 12, tm = wg / 12;
  int m0 = tm * 128, n0 = tn * 128;
  int tid = threadIdx.x;
  int w = tid >> 6, lane = tid & 63, lr = lane & 15, lg = lane >> 4;
  int wr = w >> 1, wc = w & 1;
  const f32x4 fzero = {0.f, 0.f, 0.f, 0.f};
  f32x4 acc[4][4];
#pragma unroll
  for (int mi = 0; mi < 4; ++mi)
#pragma unroll
    for (int ni = 0; ni < 4; ++ni) acc[mi][ni] = fzero;

  // prologue: stage kt=0 into buf 0
#pragma unroll
  for (int i = 0; i < 4; ++i) {
    int s = i * 256 + tid;
    int r = s >> 3, c = s & 7;
    gl_lds16(gn + ((size_t)(m0 + r) * 512 + ((c ^ (r & 7)) << 3)),
             smem + ((s & ~63) << 4));
    gl_lds16(wT + ((size_t)(n0 + r) * 512 + ((c ^ (r & 7)) << 3)),
             smem + 32768 + ((s & ~63) << 4));
  }
  __syncthreads();

  for (int kt = 0; kt < 8; ++kt) {
    int cur = kt & 1;
    char* Asb = smem + cur * 16384;
    char* Bsb = smem + 32768 + cur * 16384;
    if (kt < 7) {
      int nb = cur ^ 1, k0n = (kt + 1) * 64;
#pragma unroll
      for (int i = 0; i < 4; ++i) {
        int s = i * 256 + tid;
        int r = s >> 3, c = s & 7;
        gl_lds16(gn + ((size_t)(m0 + r) * 512 + k0n + ((c ^ (r & 7)) << 3)),
                 smem + nb * 16384 + ((s & ~63) << 4));
        gl_lds16(wT + ((size_t)(n0 + r) * 512 + k0n + ((c ^ (r & 7)) << 3)),
                 smem + 32768 + nb * 16384 + ((s & ~63) << 4));
      }
    }
#pragma unroll
    for (int ks = 0; ks < 2; ++ks) {
      short8 af[4], bf[4];
#pragma unroll
      for (int mi = 0; mi < 4; ++mi) {
        int row = wr * 64 + mi * 16 + lr;
        int ck = ks * 4 + lg;
        af[mi] = *(const short8*)(Asb + row * 128 + ((ck ^ (lr & 7)) << 4));
      }
#pragma unroll
      for (int ni = 0; ni < 4; ++ni) {
        int row = wc * 64 + ni * 16 + lr;
        int ck = ks * 4 + lg;
        bf[ni] = *(const short8*)(Bsb + row * 128 + ((ck ^ (lr & 7)) << 4));
      }
#pragma unroll
      for (int mi = 0; mi < 4; ++mi)
#pragma unroll
        for (int ni = 0; ni < 4; ++ni)
          acc[mi][ni] = mfma16(af[mi], bf[ni], acc[mi][ni]);
    }
    __syncthreads();
  }

  if (tn >= 8) {
    // ---- v-block epilogue: transpose via LDS, coalesced dwordx4 stores ----
    float* T = (float*)smem;  // [128 n_local][130]
#pragma unroll
    for (int mi = 0; mi < 4; ++mi)
#pragma unroll
      for (int ni = 0; ni < 4; ++ni) {
        int n_l = wc * 64 + ni * 16 + lr;
        float bn = bias[n0 + n_l];
#pragma unroll
        for (int rr = 0; rr < 4; ++rr) {
          int m_l = wr * 64 + mi * 16 + lg * 4 + rr;
          T[n_l * 130 + m_l] = acc[mi][ni][rr] + bn;
        }
      }
    __syncthreads();
    int n_l = tid >> 1, half = tid & 1;
    int nv = n0 - 1024 + n_l;
    int h = nv >> 6, dd = nv & 63;
    int bb = m0 >> 10, li0 = m0 & 1023;
    u16* dst = vT + ((size_t)(bb * 8 + h) * 64 + dd) * 1024 + li0;
    const float* Tr = T + n_l * 130;
#pragma unroll
    for (int j = 0; j < 8; ++j) {       // 8 chunks x 8 elems = full 128 m per row
      int mb = half * 8 + 16 * j;       // 8 consecutive li; lane pairs form 32B runs
      uint4 o;
      o.x = (unsigned)f2bf(Tr[mb + 0]) | ((unsigned)f2bf(Tr[mb + 1]) << 16);
      o.y = (unsigned)f2bf(Tr[mb + 2]) | ((unsigned)f2bf(Tr[mb + 3]) << 16);
      o.z = (unsigned)f2bf(Tr[mb + 4]) | ((unsigned)f2bf(Tr[mb + 5]) << 16);
      o.w = (unsigned)f2bf(Tr[mb + 6]) | ((unsigned)f2bf(Tr[mb + 7]) << 16);
      *(uint4*)(dst + mb) = o;
    }
  } else {
    // ---- q/k epilogue: direct stores (32B segments) ----
#pragma unroll
    for (int mi = 0; mi < 4; ++mi) {
#pragma unroll
      for (int ni = 0; ni < 4; ++ni) {
        int n = n0 + wc * 64 + ni * 16 + lr;
        float bn = bias[n];
        int which = n >> 9, nn = n & 511;
        int h = nn >> 6, dd = nn & 63;
#pragma unroll
        for (int rr = 0; rr < 4; ++rr) {
          int m = m0 + wr * 64 + mi * 16 + lg * 4 + rr;
          float v = acc[mi][ni][rr] + bn;
          int bb = m >> 10, li = m & 1023;
          if (which == 0)
            qb[((size_t)(bb * 8 + h) * 1024 + li) * 64 + dd] = f2bf(v);
          else
            kb[((size_t)(bb * 8 + h) * 1024 + li) * 64 + dd] = f2bf(v);
        }
      }
    }
  }
}

// ---------------- K5: flash attention, 8-wave block, LDS-shared K/V, 2-phase pipeline ----------------
__global__ __launch_bounds__(512, 4) void k_attn(const u16* __restrict__ qb,
                                                 const u16* __restrict__ kb,
                                                 const u16* __restrict__ vT,
                                                 u16* __restrict__ ob) {
  __shared__ __attribute__((aligned(16))) u16 Ks[2 * 64 * 64];  // 16 KB dbuf
  __shared__ __attribute__((aligned(16))) u16 Vs[2 * 64 * 64];  // 16 KB dbuf
  __shared__ __attribute__((aligned(16))) u16 Ps[8 * 32 * 64];  // 32 KB per-wave P
  int bid = blockIdx.x;
  // XCD-bijective swizzle: all 4 q-tiles of a head keep bid%8 constant
  int xq = bid & 7, kk = bid >> 3;              // bid in [0,512)
  int bh = ((kk & 15) << 3) | xq;               // [0,128)
  int qt = kk >> 4;                             // [0,4)
  const u16* qh = qb + (size_t)bh * 65536;
  const u16* kh = kb + (size_t)bh * 65536;
  const u16* vh = vT + (size_t)bh * 65536;
  int tid = threadIdx.x, w = tid >> 6, lane = tid & 63, lr = lane & 15, lg = lane >> 4;
  int q0 = qt * 256 + w * 32;
  const f32x4 fzero = {0.f, 0.f, 0.f, 0.f};

  // Q fragments (B-operand of swapped QK^T): lane holds col q=lr, d-slice lg*8
  short8 qf[2][2];
#pragma unroll
  for (int mi = 0; mi < 2; ++mi)
#pragma unroll
    for (int ks = 0; ks < 2; ++ks)
      qf[mi][ks] = *(const short8*)(qh + (size_t)(q0 + mi * 16 + lr) * 64 +
                                    ks * 32 + lg * 8);
  f32x4 accO[2][4];
  float mst[2], lst[2];
#pragma unroll
  for (int mi = 0; mi < 2; ++mi) {
#pragma unroll
    for (int nd = 0; nd < 4; ++nd) accO[mi][nd] = fzero;
    mst[mi] = -1e30f; lst[mi] = 0.f;
  }
  char* Pwb = (char*)(Ps + w * 2048);   // 32 rows x 128 B per wave

  int sr = tid >> 3, sc8 = tid & 7;     // staging: row, 16B-chunk (512 thr = 64x8)
  size_t koff = (size_t)sr * 64 + ((sc8 ^ (sr & 7)) << 3);
  size_t voff = (size_t)sr * 1024 + ((sc8 ^ (sr & 7)) << 3);
  int ldst = (tid & ~63) << 4;          // wave-uniform LDS dest base

  // prologue: stage tile 0 into buf 0
  gl_lds16(kh + koff, (char*)Ks + ldst);
  gl_lds16(vh + voff, (char*)Vs + ldst);
  __syncthreads();

#pragma unroll 1
  for (int jt = 0; jt < 16; ++jt) {
    int cur = jt & 1;
    char* Ksb = (char*)Ks + cur * 8192;
    char* Vsb = (char*)Vs + cur * 8192;
    // stage next tile into the other buffer (issued before compute)
    if (jt < 15) {
      int nb = cur ^ 1;
      gl_lds16(kh + (size_t)(jt + 1) * 64 * 64 + koff, (char*)Ks + nb * 8192 + ldst);
      gl_lds16(vh + (size_t)(jt + 1) * 64 + voff, (char*)Vs + nb * 8192 + ldst);
    }

    // K fragments (A-operand): row = k-pos, from LDS
    short8 kf[4][2];
#pragma unroll
    for (int nj = 0; nj < 4; ++nj)
#pragma unroll
      for (int ks = 0; ks < 2; ++ks) {
        int row = nj * 16 + lr;
        kf[nj][ks] = *(const short8*)(Ksb + row * 128 + (((ks * 4 + lg) ^ (row & 7)) << 4));
      }

    // S^T = K Q^T: sc[mi][nj] has col=q(lr), row=k(nj*16+lg*4+rr)
    f32x4 sc[2][4];
#pragma unroll
    for (int mi = 0; mi < 2; ++mi)
#pragma unroll
      for (int nj = 0; nj < 4; ++nj) sc[mi][nj] = fzero;
#pragma unroll
    for (int ks = 0; ks < 2; ++ks)
#pragma unroll
      for (int mi = 0; mi < 2; ++mi)
#pragma unroll
        for (int nj = 0; nj < 4; ++nj)
          sc[mi][nj] = mfma16(kf[nj][ks], qf[mi][ks], sc[mi][nj]);

    // online softmax: each lane holds 16 raw scores of q-row lr
#pragma unroll
    for (int mi = 0; mi < 2; ++mi) {
      float mloc = sc[mi][0][0];
#pragma unroll
      for (int nj = 0; nj < 4; ++nj)
#pragma unroll
        for (int rr = 0; rr < 4; ++rr) mloc = fmaxf(mloc, sc[mi][nj][rr]);
      mloc = fmaxf(mloc, __shfl_xor(mloc, 16));
      mloc = fmaxf(mloc, __shfl_xor(mloc, 32));
      float mn = fmaxf(mst[mi], mloc);
      float al = __expf((mst[mi] - mn) * 0.125f);
      mst[mi] = mn;
      float nm = -mn * 0.125f;
      float rs = 0.f;
#pragma unroll
      for (int nj = 0; nj < 4; ++nj)
#pragma unroll
        for (int rr = 0; rr < 4; ++rr) {
          float p = __expf(__builtin_fmaf(sc[mi][nj][rr], 0.125f, nm));
          sc[mi][nj][rr] = p;
          rs += p;
        }
      rs += __shfl_xor(rs, 16);
      rs += __shfl_xor(rs, 32);
      lst[mi] = lst[mi] * al + rs;

      // broadcast al (lr-indexed) to accO rows (lg*4+rr-indexed), rescale O
#pragma unroll
      for (int rr = 0; rr < 4; ++rr) {
        float ab = __shfl(al, (lane & 48) | ((lane >> 4) & 3) * 4 + rr);
#pragma unroll
        for (int nd = 0; nd < 4; ++nd) accO[mi][nd][rr] *= ab;
      }

      // pack 4 consecutive-k bf16 and write P[q][k] row as ds_write_b64
#pragma unroll
      for (int nj = 0; nj < 4; ++nj) {
        unsigned p01 = (unsigned)f2bf(sc[mi][nj][0]) | ((unsigned)f2bf(sc[mi][nj][1]) << 16);
        unsigned p23 = (unsigned)f2bf(sc[mi][nj][2]) | ((unsigned)f2bf(sc[mi][nj][3]) << 16);
        int row = mi * 16 + lr;
        int byte = row * 128 + (nj * 16 + lg * 4) * 2;
        byte ^= (row & 7) << 4;
        uint2 pv; pv.x = p01; pv.y = p23;
        *(uint2*)(Pwb + byte) = pv;
      }
    }

    // V fragments (B-operand of PV) from LDS
    short8 bv[4][2];
#pragma unroll
    for (int nd = 0; nd < 4; ++nd)
#pragma unroll
      for (int ks = 0; ks < 2; ++ks) {
        int row = nd * 16 + lr;
        bv[nd][ks] = *(const short8*)(Vsb + row * 128 + (((ks * 4 + lg) ^ (row & 7)) << 4));
      }

    // O += P @ V : A-fragment of P from LDS (XOR-swizzled b128)
    short8 ap[2][2];
#pragma unroll
    for (int mi = 0; mi < 2; ++mi)
#pragma unroll
      for (int ks = 0; ks < 2; ++ks) {
        int row = mi * 16 + lr;
        int byte = row * 128 + (ks * 32 + lg * 8) * 2;
        byte ^= (row & 7) << 4;
        ap[mi][ks] = *(const short8*)(Pwb + byte);
      }
#pragma unroll
    for (int ks = 0; ks < 2; ++ks)
#pragma unroll
      for (int mi = 0; mi < 2; ++mi)
#pragma unroll
        for (int nd = 0; nd < 4; ++nd)
          accO[mi][nd] = mfma16(ap[mi][ks], bv[nd][ks], accO[mi][nd]);

    // publish: own staged loads landed (syncthreads drains vmcnt) + all waves done with cur
    __syncthreads();
  }

  // epilogue: O /= l (broadcast 1/lst from lr-lanes to accO rows), write bf16
  int b = bh >> 3, h = bh & 7;
#pragma unroll
  for (int mi = 0; mi < 2; ++mi) {
    float il = 1.f / lst[mi];
#pragma unroll
    for (int rr = 0; rr < 4; ++rr) {
      float ib = __shfl(il, (lane & 48) | ((lane >> 4) & 3) * 4 + rr);
      int row = q0 + mi * 16 + lg * 4 + rr;
#pragma unroll
      for (int nd = 0; nd < 4; ++nd) {
        int col = h * 64 + nd * 16 + lr;
        ob[(size_t)(b * 1024 + row) * 512 + col] = f2bf(accO[mi][nd][rr] * ib);
      }
    }
  }
}

// ---------------- K6: out-proj GEMM + bias + residual, 2-phase dbuf (fp32 out) ----------------
__global__ __launch_bounds__(256) void k_out(const u16* __restrict__ ob,
                                             const u16* __restrict__ wT,
                                             const float* __restrict__ bias,
                                             const float* __restrict__ x,
                                             float* __restrict__ out) {
  __shared__ __attribute__((aligned(16))) u16 As[2 * 128 * 64];
  __shared__ __attribute__((aligned(16))) u16 Bs[2 * 128 * 64];
  // XCD-chunk swizzle: each XCD gets 64 consecutive work ids = 16 m-rows x 4 n
  int bid = blockIdx.x;
  int wg = (bid & 7) * 64 + (bid >> 3);
  int tn = wg & 3, tm = wg >> 2;
  int m0 = tm * 128, n0 = tn * 128;
  int tid = threadIdx.x;
  int w = tid >> 6, lane = tid & 63, lr = lane & 15, lg = lane >> 4;
  int wr = w >> 1, wc = w & 1;
  const f32x4 fzero = {0.f, 0.f, 0.f, 0.f};
  f32x4 acc[4][4];
#pragma unroll
  for (int mi = 0; mi < 4; ++mi)
#pragma unroll
    for (int ni = 0; ni < 4; ++ni) acc[mi][ni] = fzero;

  // prologue: stage kt=0 into buf 0
#pragma unroll
  for (int i = 0; i < 4; ++i) {
    int s = i * 256 + tid;
    int r = s >> 3, c = s & 7;
    gl_lds16(ob + ((size_t)(m0 + r) * 512 + ((c ^ (r & 7)) << 3)),
             (char*)As + ((s & ~63) << 4));
    gl_lds16(wT + ((size_t)(n0 + r) * 512 + ((c ^ (r & 7)) << 3)),
             (char*)Bs + ((s & ~63) << 4));
  }
  __syncthreads();

  for (int kt = 0; kt < 8; ++kt) {
    int cur = kt & 1;
    char* Asb = (char*)As + cur * 16384;
    char* Bsb = (char*)Bs + cur * 16384;
    if (kt < 7) {
      int nb = cur ^ 1, k0n = (kt + 1) * 64;
#pragma unroll
      for (int i = 0; i < 4; ++i) {
        int s = i * 256 + tid;
        int r = s >> 3, c = s & 7;
        gl_lds16(ob + ((size_t)(m0 + r) * 512 + k0n + ((c ^ (r & 7)) << 3)),
                 (char*)As + nb * 16384 + ((s & ~63) << 4));
        gl_lds16(wT + ((size_t)(n0 + r) * 512 + k0n + ((c ^ (r & 7)) << 3)),
                 (char*)Bs + nb * 16384 + ((s & ~63) << 4));
      }
    }
#pragma unroll
    for (int ks = 0; ks < 2; ++ks) {
      short8 af[4], bf[4];
#pragma unroll
      for (int mi = 0; mi < 4; ++mi) {
        int row = wr * 64 + mi * 16 + lr;
        int ck = ks * 4 + lg;
        af[mi] = *(const short8*)(Asb + row * 128 + ((ck ^ (lr & 7)) << 4));
      }
#pragma unroll
      for (int ni = 0; ni < 4; ++ni) {
        int row = wc * 64 + ni * 16 + lr;
        int ck = ks * 4 + lg;
        bf[ni] = *(const short8*)(Bsb + row * 128 + ((ck ^ (lr & 7)) << 4));
      }
#pragma unroll
      for (int mi = 0; mi < 4; ++mi)
#pragma unroll
        for (int ni = 0; ni < 4; ++ni)
          acc[mi][ni] = mfma16(af[mi], bf[ni], acc[mi][ni]);
    }
    __syncthreads();
  }
#pragma unroll
  for (int mi = 0; mi < 4; ++mi) {
#pragma unroll
    for (int ni = 0; ni < 4; ++ni) {
      int n = n0 + wc * 64 + ni * 16 + lr;
      float bn = bias[n];
#pragma unroll
      for (int rr = 0; rr < 4; ++rr) {
        int m = m0 + wr * 64 + mi * 16 + lg * 4 + rr;
        size_t off = (size_t)m * 512 + n;
        out[off] = x[off] + acc[mi][ni][rr] + bn;
      }
    }
  }
}

extern "C" void kernel_launch(void* const* d_in, const int* in_sizes, int n_in,
                              void* d_out, int out_size, void* d_ws, size_t ws_size,
                              hipStream_t stream) {
  const float* x = (const float*)d_in[0];
  // d_in[1] = timesteps (unused by the reference computation)
  const float* gamma = (const float*)d_in[2];
  const float* beta = (const float*)d_in[3];
  const float* wqkv = (const float*)d_in[4];
  const float* bqkv = (const float*)d_in[5];
  const float* wout = (const float*)d_in[6];
  const float* bout = (const float*)d_in[7];
  float* out = (float*)d_out;

  char* ws = (char*)d_ws;
  float* stats = (float*)ws;                                   //   4096 B
  u16* gn = (u16*)(ws + 4096);                                 // 16 MB  [M][512]
  u16* wqkvT = (u16*)(ws + 4096 + 16777216);                   // 1.5 MB [1536][512]
  u16* woutT = (u16*)(ws + 4096 + 16777216 + 1572864);         // 0.5 MB [512][512]
  u16* qb = (u16*)(ws + 4096 + 16777216 + 1572864 + 524288);   // 16 MB  [BH][L][64]
  u16* kb = qb + 8388608;                                      // 16 MB  [BH][L][64]
  u16* vT = kb + 8388608;                                      // 16 MB  [BH][64][L]
  u16* ob = vT + 8388608;                                      // 16 MB  [M][512]

  k_gnstats<<<512, 256, 0, stream>>>(x, stats);
  k_gnapply<<<8192, 256, 0, stream>>>(x, stats, gamma, beta, gn);
  k_wtrans<<<4096, 256, 0, stream>>>(wqkv, wout, wqkvT, woutT);
  k_qkv<<<1536, 256, 0, stream>>>(gn, wqkvT, bqkv, qb, kb, vT);
  k_attn<<<512, 512, 0, stream>>>(qb, kb, vT, ob);
  k_out<<<512, 256, 0, stream>>>(ob, woutT, bout, x, out);
}

// Round 9
// 150.159 us; speedup vs baseline: 1.8708x; 1.0072x over previous
//
#include <hip/hip_runtime.h>

// Problem constants: B=16, H=W=32 -> L=1024, C=512, G=32, nh=8, d=64
#define Bn 16
#define Ln 1024
#define Cn 512
#define Mn (Bn*Ln)     // 16384
#define N3n 1536

typedef unsigned short u16;
typedef __attribute__((ext_vector_type(8))) short short8;
typedef __attribute__((ext_vector_type(4))) float f32x4;

typedef const __attribute__((address_space(1))) void* gas_p;
typedef __attribute__((address_space(3))) void* las_p;

__device__ inline void gl_lds16(const void* g, void* l) {
  __builtin_amdgcn_global_load_lds((gas_p)g, (las_p)l, 16, 0, 0);
}

__device__ inline u16 f2bf(float f) {
  union { float f; unsigned u; } v; v.f = f;
  unsigned r = v.u + 0x7FFFu + ((v.u >> 16) & 1u);
  return (u16)(r >> 16);
}

__device__ inline f32x4 mfma16(short8 a, short8 b, f32x4 c) {
  return __builtin_amdgcn_mfma_f32_16x16x32_bf16(a, b, c, 0, 0, 0);
}

// ---------------- K1: GroupNorm stats (mean, rstd per (b,g)) ----------------
__global__ __launch_bounds__(256) void k_gnstats(const float* __restrict__ x,
                                                 float* __restrict__ stats) {
  int bid = blockIdx.x;            // b*32+g
  int b = bid >> 5, g = bid & 31;
  const float* base = x + (size_t)b * (Ln * Cn) + g * 16;
  int tid = threadIdx.x;
  float s1 = 0.f, s2 = 0.f;
  for (int i = 0; i < 16; ++i) {
    int s = i * 256 + tid;
    int l = s >> 2, cq = s & 3;
    float4 v = *(const float4*)(base + (size_t)l * Cn + cq * 4);
    s1 += v.x + v.y + v.z + v.w;
    s2 += v.x * v.x + v.y * v.y + v.z * v.z + v.w * v.w;
  }
  for (int off = 32; off > 0; off >>= 1) {
    s1 += __shfl_down(s1, off);
    s2 += __shfl_down(s2, off);
  }
  __shared__ float rb[8];
  int w = tid >> 6, lane = tid & 63;
  if (lane == 0) { rb[w] = s1; rb[4 + w] = s2; }
  __syncthreads();
  if (tid == 0) {
    float a = rb[0] + rb[1] + rb[2] + rb[3];
    float q = rb[4] + rb[5] + rb[6] + rb[7];
    float mean = a * (1.f / 16384.f);
    float var = q * (1.f / 16384.f) - mean * mean;
    stats[bid * 2] = mean;
    stats[bid * 2 + 1] = rsqrtf(var + 1e-5f);
  }
}

// ---------------- K2: GN apply + cast to bf16 ----------------
__global__ __launch_bounds__(256) void k_gnapply(const float* __restrict__ x,
                                                 const float* __restrict__ stats,
                                                 const float* __restrict__ gamma,
                                                 const float* __restrict__ beta,
                                                 u16* __restrict__ gn) {
  int idx = blockIdx.x * 256 + threadIdx.x;
  size_t e = (size_t)idx << 2;
  int m = (int)(e >> 9), c = (int)(e & 511);
  int b = m >> 10, g = c >> 4;
  float mean = stats[(b * 32 + g) * 2];
  float rstd = stats[(b * 32 + g) * 2 + 1];
  float4 xv = *(const float4*)(x + e);
  float4 gv = *(const float4*)(gamma + c);
  float4 bv = *(const float4*)(beta + c);
  ushort4 o;
  o.x = f2bf((xv.x - mean) * rstd * gv.x + bv.x);
  o.y = f2bf((xv.y - mean) * rstd * gv.y + bv.y);
  o.z = f2bf((xv.z - mean) * rstd * gv.z + bv.z);
  o.w = f2bf((xv.w - mean) * rstd * gv.w + bv.w);
  *(ushort4*)(gn + e) = o;
}

// ---------------- K3: transpose+cast weights to [N][K] bf16 ----------------
__global__ __launch_bounds__(256) void k_wtrans(const float* __restrict__ wqkv,
                                                const float* __restrict__ wout,
                                                u16* __restrict__ wqkvT,
                                                u16* __restrict__ woutT) {
  int id = blockIdx.x * 256 + threadIdx.x;
  if (id < Cn * N3n) {
    int k = id & 511, n = id >> 9;
    wqkvT[id] = f2bf(wqkv[(size_t)k * N3n + n]);
  } else {
    int id2 = id - Cn * N3n;
    int k = id2 & 511, n = id2 >> 9;
    woutT[id2] = f2bf(wout[(size_t)k * Cn + n]);
  }
}

// ---------------- K4: QKV GEMM, 2-phase dbuf + LDS-transposed vT epilogue ----------------
__global__ __launch_bounds__(256) void k_qkv(const u16* __restrict__ gn,
                                             const u16* __restrict__ wT,
                                             const float* __restrict__ bias,
                                             u16* __restrict__ qb,
                                             u16* __restrict__ kb,
                                             u16* __restrict__ vT) {
  // staging: A dbuf 32 KB @0, B dbuf 32 KB @32768; v-epilogue reuses as f32 [128][130]
  __shared__ __attribute__((aligned(16))) char smem[66560];
  // XCD-chunk swizzle: each XCD gets 192 consecutive work ids
  int bid = blockIdx.x;
  int wg = (bid & 7) * 192 + (bid >> 3);
  int tn = wg % 12, tm = wg / 12;
  int m0 = tm * 128, n0 = tn * 128;
  int tid = threadIdx.x;
  int w = tid >> 6, lane = tid & 63, lr = lane & 15, lg = lane >> 4;
  int wr = w >> 1, wc = w & 1;
  const f32x4 fzero = {0.f, 0.f, 0.f, 0.f};
  f32x4 acc[4][4];
#pragma unroll
  for (int mi = 0; mi < 4; ++mi)
#pragma unroll
    for (int ni = 0; ni < 4; ++ni) acc[mi][ni] = fzero;

  // prologue: stage kt=0 into buf 0
#pragma unroll
  for (int i = 0; i < 4; ++i) {
    int s = i * 256 + tid;
    int r = s >> 3, c = s & 7;
    gl_lds16(gn + ((size_t)(m0 + r) * 512 + ((c ^ (r & 7)) << 3)),
             smem + ((s & ~63) << 4));
    gl_lds16(wT + ((size_t)(n0 + r) * 512 + ((c ^ (r & 7)) << 3)),
             smem + 32768 + ((s & ~63) << 4));
  }
  __syncthreads();

  for (int kt = 0; kt < 8; ++kt) {
    int cur = kt & 1;
    char* Asb = smem + cur * 16384;
    char* Bsb = smem + 32768 + cur * 16384;
    if (kt < 7) {
      int nb = cur ^ 1, k0n = (kt + 1) * 64;
#pragma unroll
      for (int i = 0; i < 4; ++i) {
        int s = i * 256 + tid;
        int r = s >> 3, c = s & 7;
        gl_lds16(gn + ((size_t)(m0 + r) * 512 + k0n + ((c ^ (r & 7)) << 3)),
                 smem + nb * 16384 + ((s & ~63) << 4));
        gl_lds16(wT + ((size_t)(n0 + r) * 512 + k0n + ((c ^ (r & 7)) << 3)),
                 smem + 32768 + nb * 16384 + ((s & ~63) << 4));
      }
    }
#pragma unroll
    for (int ks = 0; ks < 2; ++ks) {
      short8 af[4], bf[4];
#pragma unroll
      for (int mi = 0; mi < 4; ++mi) {
        int row = wr * 64 + mi * 16 + lr;
        int ck = ks * 4 + lg;
        af[mi] = *(const short8*)(Asb + row * 128 + ((ck ^ (lr & 7)) << 4));
      }
#pragma unroll
      for (int ni = 0; ni < 4; ++ni) {
        int row = wc * 64 + ni * 16 + lr;
        int ck = ks * 4 + lg;
        bf[ni] = *(const short8*)(Bsb + row * 128 + ((ck ^ (lr & 7)) << 4));
      }
#pragma unroll
      for (int mi = 0; mi < 4; ++mi)
#pragma unroll
        for (int ni = 0; ni < 4; ++ni)
          acc[mi][ni] = mfma16(af[mi], bf[ni], acc[mi][ni]);
    }
    __syncthreads();
  }

  if (tn >= 8) {
    // ---- v-block epilogue: transpose via LDS, coalesced dwordx4 stores ----
    float* T = (float*)smem;  // [128 n_local][130]
#pragma unroll
    for (int mi = 0; mi < 4; ++mi)
#pragma unroll
      for (int ni = 0; ni < 4; ++ni) {
        int n_l = wc * 64 + ni * 16 + lr;
        float bn = bias[n0 + n_l];
#pragma unroll
        for (int rr = 0; rr < 4; ++rr) {
          int m_l = wr * 64 + mi * 16 + lg * 4 + rr;
          T[n_l * 130 + m_l] = acc[mi][ni][rr] + bn;
        }
      }
    __syncthreads();
    int n_l = tid >> 1, half = tid & 1;
    int nv = n0 - 1024 + n_l;
    int h = nv >> 6, dd = nv & 63;
    int bb = m0 >> 10, li0 = m0 & 1023;
    u16* dst = vT + ((size_t)(bb * 8 + h) * 64 + dd) * 1024 + li0;
    const float* Tr = T + n_l * 130;
#pragma unroll
    for (int j = 0; j < 8; ++j) {       // 8 chunks x 8 elems = full 128 m per row
      int mb = half * 8 + 16 * j;       // 8 consecutive li; lane pairs form 32B runs
      uint4 o;
      o.x = (unsigned)f2bf(Tr[mb + 0]) | ((unsigned)f2bf(Tr[mb + 1]) << 16);
      o.y = (unsigned)f2bf(Tr[mb + 2]) | ((unsigned)f2bf(Tr[mb + 3]) << 16);
      o.z = (unsigned)f2bf(Tr[mb + 4]) | ((unsigned)f2bf(Tr[mb + 5]) << 16);
      o.w = (unsigned)f2bf(Tr[mb + 6]) | ((unsigned)f2bf(Tr[mb + 7]) << 16);
      *(uint4*)(dst + mb) = o;
    }
  } else {
    // ---- q/k epilogue: direct stores (32B segments) ----
#pragma unroll
    for (int mi = 0; mi < 4; ++mi) {
#pragma unroll
      for (int ni = 0; ni < 4; ++ni) {
        int n = n0 + wc * 64 + ni * 16 + lr;
        float bn = bias[n];
        int which = n >> 9, nn = n & 511;
        int h = nn >> 6, dd = nn & 63;
#pragma unroll
        for (int rr = 0; rr < 4; ++rr) {
          int m = m0 + wr * 64 + mi * 16 + lg * 4 + rr;
          float v = acc[mi][ni][rr] + bn;
          int bb = m >> 10, li = m & 1023;
          if (which == 0)
            qb[((size_t)(bb * 8 + h) * 1024 + li) * 64 + dd] = f2bf(v);
          else
            kb[((size_t)(bb * 8 + h) * 1024 + li) * 64 + dd] = f2bf(v);
        }
      }
    }
  }
}

// ---------------- K5: flash attention, 8-wave block, LDS K/V dbuf, lean softmax ----------------
__global__ __launch_bounds__(512, 4) void k_attn(const u16* __restrict__ qb,
                                                 const u16* __restrict__ kb,
                                                 const u16* __restrict__ vT,
                                                 u16* __restrict__ ob) {
  __shared__ __attribute__((aligned(16))) u16 Ks[2 * 64 * 64];  // 16 KB dbuf
  __shared__ __attribute__((aligned(16))) u16 Vs[2 * 64 * 64];  // 16 KB dbuf
  __shared__ __attribute__((aligned(16))) u16 Ps[8 * 32 * 64];  // 32 KB per-wave P
  int bid = blockIdx.x;
  // XCD-bijective swizzle: all 4 q-tiles of a head keep bid%8 constant
  int xq = bid & 7, kk = bid >> 3;              // bid in [0,512)
  int bh = ((kk & 15) << 3) | xq;               // [0,128)
  int qt = kk >> 4;                             // [0,4)
  const u16* qh = qb + (size_t)bh * 65536;
  const u16* kh = kb + (size_t)bh * 65536;
  const u16* vh = vT + (size_t)bh * 65536;
  int tid = threadIdx.x, w = tid >> 6, lane = tid & 63, lr = lane & 15, lg = lane >> 4;
  int q0 = qt * 256 + w * 32;
  const f32x4 fzero = {0.f, 0.f, 0.f, 0.f};
  const float C1 = 0.18033688011112042f;   // 0.125 * log2(e)

  // Q fragments (B-operand of swapped QK^T): lane holds col q=lr, d-slice lg*8
  short8 qf[2][2];
#pragma unroll
  for (int mi = 0; mi < 2; ++mi)
#pragma unroll
    for (int ks = 0; ks < 2; ++ks)
      qf[mi][ks] = *(const short8*)(qh + (size_t)(q0 + mi * 16 + lr) * 64 +
                                    ks * 32 + lg * 8);
  f32x4 accO[2][4];
  float mst[2], lst[2], nmc[2];
#pragma unroll
  for (int mi = 0; mi < 2; ++mi) {
#pragma unroll
    for (int nd = 0; nd < 4; ++nd) accO[mi][nd] = fzero;
    mst[mi] = -1e30f; lst[mi] = 0.f; nmc[mi] = 0.f;  // first iter always updates nmc
  }
  char* Pwb = (char*)(Ps + w * 2048);   // 32 rows x 128 B per wave

  int sr = tid >> 3, sc8 = tid & 7;     // staging: row, 16B-chunk (512 thr = 64x8)
  size_t koff = (size_t)sr * 64 + ((sc8 ^ (sr & 7)) << 3);
  size_t voff = (size_t)sr * 1024 + ((sc8 ^ (sr & 7)) << 3);
  int ldst = (tid & ~63) << 4;          // wave-uniform LDS dest base

  // prologue: stage tile 0 into buf 0
  gl_lds16(kh + koff, (char*)Ks + ldst);
  gl_lds16(vh + voff, (char*)Vs + ldst);
  __syncthreads();

#pragma unroll 1
  for (int jt = 0; jt < 16; ++jt) {
    int cur = jt & 1;
    char* Ksb = (char*)Ks + cur * 8192;
    char* Vsb = (char*)Vs + cur * 8192;
    // stage next tile into the other buffer (issued before compute)
    if (jt < 15) {
      int nb = cur ^ 1;
      gl_lds16(kh + (size_t)(jt + 1) * 64 * 64 + koff, (char*)Ks + nb * 8192 + ldst);
      gl_lds16(vh + (size_t)(jt + 1) * 64 + voff, (char*)Vs + nb * 8192 + ldst);
    }

    // K fragments (A-operand): row = k-pos, from LDS
    short8 kf[4][2];
#pragma unroll
    for (int nj = 0; nj < 4; ++nj)
#pragma unroll
      for (int ks = 0; ks < 2; ++ks) {
        int row = nj * 16 + lr;
        kf[nj][ks] = *(const short8*)(Ksb + row * 128 + (((ks * 4 + lg) ^ (row & 7)) << 4));
      }

    // S^T = K Q^T: sc[mi][nj] has col=q(lr), row=k(nj*16+lg*4+rr)
    f32x4 sc[2][4];
#pragma unroll
    for (int mi = 0; mi < 2; ++mi)
#pragma unroll
      for (int nj = 0; nj < 4; ++nj) sc[mi][nj] = fzero;
#pragma unroll
    for (int ks = 0; ks < 2; ++ks)
#pragma unroll
      for (int mi = 0; mi < 2; ++mi)
#pragma unroll
        for (int nj = 0; nj < 4; ++nj)
          sc[mi][nj] = mfma16(kf[nj][ks], qf[mi][ks], sc[mi][nj]);

    // online softmax, defer-max THR=8 (raw-score units), exp2-direct, manual bf16 pack
#pragma unroll
    for (int mi = 0; mi < 2; ++mi) {
      // tree max over 16 raw scores (enables v_max3 fusion)
      float t0 = fmaxf(fmaxf(sc[mi][0][0], sc[mi][0][1]), fmaxf(sc[mi][0][2], sc[mi][0][3]));
      float t1 = fmaxf(fmaxf(sc[mi][1][0], sc[mi][1][1]), fmaxf(sc[mi][1][2], sc[mi][1][3]));
      float t2 = fmaxf(fmaxf(sc[mi][2][0], sc[mi][2][1]), fmaxf(sc[mi][2][2], sc[mi][2][3]));
      float t3 = fmaxf(fmaxf(sc[mi][3][0], sc[mi][3][1]), fmaxf(sc[mi][3][2], sc[mi][3][3]));
      float mloc = fmaxf(fmaxf(t0, t1), fmaxf(t2, t3));
      mloc = fmaxf(mloc, __shfl_xor(mloc, 16));
      mloc = fmaxf(mloc, __shfl_xor(mloc, 32));
      if (__any(mloc - mst[mi] > 8.f)) {      // wave-uniform rescale path (exact math)
        float mn = fmaxf(mst[mi], mloc);
        float al = __builtin_amdgcn_exp2f((mst[mi] - mn) * C1);
        mst[mi] = mn;
        nmc[mi] = -mn * C1;
        lst[mi] *= al;
        // broadcast al (lr-indexed) to accO rows (lg*4+rr-indexed), rescale O
#pragma unroll
        for (int rr = 0; rr < 4; ++rr) {
          float ab = __shfl(al, (lane & 48) | ((lane >> 4) & 3) * 4 + rr);
#pragma unroll
          for (int nd = 0; nd < 4; ++nd) accO[mi][nd][rr] *= ab;
        }
      }
      float nm = nmc[mi];
      float rs = 0.f;
#pragma unroll
      for (int nj = 0; nj < 4; ++nj) {
        float p0 = __builtin_amdgcn_exp2f(__builtin_fmaf(sc[mi][nj][0], C1, nm));
        float p1 = __builtin_amdgcn_exp2f(__builtin_fmaf(sc[mi][nj][1], C1, nm));
        float p2 = __builtin_amdgcn_exp2f(__builtin_fmaf(sc[mi][nj][2], C1, nm));
        float p3 = __builtin_amdgcn_exp2f(__builtin_fmaf(sc[mi][nj][3], C1, nm));
        rs += (p0 + p1) + (p2 + p3);
        // pack 4 consecutive-k bf16 (verified manual RNE pack), write as ds_write_b64
        uint2 pv;
        pv.x = (unsigned)f2bf(p0) | ((unsigned)f2bf(p1) << 16);
        pv.y = (unsigned)f2bf(p2) | ((unsigned)f2bf(p3) << 16);
        int row = mi * 16 + lr;
        int byte = row * 128 + (nj * 16 + lg * 4) * 2;
        byte ^= (row & 7) << 4;
        *(uint2*)(Pwb + byte) = pv;
      }
      rs += __shfl_xor(rs, 16);
      rs += __shfl_xor(rs, 32);
      lst[mi] += rs;
    }

    // V fragments (B-operand of PV) from LDS
    short8 bv[4][2];
#pragma unroll
    for (int nd = 0; nd < 4; ++nd)
#pragma unroll
      for (int ks = 0; ks < 2; ++ks) {
        int row = nd * 16 + lr;
        bv[nd][ks] = *(const short8*)(Vsb + row * 128 + (((ks * 4 + lg) ^ (row & 7)) << 4));
      }

    // O += P @ V : A-fragment of P from LDS (XOR-swizzled b128)
    short8 ap[2][2];
#pragma unroll
    for (int mi = 0; mi < 2; ++mi)
#pragma unroll
      for (int ks = 0; ks < 2; ++ks) {
        int row = mi * 16 + lr;
        int byte = row * 128 + (ks * 32 + lg * 8) * 2;
        byte ^= (row & 7) << 4;
        ap[mi][ks] = *(const short8*)(Pwb + byte);
      }
#pragma unroll
    for (int ks = 0; ks < 2; ++ks)
#pragma unroll
      for (int mi = 0; mi < 2; ++mi)
#pragma unroll
        for (int nd = 0; nd < 4; ++nd)
          accO[mi][nd] = mfma16(ap[mi][ks], bv[nd][ks], accO[mi][nd]);

    // publish: own staged loads landed (syncthreads drains vmcnt) + all waves done with cur
    __syncthreads();
  }

  // epilogue: O /= l (broadcast 1/lst from lr-lanes to accO rows), write bf16
  int b = bh >> 3, h = bh & 7;
#pragma unroll
  for (int mi = 0; mi < 2; ++mi) {
    float il = 1.f / lst[mi];
#pragma unroll
    for (int rr = 0; rr < 4; ++rr) {
      float ib = __shfl(il, (lane & 48) | ((lane >> 4) & 3) * 4 + rr);
      int row = q0 + mi * 16 + lg * 4 + rr;
#pragma unroll
      for (int nd = 0; nd < 4; ++nd) {
        int col = h * 64 + nd * 16 + lr;
        ob[(size_t)(b * 1024 + row) * 512 + col] = f2bf(accO[mi][nd][rr] * ib);
      }
    }
  }
}

// ---------------- K6: out-proj GEMM + bias + residual, 2-phase dbuf (fp32 out) ----------------
__global__ __launch_bounds__(256) void k_out(const u16* __restrict__ ob,
                                             const u16* __restrict__ wT,
                                             const float* __restrict__ bias,
                                             const float* __restrict__ x,
                                             float* __restrict__ out) {
  __shared__ __attribute__((aligned(16))) u16 As[2 * 128 * 64];
  __shared__ __attribute__((aligned(16))) u16 Bs[2 * 128 * 64];
  // XCD-chunk swizzle: each XCD gets 64 consecutive work ids = 16 m-rows x 4 n
  int bid = blockIdx.x;
  int wg = (bid & 7) * 64 + (bid >> 3);
  int tn = wg & 3, tm = wg >> 2;
  int m0 = tm * 128, n0 = tn * 128;
  int tid = threadIdx.x;
  int w = tid >> 6, lane = tid & 63, lr = lane & 15, lg = lane >> 4;
  int wr = w >> 1, wc = w & 1;
  const f32x4 fzero = {0.f, 0.f, 0.f, 0.f};
  f32x4 acc[4][4];
#pragma unroll
  for (int mi = 0; mi < 4; ++mi)
#pragma unroll
    for (int ni = 0; ni < 4; ++ni) acc[mi][ni] = fzero;

  // prologue: stage kt=0 into buf 0
#pragma unroll
  for (int i = 0; i < 4; ++i) {
    int s = i * 256 + tid;
    int r = s >> 3, c = s & 7;
    gl_lds16(ob + ((size_t)(m0 + r) * 512 + ((c ^ (r & 7)) << 3)),
             (char*)As + ((s & ~63) << 4));
    gl_lds16(wT + ((size_t)(n0 + r) * 512 + ((c ^ (r & 7)) << 3)),
             (char*)Bs + ((s & ~63) << 4));
  }
  __syncthreads();

  for (int kt = 0; kt < 8; ++kt) {
    int cur = kt & 1;
    char* Asb = (char*)As + cur * 16384;
    char* Bsb = (char*)Bs + cur * 16384;
    if (kt < 7) {
      int nb = cur ^ 1, k0n = (kt + 1) * 64;
#pragma unroll
      for (int i = 0; i < 4; ++i) {
        int s = i * 256 + tid;
        int r = s >> 3, c = s & 7;
        gl_lds16(ob + ((size_t)(m0 + r) * 512 + k0n + ((c ^ (r & 7)) << 3)),
                 (char*)As + nb * 16384 + ((s & ~63) << 4));
        gl_lds16(wT + ((size_t)(n0 + r) * 512 + k0n + ((c ^ (r & 7)) << 3)),
                 (char*)Bs + nb * 16384 + ((s & ~63) << 4));
      }
    }
#pragma unroll
    for (int ks = 0; ks < 2; ++ks) {
      short8 af[4], bf[4];
#pragma unroll
      for (int mi = 0; mi < 4; ++mi) {
        int row = wr * 64 + mi * 16 + lr;
        int ck = ks * 4 + lg;
        af[mi] = *(const short8*)(Asb + row * 128 + ((ck ^ (lr & 7)) << 4));
      }
#pragma unroll
      for (int ni = 0; ni < 4; ++ni) {
        int row = wc * 64 + ni * 16 + lr;
        int ck = ks * 4 + lg;
        bf[ni] = *(const short8*)(Bsb + row * 128 + ((ck ^ (lr & 7)) << 4));
      }
#pragma unroll
      for (int mi = 0; mi < 4; ++mi)
#pragma unroll
        for (int ni = 0; ni < 4; ++ni)
          acc[mi][ni] = mfma16(af[mi], bf[ni], acc[mi][ni]);
    }
    __syncthreads();
  }
#pragma unroll
  for (int mi = 0; mi < 4; ++mi) {
#pragma unroll
    for (int ni = 0; ni < 4; ++ni) {
      int n = n0 + wc * 64 + ni * 16 + lr;
      float bn = bias[n];
#pragma unroll
      for (int rr = 0; rr < 4; ++rr) {
        int m = m0 + wr * 64 + mi * 16 + lg * 4 + rr;
        size_t off = (size_t)m * 512 + n;
        out[off] = x[off] + acc[mi][ni][rr] + bn;
      }
    }
  }
}

extern "C" void kernel_launch(void* const* d_in, const int* in_sizes, int n_in,
                              void* d_out, int out_size, void* d_ws, size_t ws_size,
                              hipStream_t stream) {
  const float* x = (const float*)d_in[0];
  // d_in[1] = timesteps (unused by the reference computation)
  const float* gamma = (const float*)d_in[2];
  const float* beta = (const float*)d_in[3];
  const float* wqkv = (const float*)d_in[4];
  const float* bqkv = (const float*)d_in[5];
  const float* wout = (const float*)d_in[6];
  const float* bout = (const float*)d_in[7];
  float* out = (float*)d_out;

  char* ws = (char*)d_ws;
  float* stats = (float*)ws;                                   //   4096 B
  u16* gn = (u16*)(ws + 4096);                                 // 16 MB  [M][512]
  u16* wqkvT = (u16*)(ws + 4096 + 16777216);                   // 1.5 MB [1536][512]
  u16* woutT = (u16*)(ws + 4096 + 16777216 + 1572864);         // 0.5 MB [512][512]
  u16* qb = (u16*)(ws + 4096 + 16777216 + 1572864 + 524288);   // 16 MB  [BH][L][64]
  u16* kb = qb + 8388608;                                      // 16 MB  [BH][L][64]
  u16* vT = kb + 8388608;                                      // 16 MB  [BH][64][L]
  u16* ob = vT + 8388608;                                      // 16 MB  [M][512]

  k_gnstats<<<512, 256, 0, stream>>>(x, stats);
  k_gnapply<<<8192, 256, 0, stream>>>(x, stats, gamma, beta, gn);
  k_wtrans<<<4096, 256, 0, stream>>>(wqkv, wout, wqkvT, woutT);
  k_qkv<<<1536, 256, 0, stream>>>(gn, wqkvT, bqkv, qb, kb, vT);
  k_attn<<<512, 512, 0, stream>>>(qb, kb, vT, ob);
  k_out<<<512, 256, 0, stream>>>(ob, woutT, bout, x, out);
}

// Round 10
// 144.179 us; speedup vs baseline: 1.9484x; 1.0415x over previous
//
#include <hip/hip_runtime.h>

// Problem constants: B=16, H=W=32 -> L=1024, C=512, G=32, nh=8, d=64
#define Bn 16
#define Ln 1024
#define Cn 512
#define Mn (Bn*Ln)     // 16384
#define N3n 1536

typedef unsigned short u16;
typedef __attribute__((ext_vector_type(8))) short short8;
typedef __attribute__((ext_vector_type(4))) float f32x4;

typedef const __attribute__((address_space(1))) void* gas_p;
typedef __attribute__((address_space(3))) void* las_p;

__device__ inline void gl_lds16(const void* g, void* l) {
  __builtin_amdgcn_global_load_lds((gas_p)g, (las_p)l, 16, 0, 0);
}

__device__ inline u16 f2bf(float f) {
  union { float f; unsigned u; } v; v.f = f;
  unsigned r = v.u + 0x7FFFu + ((v.u >> 16) & 1u);
  return (u16)(r >> 16);
}

__device__ inline f32x4 mfma16(short8 a, short8 b, f32x4 c) {
  return __builtin_amdgcn_mfma_f32_16x16x32_bf16(a, b, c, 0, 0, 0);
}

// ---------------- K1: GroupNorm stats (mean, rstd per (b,g)) ----------------
__global__ __launch_bounds__(256) void k_gnstats(const float* __restrict__ x,
                                                 float* __restrict__ stats) {
  int bid = blockIdx.x;            // b*32+g
  int b = bid >> 5, g = bid & 31;
  const float* base = x + (size_t)b * (Ln * Cn) + g * 16;
  int tid = threadIdx.x;
  float s1 = 0.f, s2 = 0.f;
  for (int i = 0; i < 16; ++i) {
    int s = i * 256 + tid;
    int l = s >> 2, cq = s & 3;
    float4 v = *(const float4*)(base + (size_t)l * Cn + cq * 4);
    s1 += v.x + v.y + v.z + v.w;
    s2 += v.x * v.x + v.y * v.y + v.z * v.z + v.w * v.w;
  }
  for (int off = 32; off > 0; off >>= 1) {
    s1 += __shfl_down(s1, off);
    s2 += __shfl_down(s2, off);
  }
  __shared__ float rb[8];
  int w = tid >> 6, lane = tid & 63;
  if (lane == 0) { rb[w] = s1; rb[4 + w] = s2; }
  __syncthreads();
  if (tid == 0) {
    float a = rb[0] + rb[1] + rb[2] + rb[3];
    float q = rb[4] + rb[5] + rb[6] + rb[7];
    float mean = a * (1.f / 16384.f);
    float var = q * (1.f / 16384.f) - mean * mean;
    stats[bid * 2] = mean;
    stats[bid * 2 + 1] = rsqrtf(var + 1e-5f);
  }
}

// ---------------- K2: GN apply + cast to bf16 ----------------
__global__ __launch_bounds__(256) void k_gnapply(const float* __restrict__ x,
                                                 const float* __restrict__ stats,
                                                 const float* __restrict__ gamma,
                                                 const float* __restrict__ beta,
                                                 u16* __restrict__ gn) {
  int idx = blockIdx.x * 256 + threadIdx.x;
  size_t e = (size_t)idx << 2;
  int m = (int)(e >> 9), c = (int)(e & 511);
  int b = m >> 10, g = c >> 4;
  float mean = stats[(b * 32 + g) * 2];
  float rstd = stats[(b * 32 + g) * 2 + 1];
  float4 xv = *(const float4*)(x + e);
  float4 gv = *(const float4*)(gamma + c);
  float4 bv = *(const float4*)(beta + c);
  ushort4 o;
  o.x = f2bf((xv.x - mean) * rstd * gv.x + bv.x);
  o.y = f2bf((xv.y - mean) * rstd * gv.y + bv.y);
  o.z = f2bf((xv.z - mean) * rstd * gv.z + bv.z);
  o.w = f2bf((xv.w - mean) * rstd * gv.w + bv.w);
  *(ushort4*)(gn + e) = o;
}

// ---------------- K3: transpose+cast weights to [N][K] bf16 ----------------
__global__ __launch_bounds__(256) void k_wtrans(const float* __restrict__ wqkv,
                                                const float* __restrict__ wout,
                                                u16* __restrict__ wqkvT,
                                                u16* __restrict__ woutT) {
  int id = blockIdx.x * 256 + threadIdx.x;
  if (id < Cn * N3n) {
    int k = id & 511, n = id >> 9;
    wqkvT[id] = f2bf(wqkv[(size_t)k * N3n + n]);
  } else {
    int id2 = id - Cn * N3n;
    int k = id2 & 511, n = id2 >> 9;
    woutT[id2] = f2bf(wout[(size_t)k * Cn + n]);
  }
}

// ---------------- K4: QKV GEMM, 2-phase dbuf + LDS-transposed vT epilogue ----------------
__global__ __launch_bounds__(256) void k_qkv(const u16* __restrict__ gn,
                                             const u16* __restrict__ wT,
                                             const float* __restrict__ bias,
                                             u16* __restrict__ qb,
                                             u16* __restrict__ kb,
                                             u16* __restrict__ vT) {
  // staging: A dbuf 32 KB @0, B dbuf 32 KB @32768; v-epilogue reuses as f32 [128][130]
  __shared__ __attribute__((aligned(16))) char smem[66560];
  // XCD-chunk swizzle: each XCD gets 192 consecutive work ids
  int bid = blockIdx.x;
  int wg = (bid & 7) * 192 + (bid >> 3);
  int tn = wg % 12, tm = wg / 12;
  int m0 = tm * 128, n0 = tn * 128;
  int tid = threadIdx.x;
  int w = tid >> 6, lane = tid & 63, lr = lane & 15, lg = lane >> 4;
  int wr = w >> 1, wc = w & 1;
  const f32x4 fzero = {0.f, 0.f, 0.f, 0.f};
  f32x4 acc[4][4];
#pragma unroll
  for (int mi = 0; mi < 4; ++mi)
#pragma unroll
    for (int ni = 0; ni < 4; ++ni) acc[mi][ni] = fzero;

  // prologue: stage kt=0 into buf 0
#pragma unroll
  for (int i = 0; i < 4; ++i) {
    int s = i * 256 + tid;
    int r = s >> 3, c = s & 7;
    gl_lds16(gn + ((size_t)(m0 + r) * 512 + ((c ^ (r & 7)) << 3)),
             smem + ((s & ~63) << 4));
    gl_lds16(wT + ((size_t)(n0 + r) * 512 + ((c ^ (r & 7)) << 3)),
             smem + 32768 + ((s & ~63) << 4));
  }
  __syncthreads();

  for (int kt = 0; kt < 8; ++kt) {
    int cur = kt & 1;
    char* Asb = smem + cur * 16384;
    char* Bsb = smem + 32768 + cur * 16384;
    if (kt < 7) {
      int nb = cur ^ 1, k0n = (kt + 1) * 64;
#pragma unroll
      for (int i = 0; i < 4; ++i) {
        int s = i * 256 + tid;
        int r = s >> 3, c = s & 7;
        gl_lds16(gn + ((size_t)(m0 + r) * 512 + k0n + ((c ^ (r & 7)) << 3)),
                 smem + nb * 16384 + ((s & ~63) << 4));
        gl_lds16(wT + ((size_t)(n0 + r) * 512 + k0n + ((c ^ (r & 7)) << 3)),
                 smem + 32768 + nb * 16384 + ((s & ~63) << 4));
      }
    }
#pragma unroll
    for (int ks = 0; ks < 2; ++ks) {
      short8 af[4], bf[4];
#pragma unroll
      for (int mi = 0; mi < 4; ++mi) {
        int row = wr * 64 + mi * 16 + lr;
        int ck = ks * 4 + lg;
        af[mi] = *(const short8*)(Asb + row * 128 + ((ck ^ (lr & 7)) << 4));
      }
#pragma unroll
      for (int ni = 0; ni < 4; ++ni) {
        int row = wc * 64 + ni * 16 + lr;
        int ck = ks * 4 + lg;
        bf[ni] = *(const short8*)(Bsb + row * 128 + ((ck ^ (lr & 7)) << 4));
      }
#pragma unroll
      for (int mi = 0; mi < 4; ++mi)
#pragma unroll
        for (int ni = 0; ni < 4; ++ni)
          acc[mi][ni] = mfma16(af[mi], bf[ni], acc[mi][ni]);
    }
    __syncthreads();
  }

  if (tn >= 8) {
    // ---- v-block epilogue: transpose via LDS, coalesced dwordx4 stores ----
    float* T = (float*)smem;  // [128 n_local][130]
#pragma unroll
    for (int mi = 0; mi < 4; ++mi)
#pragma unroll
      for (int ni = 0; ni < 4; ++ni) {
        int n_l = wc * 64 + ni * 16 + lr;
        float bn = bias[n0 + n_l];
#pragma unroll
        for (int rr = 0; rr < 4; ++rr) {
          int m_l = wr * 64 + mi * 16 + lg * 4 + rr;
          T[n_l * 130 + m_l] = acc[mi][ni][rr] + bn;
        }
      }
    __syncthreads();
    int n_l = tid >> 1, half = tid & 1;
    int nv = n0 - 1024 + n_l;
    int h = nv >> 6, dd = nv & 63;
    int bb = m0 >> 10, li0 = m0 & 1023;
    u16* dst = vT + ((size_t)(bb * 8 + h) * 64 + dd) * 1024 + li0;
    const float* Tr = T + n_l * 130;
#pragma unroll
    for (int j = 0; j < 8; ++j) {       // 8 chunks x 8 elems = full 128 m per row
      int mb = half * 8 + 16 * j;       // 8 consecutive li; lane pairs form 32B runs
      uint4 o;
      o.x = (unsigned)f2bf(Tr[mb + 0]) | ((unsigned)f2bf(Tr[mb + 1]) << 16);
      o.y = (unsigned)f2bf(Tr[mb + 2]) | ((unsigned)f2bf(Tr[mb + 3]) << 16);
      o.z = (unsigned)f2bf(Tr[mb + 4]) | ((unsigned)f2bf(Tr[mb + 5]) << 16);
      o.w = (unsigned)f2bf(Tr[mb + 6]) | ((unsigned)f2bf(Tr[mb + 7]) << 16);
      *(uint4*)(dst + mb) = o;
    }
  } else {
    // ---- q/k epilogue: direct stores (32B segments) ----
#pragma unroll
    for (int mi = 0; mi < 4; ++mi) {
#pragma unroll
      for (int ni = 0; ni < 4; ++ni) {
        int n = n0 + wc * 64 + ni * 16 + lr;
        float bn = bias[n];
        int which = n >> 9, nn = n & 511;
        int h = nn >> 6, dd = nn & 63;
#pragma unroll
        for (int rr = 0; rr < 4; ++rr) {
          int m = m0 + wr * 64 + mi * 16 + lg * 4 + rr;
          float v = acc[mi][ni][rr] + bn;
          int bb = m >> 10, li = m & 1023;
          if (which == 0)
            qb[((size_t)(bb * 8 + h) * 1024 + li) * 64 + dd] = f2bf(v);
          else
            kb[((size_t)(bb * 8 + h) * 1024 + li) * 64 + dd] = f2bf(v);
        }
      }
    }
  }
}

// ---------------- K5: flash attention, 8-wave block, triple-buffered K/V, counted vmcnt ----------------
__global__ __launch_bounds__(512, 4) void k_attn(const u16* __restrict__ qb,
                                                 const u16* __restrict__ kb,
                                                 const u16* __restrict__ vT,
                                                 u16* __restrict__ ob) {
  __shared__ __attribute__((aligned(16))) u16 Ks[3 * 64 * 64];  // 24 KB tri-buf
  __shared__ __attribute__((aligned(16))) u16 Vs[3 * 64 * 64];  // 24 KB tri-buf
  __shared__ __attribute__((aligned(16))) u16 Ps[8 * 32 * 64];  // 32 KB per-wave P
  int bid = blockIdx.x;
  // XCD-bijective swizzle: all 4 q-tiles of a head keep bid%8 constant
  int xq = bid & 7, kk = bid >> 3;              // bid in [0,512)
  int bh = ((kk & 15) << 3) | xq;               // [0,128)
  int qt = kk >> 4;                             // [0,4)
  const u16* qh = qb + (size_t)bh * 65536;
  const u16* kh = kb + (size_t)bh * 65536;
  const u16* vh = vT + (size_t)bh * 65536;
  int tid = threadIdx.x, w = tid >> 6, lane = tid & 63, lr = lane & 15, lg = lane >> 4;
  int q0 = qt * 256 + w * 32;
  const f32x4 fzero = {0.f, 0.f, 0.f, 0.f};
  const float C1 = 0.18033688011112042f;   // 0.125 * log2(e)

  // Q fragments (B-operand of swapped QK^T): lane holds col q=lr, d-slice lg*8
  short8 qf[2][2];
#pragma unroll
  for (int mi = 0; mi < 2; ++mi)
#pragma unroll
    for (int ks = 0; ks < 2; ++ks)
      qf[mi][ks] = *(const short8*)(qh + (size_t)(q0 + mi * 16 + lr) * 64 +
                                    ks * 32 + lg * 8);
  f32x4 accO[2][4];
  float mst[2], lst[2], nmc[2];
#pragma unroll
  for (int mi = 0; mi < 2; ++mi) {
#pragma unroll
    for (int nd = 0; nd < 4; ++nd) accO[mi][nd] = fzero;
    mst[mi] = -1e30f; lst[mi] = 0.f; nmc[mi] = 0.f;  // first iter always updates nmc
  }
  char* Pwb = (char*)(Ps + w * 2048);   // 32 rows x 128 B per wave

  int sr = tid >> 3, sc8 = tid & 7;     // staging: row, 16B-chunk (512 thr = 64x8)
  size_t koff = (size_t)sr * 64 + ((sc8 ^ (sr & 7)) << 3);
  size_t voff = (size_t)sr * 1024 + ((sc8 ^ (sr & 7)) << 3);
  int ldst = (tid & ~63) << 4;          // wave-uniform LDS dest base

  // prologue: stage tiles 0,1 into bufs 0,1; wait tile 0 only (2 newest stay in flight)
  gl_lds16(kh + koff, (char*)Ks + ldst);
  gl_lds16(vh + voff, (char*)Vs + ldst);
  gl_lds16(kh + 4096 + koff, (char*)Ks + 8192 + ldst);
  gl_lds16(vh + 64 + voff, (char*)Vs + 8192 + ldst);
  asm volatile("s_waitcnt vmcnt(2)" ::: "memory");
  __builtin_amdgcn_s_barrier();

#pragma unroll 1
  for (int jt = 0; jt < 16; ++jt) {
    int cb = jt % 3;
    char* Ksb = (char*)Ks + cb * 8192;
    char* Vsb = (char*)Vs + cb * 8192;
    // stage tile jt+2 into buf (jt+2)%3 — stays in flight across this iteration's barrier
    if (jt < 14) {
      int nb = (jt + 2) % 3;
      gl_lds16(kh + (size_t)(jt + 2) * 4096 + koff, (char*)Ks + nb * 8192 + ldst);
      gl_lds16(vh + (size_t)(jt + 2) * 64 + voff, (char*)Vs + nb * 8192 + ldst);
    }

    // K fragments (A-operand): row = k-pos, from LDS
    short8 kf[4][2];
#pragma unroll
    for (int nj = 0; nj < 4; ++nj)
#pragma unroll
      for (int ks = 0; ks < 2; ++ks) {
        int row = nj * 16 + lr;
        kf[nj][ks] = *(const short8*)(Ksb + row * 128 + (((ks * 4 + lg) ^ (row & 7)) << 4));
      }

    // S^T = K Q^T: sc[mi][nj] has col=q(lr), row=k(nj*16+lg*4+rr)
    f32x4 sc[2][4];
#pragma unroll
    for (int mi = 0; mi < 2; ++mi)
#pragma unroll
      for (int nj = 0; nj < 4; ++nj) sc[mi][nj] = fzero;
#pragma unroll
    for (int ks = 0; ks < 2; ++ks)
#pragma unroll
      for (int mi = 0; mi < 2; ++mi)
#pragma unroll
        for (int nj = 0; nj < 4; ++nj)
          sc[mi][nj] = mfma16(kf[nj][ks], qf[mi][ks], sc[mi][nj]);

    // online softmax, defer-max THR=8, exp2-direct, truncation pack (bit-exact safe)
#pragma unroll
    for (int mi = 0; mi < 2; ++mi) {
      float t0 = fmaxf(fmaxf(sc[mi][0][0], sc[mi][0][1]), fmaxf(sc[mi][0][2], sc[mi][0][3]));
      float t1 = fmaxf(fmaxf(sc[mi][1][0], sc[mi][1][1]), fmaxf(sc[mi][1][2], sc[mi][1][3]));
      float t2 = fmaxf(fmaxf(sc[mi][2][0], sc[mi][2][1]), fmaxf(sc[mi][2][2], sc[mi][2][3]));
      float t3 = fmaxf(fmaxf(sc[mi][3][0], sc[mi][3][1]), fmaxf(sc[mi][3][2], sc[mi][3][3]));
      float mloc = fmaxf(fmaxf(t0, t1), fmaxf(t2, t3));
      mloc = fmaxf(mloc, __shfl_xor(mloc, 16));
      mloc = fmaxf(mloc, __shfl_xor(mloc, 32));
      if (__any(mloc - mst[mi] > 8.f)) {      // wave-uniform rescale path (exact math)
        float mn = fmaxf(mst[mi], mloc);
        float al = __builtin_amdgcn_exp2f((mst[mi] - mn) * C1);
        mst[mi] = mn;
        nmc[mi] = -mn * C1;
        lst[mi] *= al;
#pragma unroll
        for (int rr = 0; rr < 4; ++rr) {
          float ab = __shfl(al, (lane & 48) | ((lane >> 4) & 3) * 4 + rr);
#pragma unroll
          for (int nd = 0; nd < 4; ++nd) accO[mi][nd][rr] *= ab;
        }
      }
      float nm = nmc[mi];
      float rs = 0.f;
#pragma unroll
      for (int nj = 0; nj < 4; ++nj) {
        float p0 = __builtin_amdgcn_exp2f(__builtin_fmaf(sc[mi][nj][0], C1, nm));
        float p1 = __builtin_amdgcn_exp2f(__builtin_fmaf(sc[mi][nj][1], C1, nm));
        float p2 = __builtin_amdgcn_exp2f(__builtin_fmaf(sc[mi][nj][2], C1, nm));
        float p3 = __builtin_amdgcn_exp2f(__builtin_fmaf(sc[mi][nj][3], C1, nm));
        rs += (p0 + p1) + (p2 + p3);
        // truncation pack: bf16 = high 16 bits (P>0; bias ~2^-9 cancels in num/den)
        unsigned u0 = __float_as_uint(p0), u1 = __float_as_uint(p1);
        unsigned u2 = __float_as_uint(p2), u3 = __float_as_uint(p3);
        uint2 pv;
        pv.x = (u0 >> 16) | (u1 & 0xFFFF0000u);
        pv.y = (u2 >> 16) | (u3 & 0xFFFF0000u);
        int row = mi * 16 + lr;
        int byte = row * 128 + (nj * 16 + lg * 4) * 2;
        byte ^= (row & 7) << 4;
        *(uint2*)(Pwb + byte) = pv;
      }
      rs += __shfl_xor(rs, 16);
      rs += __shfl_xor(rs, 32);
      lst[mi] += rs;
    }

    // V fragments (B-operand of PV) from LDS
    short8 bv[4][2];
#pragma unroll
    for (int nd = 0; nd < 4; ++nd)
#pragma unroll
      for (int ks = 0; ks < 2; ++ks) {
        int row = nd * 16 + lr;
        bv[nd][ks] = *(const short8*)(Vsb + row * 128 + (((ks * 4 + lg) ^ (row & 7)) << 4));
      }

    // O += P @ V : A-fragment of P from LDS (XOR-swizzled b128)
    short8 ap[2][2];
#pragma unroll
    for (int mi = 0; mi < 2; ++mi)
#pragma unroll
      for (int ks = 0; ks < 2; ++ks) {
        int row = mi * 16 + lr;
        int byte = row * 128 + (ks * 32 + lg * 8) * 2;
        byte ^= (row & 7) << 4;
        ap[mi][ks] = *(const short8*)(Pwb + byte);
      }
#pragma unroll
    for (int ks = 0; ks < 2; ++ks)
#pragma unroll
      for (int mi = 0; mi < 2; ++mi)
#pragma unroll
        for (int nd = 0; nd < 4; ++nd)
          accO[mi][nd] = mfma16(ap[mi][ks], bv[nd][ks], accO[mi][nd]);

    // counted-vmcnt barrier: only jt+1's loads must be complete; jt+2's 2 loads stay in flight
    if (jt < 14)
      asm volatile("s_waitcnt vmcnt(2)" ::: "memory");
    else
      asm volatile("s_waitcnt vmcnt(0)" ::: "memory");
    __builtin_amdgcn_s_barrier();
  }

  // epilogue: O /= l (broadcast 1/lst from lr-lanes to accO rows), write bf16
  int b = bh >> 3, h = bh & 7;
#pragma unroll
  for (int mi = 0; mi < 2; ++mi) {
    float il = 1.f / lst[mi];
#pragma unroll
    for (int rr = 0; rr < 4; ++rr) {
      float ib = __shfl(il, (lane & 48) | ((lane >> 4) & 3) * 4 + rr);
      int row = q0 + mi * 16 + lg * 4 + rr;
#pragma unroll
      for (int nd = 0; nd < 4; ++nd) {
        int col = h * 64 + nd * 16 + lr;
        ob[(size_t)(b * 1024 + row) * 512 + col] = f2bf(accO[mi][nd][rr] * ib);
      }
    }
  }
}

// ---------------- K6: out-proj GEMM + bias + residual, 2-phase dbuf (fp32 out) ----------------
__global__ __launch_bounds__(256) void k_out(const u16* __restrict__ ob,
                                             const u16* __restrict__ wT,
                                             const float* __restrict__ bias,
                                             const float* __restrict__ x,
                                             float* __restrict__ out) {
  __shared__ __attribute__((aligned(16))) u16 As[2 * 128 * 64];
  __shared__ __attribute__((aligned(16))) u16 Bs[2 * 128 * 64];
  // XCD-chunk swizzle: each XCD gets 64 consecutive work ids = 16 m-rows x 4 n
  int bid = blockIdx.x;
  int wg = (bid & 7) * 64 + (bid >> 3);
  int tn = wg & 3, tm = wg >> 2;
  int m0 = tm * 128, n0 = tn * 128;
  int tid = threadIdx.x;
  int w = tid >> 6, lane = tid & 63, lr = lane & 15, lg = lane >> 4;
  int wr = w >> 1, wc = w & 1;
  const f32x4 fzero = {0.f, 0.f, 0.f, 0.f};
  f32x4 acc[4][4];
#pragma unroll
  for (int mi = 0; mi < 4; ++mi)
#pragma unroll
    for (int ni = 0; ni < 4; ++ni) acc[mi][ni] = fzero;

  // prologue: stage kt=0 into buf 0
#pragma unroll
  for (int i = 0; i < 4; ++i) {
    int s = i * 256 + tid;
    int r = s >> 3, c = s & 7;
    gl_lds16(ob + ((size_t)(m0 + r) * 512 + ((c ^ (r & 7)) << 3)),
             (char*)As + ((s & ~63) << 4));
    gl_lds16(wT + ((size_t)(n0 + r) * 512 + ((c ^ (r & 7)) << 3)),
             (char*)Bs + ((s & ~63) << 4));
  }
  __syncthreads();

  for (int kt = 0; kt < 8; ++kt) {
    int cur = kt & 1;
    char* Asb = (char*)As + cur * 16384;
    char* Bsb = (char*)Bs + cur * 16384;
    if (kt < 7) {
      int nb = cur ^ 1, k0n = (kt + 1) * 64;
#pragma unroll
      for (int i = 0; i < 4; ++i) {
        int s = i * 256 + tid;
        int r = s >> 3, c = s & 7;
        gl_lds16(ob + ((size_t)(m0 + r) * 512 + k0n + ((c ^ (r & 7)) << 3)),
                 (char*)As + nb * 16384 + ((s & ~63) << 4));
        gl_lds16(wT + ((size_t)(n0 + r) * 512 + k0n + ((c ^ (r & 7)) << 3)),
                 (char*)Bs + nb * 16384 + ((s & ~63) << 4));
      }
    }
#pragma unroll
    for (int ks = 0; ks < 2; ++ks) {
      short8 af[4], bf[4];
#pragma unroll
      for (int mi = 0; mi < 4; ++mi) {
        int row = wr * 64 + mi * 16 + lr;
        int ck = ks * 4 + lg;
        af[mi] = *(const short8*)(Asb + row * 128 + ((ck ^ (lr & 7)) << 4));
      }
#pragma unroll
      for (int ni = 0; ni < 4; ++ni) {
        int row = wc * 64 + ni * 16 + lr;
        int ck = ks * 4 + lg;
        bf[ni] = *(const short8*)(Bsb + row * 128 + ((ck ^ (lr & 7)) << 4));
      }
#pragma unroll
      for (int mi = 0; mi < 4; ++mi)
#pragma unroll
        for (int ni = 0; ni < 4; ++ni)
          acc[mi][ni] = mfma16(af[mi], bf[ni], acc[mi][ni]);
    }
    __syncthreads();
  }
#pragma unroll
  for (int mi = 0; mi < 4; ++mi) {
#pragma unroll
    for (int ni = 0; ni < 4; ++ni) {
      int n = n0 + wc * 64 + ni * 16 + lr;
      float bn = bias[n];
#pragma unroll
      for (int rr = 0; rr < 4; ++rr) {
        int m = m0 + wr * 64 + mi * 16 + lg * 4 + rr;
        size_t off = (size_t)m * 512 + n;
        out[off] = x[off] + acc[mi][ni][rr] + bn;
      }
    }
  }
}

extern "C" void kernel_launch(void* const* d_in, const int* in_sizes, int n_in,
                              void* d_out, int out_size, void* d_ws, size_t ws_size,
                              hipStream_t stream) {
  const float* x = (const float*)d_in[0];
  // d_in[1] = timesteps (unused by the reference computation)
  const float* gamma = (const float*)d_in[2];
  const float* beta = (const float*)d_in[3];
  const float* wqkv = (const float*)d_in[4];
  const float* bqkv = (const float*)d_in[5];
  const float* wout = (const float*)d_in[6];
  const float* bout = (const float*)d_in[7];
  float* out = (float*)d_out;

  char* ws = (char*)d_ws;
  float* stats = (float*)ws;                                   //   4096 B
  u16* gn = (u16*)(ws + 4096);                                 // 16 MB  [M][512]
  u16* wqkvT = (u16*)(ws + 4096 + 16777216);                   // 1.5 MB [1536][512]
  u16* woutT = (u16*)(ws + 4096 + 16777216 + 1572864);         // 0.5 MB [512][512]
  u16* qb = (u16*)(ws + 4096 + 16777216 + 1572864 + 524288);   // 16 MB  [BH][L][64]
  u16* kb = qb + 8388608;                                      // 16 MB  [BH][L][64]
  u16* vT = kb + 8388608;                                      // 16 MB  [BH][64][L]
  u16* ob = vT + 8388608;                                      // 16 MB  [M][512]

  k_gnstats<<<512, 256, 0, stream>>>(x, stats);
  k_gnapply<<<8192, 256, 0, stream>>>(x, stats, gamma, beta, gn);
  k_wtrans<<<4096, 256, 0, stream>>>(wqkv, wout, wqkvT, woutT);
  k_qkv<<<1536, 256, 0, stream>>>(gn, wqkvT, bqkv, qb, kb, vT);
  k_attn<<<512, 512, 0, stream>>>(qb, kb, vT, ob);
  k_out<<<512, 256, 0, stream>>>(ob, woutT, bout, x, out);
}

// Round 11
// 139.794 us; speedup vs baseline: 2.0095x; 1.0314x over previous
//
#include <hip/hip_runtime.h>

// Problem constants: B=16, H=W=32 -> L=1024, C=512, G=32, nh=8, d=64
#define Bn 16
#define Ln 1024
#define Cn 512
#define Mn (Bn*Ln)     // 16384
#define N3n 1536

typedef unsigned short u16;
typedef __attribute__((ext_vector_type(8))) short short8;
typedef __attribute__((ext_vector_type(4))) float f32x4;

typedef const __attribute__((address_space(1))) void* gas_p;
typedef __attribute__((address_space(3))) void* las_p;

__device__ inline void gl_lds16(const void* g, void* l) {
  __builtin_amdgcn_global_load_lds((gas_p)g, (las_p)l, 16, 0, 0);
}

__device__ inline u16 f2bf(float f) {
  union { float f; unsigned u; } v; v.f = f;
  unsigned r = v.u + 0x7FFFu + ((v.u >> 16) & 1u);
  return (u16)(r >> 16);
}

__device__ inline f32x4 mfma16(short8 a, short8 b, f32x4 c) {
  return __builtin_amdgcn_mfma_f32_16x16x32_bf16(a, b, c, 0, 0, 0);
}

// ---------------- K1: fused GroupNorm (stats + apply) via LDS staging ----------------
// block = (b, group-pair): stages 1024 rows x 32 ch of x (128 KB) once from HBM
__global__ __launch_bounds__(256) void k_gn(const float* __restrict__ x,
                                            const float* __restrict__ gamma,
                                            const float* __restrict__ beta,
                                            u16* __restrict__ gn) {
  __shared__ __attribute__((aligned(16))) float xs[1024 * 32];  // 128 KB
  __shared__ float red[32];
  __shared__ float stat[4];
  int bid = blockIdx.x;            // b*16 + gp
  int b = bid >> 4, gp = bid & 15;
  const float* base = x + (size_t)b * (Ln * Cn) + gp * 32;
  int tid = threadIdx.x;
  int c = tid & 7;                 // 16B-quad within 32-ch span; group = c>>2
  float s1 = 0.f, s2 = 0.f;
  // pass 1: stage + accumulate (each thread's c is fixed -> single group)
  for (int i = 0; i < 32; ++i) {
    int s = i * 256 + tid;
    int r = s >> 3;
    float4 v = *(const float4*)(base + (size_t)r * Cn + c * 4);
    *(float4*)(xs + (size_t)s * 4) = v;
    s1 += v.x + v.y + v.z + v.w;
    s2 += v.x * v.x + v.y * v.y + v.z * v.z + v.w * v.w;
  }
  // wave reduce over lanes of the SAME group (skip xor 4 = group bit)
  s1 += __shfl_xor(s1, 1);  s2 += __shfl_xor(s2, 1);
  s1 += __shfl_xor(s1, 2);  s2 += __shfl_xor(s2, 2);
  s1 += __shfl_xor(s1, 8);  s2 += __shfl_xor(s2, 8);
  s1 += __shfl_xor(s1, 16); s2 += __shfl_xor(s2, 16);
  s1 += __shfl_xor(s1, 32); s2 += __shfl_xor(s2, 32);
  int w = tid >> 6, lane = tid & 63;
  if (lane == 0) { red[w * 2 + 0] = s1; red[16 + w * 2 + 0] = s2; }
  if (lane == 4) { red[w * 2 + 1] = s1; red[16 + w * 2 + 1] = s2; }
  __syncthreads();
  if (tid < 2) {
    float a = red[tid] + red[2 + tid] + red[4 + tid] + red[6 + tid];
    float q = red[16 + tid] + red[18 + tid] + red[20 + tid] + red[22 + tid];
    float mean = a * (1.f / 16384.f);
    float var = q * (1.f / 16384.f) - mean * mean;
    stat[tid * 2] = mean;
    stat[tid * 2 + 1] = rsqrtf(var + 1e-5f);
  }
  __syncthreads();
  // pass 2: normalize from LDS, write bf16
  float mean = stat[(c >> 2) * 2], rstd = stat[(c >> 2) * 2 + 1];
  float4 gv = *(const float4*)(gamma + gp * 32 + c * 4);
  float4 bv = *(const float4*)(beta + gp * 32 + c * 4);
  u16* gdst = gn + (size_t)b * (Ln * Cn) + gp * 32;
  for (int i = 0; i < 32; ++i) {
    int s = i * 256 + tid;
    int r = s >> 3;
    float4 v = *(const float4*)(xs + (size_t)s * 4);
    ushort4 o;
    o.x = f2bf((v.x - mean) * rstd * gv.x + bv.x);
    o.y = f2bf((v.y - mean) * rstd * gv.y + bv.y);
    o.z = f2bf((v.z - mean) * rstd * gv.z + bv.z);
    o.w = f2bf((v.w - mean) * rstd * gv.w + bv.w);
    *(ushort4*)(gdst + (size_t)r * Cn + c * 4) = o;
  }
}

// ---------------- K3: transpose+cast weights to [N][K] bf16 ----------------
__global__ __launch_bounds__(256) void k_wtrans(const float* __restrict__ wqkv,
                                                const float* __restrict__ wout,
                                                u16* __restrict__ wqkvT,
                                                u16* __restrict__ woutT) {
  int id = blockIdx.x * 256 + threadIdx.x;
  if (id < Cn * N3n) {
    int k = id & 511, n = id >> 9;
    wqkvT[id] = f2bf(wqkv[(size_t)k * N3n + n]);
  } else {
    int id2 = id - Cn * N3n;
    int k = id2 & 511, n = id2 >> 9;
    woutT[id2] = f2bf(wout[(size_t)k * Cn + n]);
  }
}

// ---------------- K4: QKV GEMM, 2-phase dbuf + LDS-transposed vT epilogue ----------------
__global__ __launch_bounds__(256) void k_qkv(const u16* __restrict__ gn,
                                             const u16* __restrict__ wT,
                                             const float* __restrict__ bias,
                                             u16* __restrict__ qb,
                                             u16* __restrict__ kb,
                                             u16* __restrict__ vT) {
  // staging: A dbuf 32 KB @0, B dbuf 32 KB @32768; v-epilogue reuses as f32 [128][130]
  __shared__ __attribute__((aligned(16))) char smem[66560];
  // XCD-chunk swizzle: each XCD gets 192 consecutive work ids
  int bid = blockIdx.x;
  int wg = (bid & 7) * 192 + (bid >> 3);
  int tn = wg % 12, tm = wg / 12;
  int m0 = tm * 128, n0 = tn * 128;
  int tid = threadIdx.x;
  int w = tid >> 6, lane = tid & 63, lr = lane & 15, lg = lane >> 4;
  int wr = w >> 1, wc = w & 1;
  const f32x4 fzero = {0.f, 0.f, 0.f, 0.f};
  f32x4 acc[4][4];
#pragma unroll
  for (int mi = 0; mi < 4; ++mi)
#pragma unroll
    for (int ni = 0; ni < 4; ++ni) acc[mi][ni] = fzero;

  // prologue: stage kt=0 into buf 0
#pragma unroll
  for (int i = 0; i < 4; ++i) {
    int s = i * 256 + tid;
    int r = s >> 3, c = s & 7;
    gl_lds16(gn + ((size_t)(m0 + r) * 512 + ((c ^ (r & 7)) << 3)),
             smem + ((s & ~63) << 4));
    gl_lds16(wT + ((size_t)(n0 + r) * 512 + ((c ^ (r & 7)) << 3)),
             smem + 32768 + ((s & ~63) << 4));
  }
  __syncthreads();

  for (int kt = 0; kt < 8; ++kt) {
    int cur = kt & 1;
    char* Asb = smem + cur * 16384;
    char* Bsb = smem + 32768 + cur * 16384;
    if (kt < 7) {
      int nb = cur ^ 1, k0n = (kt + 1) * 64;
#pragma unroll
      for (int i = 0; i < 4; ++i) {
        int s = i * 256 + tid;
        int r = s >> 3, c = s & 7;
        gl_lds16(gn + ((size_t)(m0 + r) * 512 + k0n + ((c ^ (r & 7)) << 3)),
                 smem + nb * 16384 + ((s & ~63) << 4));
        gl_lds16(wT + ((size_t)(n0 + r) * 512 + k0n + ((c ^ (r & 7)) << 3)),
                 smem + 32768 + nb * 16384 + ((s & ~63) << 4));
      }
    }
#pragma unroll
    for (int ks = 0; ks < 2; ++ks) {
      short8 af[4], bf[4];
#pragma unroll
      for (int mi = 0; mi < 4; ++mi) {
        int row = wr * 64 + mi * 16 + lr;
        int ck = ks * 4 + lg;
        af[mi] = *(const short8*)(Asb + row * 128 + ((ck ^ (lr & 7)) << 4));
      }
#pragma unroll
      for (int ni = 0; ni < 4; ++ni) {
        int row = wc * 64 + ni * 16 + lr;
        int ck = ks * 4 + lg;
        bf[ni] = *(const short8*)(Bsb + row * 128 + ((ck ^ (lr & 7)) << 4));
      }
#pragma unroll
      for (int mi = 0; mi < 4; ++mi)
#pragma unroll
        for (int ni = 0; ni < 4; ++ni)
          acc[mi][ni] = mfma16(af[mi], bf[ni], acc[mi][ni]);
    }
    __syncthreads();
  }

  if (tn >= 8) {
    // ---- v-block epilogue: transpose via LDS, coalesced dwordx4 stores ----
    float* T = (float*)smem;  // [128 n_local][130]
#pragma unroll
    for (int mi = 0; mi < 4; ++mi)
#pragma unroll
      for (int ni = 0; ni < 4; ++ni) {
        int n_l = wc * 64 + ni * 16 + lr;
        float bn = bias[n0 + n_l];
#pragma unroll
        for (int rr = 0; rr < 4; ++rr) {
          int m_l = wr * 64 + mi * 16 + lg * 4 + rr;
          T[n_l * 130 + m_l] = acc[mi][ni][rr] + bn;
        }
      }
    __syncthreads();
    int n_l = tid >> 1, half = tid & 1;
    int nv = n0 - 1024 + n_l;
    int h = nv >> 6, dd = nv & 63;
    int bb = m0 >> 10, li0 = m0 & 1023;
    u16* dst = vT + ((size_t)(bb * 8 + h) * 64 + dd) * 1024 + li0;
    const float* Tr = T + n_l * 130;
#pragma unroll
    for (int j = 0; j < 8; ++j) {       // 8 chunks x 8 elems = full 128 m per row
      int mb = half * 8 + 16 * j;       // 8 consecutive li; lane pairs form 32B runs
      uint4 o;
      o.x = (unsigned)f2bf(Tr[mb + 0]) | ((unsigned)f2bf(Tr[mb + 1]) << 16);
      o.y = (unsigned)f2bf(Tr[mb + 2]) | ((unsigned)f2bf(Tr[mb + 3]) << 16);
      o.z = (unsigned)f2bf(Tr[mb + 4]) | ((unsigned)f2bf(Tr[mb + 5]) << 16);
      o.w = (unsigned)f2bf(Tr[mb + 6]) | ((unsigned)f2bf(Tr[mb + 7]) << 16);
      *(uint4*)(dst + mb) = o;
    }
  } else {
    // ---- q/k epilogue: direct stores (32B segments) ----
#pragma unroll
    for (int mi = 0; mi < 4; ++mi) {
#pragma unroll
      for (int ni = 0; ni < 4; ++ni) {
        int n = n0 + wc * 64 + ni * 16 + lr;
        float bn = bias[n];
        int which = n >> 9, nn = n & 511;
        int h = nn >> 6, dd = nn & 63;
#pragma unroll
        for (int rr = 0; rr < 4; ++rr) {
          int m = m0 + wr * 64 + mi * 16 + lg * 4 + rr;
          float v = acc[mi][ni][rr] + bn;
          int bb = m >> 10, li = m & 1023;
          if (which == 0)
            qb[((size_t)(bb * 8 + h) * 1024 + li) * 64 + dd] = f2bf(v);
          else
            kb[((size_t)(bb * 8 + h) * 1024 + li) * 64 + dd] = f2bf(v);
        }
      }
    }
  }
}

// ---------------- K5: flash attention, 8-wave block, tri-buffered K/V, counted vmcnt ----------------
__global__ __launch_bounds__(512, 4) void k_attn(const u16* __restrict__ qb,
                                                 const u16* __restrict__ kb,
                                                 const u16* __restrict__ vT,
                                                 u16* __restrict__ ob) {
  __shared__ __attribute__((aligned(16))) u16 Ks[3 * 64 * 64];  // 24 KB tri-buf
  __shared__ __attribute__((aligned(16))) u16 Vs[3 * 64 * 64];  // 24 KB tri-buf
  __shared__ __attribute__((aligned(16))) u16 Ps[8 * 32 * 64];  // 32 KB per-wave P
  int bid = blockIdx.x;
  // XCD-bijective swizzle: all 4 q-tiles of a head keep bid%8 constant
  int xq = bid & 7, kk = bid >> 3;              // bid in [0,512)
  int bh = ((kk & 15) << 3) | xq;               // [0,128)
  int qt = kk >> 4;                             // [0,4)
  const u16* qh = qb + (size_t)bh * 65536;
  const u16* kh = kb + (size_t)bh * 65536;
  const u16* vh = vT + (size_t)bh * 65536;
  int tid = threadIdx.x, w = tid >> 6, lane = tid & 63, lr = lane & 15, lg = lane >> 4;
  int q0 = qt * 256 + w * 32;
  const f32x4 fzero = {0.f, 0.f, 0.f, 0.f};
  const float C1 = 0.18033688011112042f;   // 0.125 * log2(e)

  // Q fragments (B-operand of swapped QK^T): lane holds col q=lr, d-slice lg*8
  short8 qf[2][2];
#pragma unroll
  for (int mi = 0; mi < 2; ++mi)
#pragma unroll
    for (int ks = 0; ks < 2; ++ks)
      qf[mi][ks] = *(const short8*)(qh + (size_t)(q0 + mi * 16 + lr) * 64 +
                                    ks * 32 + lg * 8);
  f32x4 accO[2][4];
  float mst[2], lst[2], nmc[2];   // lst = PER-LANE partial row-sum (reduced in epilogue)
#pragma unroll
  for (int mi = 0; mi < 2; ++mi) {
#pragma unroll
    for (int nd = 0; nd < 4; ++nd) accO[mi][nd] = fzero;
    mst[mi] = -1e30f; lst[mi] = 0.f; nmc[mi] = 0.f;  // first iter always updates nmc
  }
  char* Pwb = (char*)(Ps + w * 2048);   // 32 rows x 128 B per wave

  int sr = tid >> 3, sc8 = tid & 7;     // staging: row, 16B-chunk (512 thr = 64x8)
  size_t koff = (size_t)sr * 64 + ((sc8 ^ (sr & 7)) << 3);
  size_t voff = (size_t)sr * 1024 + ((sc8 ^ (sr & 7)) << 3);
  int ldst = (tid & ~63) << 4;          // wave-uniform LDS dest base

  // prologue: stage tiles 0,1 into bufs 0,1; wait tile 0 only (2 newest stay in flight)
  gl_lds16(kh + koff, (char*)Ks + ldst);
  gl_lds16(vh + voff, (char*)Vs + ldst);
  gl_lds16(kh + 4096 + koff, (char*)Ks + 8192 + ldst);
  gl_lds16(vh + 64 + voff, (char*)Vs + 8192 + ldst);
  asm volatile("s_waitcnt vmcnt(2)" ::: "memory");
  __builtin_amdgcn_s_barrier();

#pragma unroll 1
  for (int jt = 0; jt < 16; ++jt) {
    int cb = jt % 3;
    char* Ksb = (char*)Ks + cb * 8192;
    char* Vsb = (char*)Vs + cb * 8192;
    // stage tile jt+2 into buf (jt+2)%3 — stays in flight across this iteration's barrier
    if (jt < 14) {
      int nb = (jt + 2) % 3;
      gl_lds16(kh + (size_t)(jt + 2) * 4096 + koff, (char*)Ks + nb * 8192 + ldst);
      gl_lds16(vh + (size_t)(jt + 2) * 64 + voff, (char*)Vs + nb * 8192 + ldst);
    }

    // K fragments (A-operand): row = k-pos, from LDS
    short8 kf[4][2];
#pragma unroll
    for (int nj = 0; nj < 4; ++nj)
#pragma unroll
      for (int ks = 0; ks < 2; ++ks) {
        int row = nj * 16 + lr;
        kf[nj][ks] = *(const short8*)(Ksb + row * 128 + (((ks * 4 + lg) ^ (row & 7)) << 4));
      }

    // S^T = K Q^T: sc[mi][nj] has col=q(lr), row=k(nj*16+lg*4+rr)
    f32x4 sc[2][4];
#pragma unroll
    for (int mi = 0; mi < 2; ++mi)
#pragma unroll
      for (int nj = 0; nj < 4; ++nj) sc[mi][nj] = fzero;
#pragma unroll
    for (int ks = 0; ks < 2; ++ks)
#pragma unroll
      for (int mi = 0; mi < 2; ++mi)
#pragma unroll
        for (int nj = 0; nj < 4; ++nj)
          sc[mi][nj] = mfma16(kf[nj][ks], qf[mi][ks], sc[mi][nj]);

    // online softmax, defer-max THR=8, exp2-direct, truncation pack, per-lane lst
#pragma unroll
    for (int mi = 0; mi < 2; ++mi) {
      float t0 = fmaxf(fmaxf(sc[mi][0][0], sc[mi][0][1]), fmaxf(sc[mi][0][2], sc[mi][0][3]));
      float t1 = fmaxf(fmaxf(sc[mi][1][0], sc[mi][1][1]), fmaxf(sc[mi][1][2], sc[mi][1][3]));
      float t2 = fmaxf(fmaxf(sc[mi][2][0], sc[mi][2][1]), fmaxf(sc[mi][2][2], sc[mi][2][3]));
      float t3 = fmaxf(fmaxf(sc[mi][3][0], sc[mi][3][1]), fmaxf(sc[mi][3][2], sc[mi][3][3]));
      float mloc = fmaxf(fmaxf(t0, t1), fmaxf(t2, t3));
      mloc = fmaxf(mloc, __shfl_xor(mloc, 16));
      mloc = fmaxf(mloc, __shfl_xor(mloc, 32));
      if (__any(mloc - mst[mi] > 8.f)) {      // wave-uniform rescale path (exact math)
        float mn = fmaxf(mst[mi], mloc);
        float al = __builtin_amdgcn_exp2f((mst[mi] - mn) * C1);
        mst[mi] = mn;
        nmc[mi] = -mn * C1;
        lst[mi] *= al;                        // per-lane partial, al consistent per lr
#pragma unroll
        for (int rr = 0; rr < 4; ++rr) {
          float ab = __shfl(al, (lane & 48) | ((lane >> 4) & 3) * 4 + rr);
#pragma unroll
          for (int nd = 0; nd < 4; ++nd) accO[mi][nd][rr] *= ab;
        }
      }
      float nm = nmc[mi];
      float rs = 0.f;
#pragma unroll
      for (int nj = 0; nj < 4; ++nj) {
        float p0 = __builtin_amdgcn_exp2f(__builtin_fmaf(sc[mi][nj][0], C1, nm));
        float p1 = __builtin_amdgcn_exp2f(__builtin_fmaf(sc[mi][nj][1], C1, nm));
        float p2 = __builtin_amdgcn_exp2f(__builtin_fmaf(sc[mi][nj][2], C1, nm));
        float p3 = __builtin_amdgcn_exp2f(__builtin_fmaf(sc[mi][nj][3], C1, nm));
        rs += (p0 + p1) + (p2 + p3);
        // truncation pack: bf16 = high 16 bits (P>0; bias ~2^-9 cancels in num/den)
        unsigned u0 = __float_as_uint(p0), u1 = __float_as_uint(p1);
        unsigned u2 = __float_as_uint(p2), u3 = __float_as_uint(p3);
        uint2 pv;
        pv.x = (u0 >> 16) | (u1 & 0xFFFF0000u);
        pv.y = (u2 >> 16) | (u3 & 0xFFFF0000u);
        int row = mi * 16 + lr;
        int byte = row * 128 + (nj * 16 + lg * 4) * 2;
        byte ^= (row & 7) << 4;
        *(uint2*)(Pwb + byte) = pv;
      }
      lst[mi] += rs;   // NO cross-lane reduce here — deferred to epilogue
    }

    // V fragments (B-operand of PV) from LDS
    short8 bv[4][2];
#pragma unroll
    for (int nd = 0; nd < 4; ++nd)
#pragma unroll
      for (int ks = 0; ks < 2; ++ks) {
        int row = nd * 16 + lr;
        bv[nd][ks] = *(const short8*)(Vsb + row * 128 + (((ks * 4 + lg) ^ (row & 7)) << 4));
      }

    // O += P @ V : A-fragment of P from LDS (XOR-swizzled b128)
    short8 ap[2][2];
#pragma unroll
    for (int mi = 0; mi < 2; ++mi)
#pragma unroll
      for (int ks = 0; ks < 2; ++ks) {
        int row = mi * 16 + lr;
        int byte = row * 128 + (ks * 32 + lg * 8) * 2;
        byte ^= (row & 7) << 4;
        ap[mi][ks] = *(const short8*)(Pwb + byte);
      }
#pragma unroll
    for (int ks = 0; ks < 2; ++ks)
#pragma unroll
      for (int mi = 0; mi < 2; ++mi)
#pragma unroll
        for (int nd = 0; nd < 4; ++nd)
          accO[mi][nd] = mfma16(ap[mi][ks], bv[nd][ks], accO[mi][nd]);

    // counted-vmcnt barrier: only jt+1's loads must be complete; jt+2's 2 loads stay in flight
    if (jt < 14)
      asm volatile("s_waitcnt vmcnt(2)" ::: "memory");
    else
      asm volatile("s_waitcnt vmcnt(0)" ::: "memory");
    __builtin_amdgcn_s_barrier();
  }

  // epilogue: reduce lst across the 4 lane-groups, O /= l, write bf16
  int b = bh >> 3, h = bh & 7;
#pragma unroll
  for (int mi = 0; mi < 2; ++mi) {
    float lt = lst[mi];
    lt += __shfl_xor(lt, 16);
    lt += __shfl_xor(lt, 32);
    float il = 1.f / lt;
#pragma unroll
    for (int rr = 0; rr < 4; ++rr) {
      float ib = __shfl(il, (lane & 48) | ((lane >> 4) & 3) * 4 + rr);
      int row = q0 + mi * 16 + lg * 4 + rr;
#pragma unroll
      for (int nd = 0; nd < 4; ++nd) {
        int col = h * 64 + nd * 16 + lr;
        ob[(size_t)(b * 1024 + row) * 512 + col] = f2bf(accO[mi][nd][rr] * ib);
      }
    }
  }
}

// ---------------- K6: out-proj GEMM + bias + residual, 2-phase dbuf (fp32 out) ----------------
__global__ __launch_bounds__(256) void k_out(const u16* __restrict__ ob,
                                             const u16* __restrict__ wT,
                                             const float* __restrict__ bias,
                                             const float* __restrict__ x,
                                             float* __restrict__ out) {
  __shared__ __attribute__((aligned(16))) u16 As[2 * 128 * 64];
  __shared__ __attribute__((aligned(16))) u16 Bs[2 * 128 * 64];
  // XCD-chunk swizzle: each XCD gets 64 consecutive work ids = 16 m-rows x 4 n
  int bid = blockIdx.x;
  int wg = (bid & 7) * 64 + (bid >> 3);
  int tn = wg & 3, tm = wg >> 2;
  int m0 = tm * 128, n0 = tn * 128;
  int tid = threadIdx.x;
  int w = tid >> 6, lane = tid & 63, lr = lane & 15, lg = lane >> 4;
  int wr = w >> 1, wc = w & 1;
  const f32x4 fzero = {0.f, 0.f, 0.f, 0.f};
  f32x4 acc[4][4];
#pragma unroll
  for (int mi = 0; mi < 4; ++mi)
#pragma unroll
    for (int ni = 0; ni < 4; ++ni) acc[mi][ni] = fzero;

  // prologue: stage kt=0 into buf 0
#pragma unroll
  for (int i = 0; i < 4; ++i) {
    int s = i * 256 + tid;
    int r = s >> 3, c = s & 7;
    gl_lds16(ob + ((size_t)(m0 + r) * 512 + ((c ^ (r & 7)) << 3)),
             (char*)As + ((s & ~63) << 4));
    gl_lds16(wT + ((size_t)(n0 + r) * 512 + ((c ^ (r & 7)) << 3)),
             (char*)Bs + ((s & ~63) << 4));
  }
  __syncthreads();

  for (int kt = 0; kt < 8; ++kt) {
    int cur = kt & 1;
    char* Asb = (char*)As + cur * 16384;
    char* Bsb = (char*)Bs + cur * 16384;
    if (kt < 7) {
      int nb = cur ^ 1, k0n = (kt + 1) * 64;
#pragma unroll
      for (int i = 0; i < 4; ++i) {
        int s = i * 256 + tid;
        int r = s >> 3, c = s & 7;
        gl_lds16(ob + ((size_t)(m0 + r) * 512 + k0n + ((c ^ (r & 7)) << 3)),
                 (char*)As + nb * 16384 + ((s & ~63) << 4));
        gl_lds16(wT + ((size_t)(n0 + r) * 512 + k0n + ((c ^ (r & 7)) << 3)),
                 (char*)Bs + nb * 16384 + ((s & ~63) << 4));
      }
    }
#pragma unroll
    for (int ks = 0; ks < 2; ++ks) {
      short8 af[4], bf[4];
#pragma unroll
      for (int mi = 0; mi < 4; ++mi) {
        int row = wr * 64 + mi * 16 + lr;
        int ck = ks * 4 + lg;
        af[mi] = *(const short8*)(Asb + row * 128 + ((ck ^ (lr & 7)) << 4));
      }
#pragma unroll
      for (int ni = 0; ni < 4; ++ni) {
        int row = wc * 64 + ni * 16 + lr;
        int ck = ks * 4 + lg;
        bf[ni] = *(const short8*)(Bsb + row * 128 + ((ck ^ (lr & 7)) << 4));
      }
#pragma unroll
      for (int mi = 0; mi < 4; ++mi)
#pragma unroll
        for (int ni = 0; ni < 4; ++ni)
          acc[mi][ni] = mfma16(af[mi], bf[ni], acc[mi][ni]);
    }
    __syncthreads();
  }
#pragma unroll
  for (int mi = 0; mi < 4; ++mi) {
#pragma unroll
    for (int ni = 0; ni < 4; ++ni) {
      int n = n0 + wc * 64 + ni * 16 + lr;
      float bn = bias[n];
#pragma unroll
      for (int rr = 0; rr < 4; ++rr) {
        int m = m0 + wr * 64 + mi * 16 + lg * 4 + rr;
        size_t off = (size_t)m * 512 + n;
        out[off] = x[off] + acc[mi][ni][rr] + bn;
      }
    }
  }
}

extern "C" void kernel_launch(void* const* d_in, const int* in_sizes, int n_in,
                              void* d_out, int out_size, void* d_ws, size_t ws_size,
                              hipStream_t stream) {
  const float* x = (const float*)d_in[0];
  // d_in[1] = timesteps (unused by the reference computation)
  const float* gamma = (const float*)d_in[2];
  const float* beta = (const float*)d_in[3];
  const float* wqkv = (const float*)d_in[4];
  const float* bqkv = (const float*)d_in[5];
  const float* wout = (const float*)d_in[6];
  const float* bout = (const float*)d_in[7];
  float* out = (float*)d_out;

  char* ws = (char*)d_ws;
  u16* gn = (u16*)(ws + 4096);                                 // 16 MB  [M][512]
  u16* wqkvT = (u16*)(ws + 4096 + 16777216);                   // 1.5 MB [1536][512]
  u16* woutT = (u16*)(ws + 4096 + 16777216 + 1572864);         // 0.5 MB [512][512]
  u16* qb = (u16*)(ws + 4096 + 16777216 + 1572864 + 524288);   // 16 MB  [BH][L][64]
  u16* kb = qb + 8388608;                                      // 16 MB  [BH][L][64]
  u16* vT = kb + 8388608;                                      // 16 MB  [BH][64][L]
  u16* ob = vT + 8388608;                                      // 16 MB  [M][512]

  k_gn<<<256, 256, 0, stream>>>(x, gamma, beta, gn);
  k_wtrans<<<4096, 256, 0, stream>>>(wqkv, wout, wqkvT, woutT);
  k_qkv<<<1536, 256, 0, stream>>>(gn, wqkvT, bqkv, qb, kb, vT);
  k_attn<<<512, 512, 0, stream>>>(qb, kb, vT, ob);
  k_out<<<512, 256, 0, stream>>>(ob, woutT, bout, x, out);
}

// Round 12
// 130.141 us; speedup vs baseline: 2.1586x; 1.0742x over previous
//
#include <hip/hip_runtime.h>

// Problem constants: B=16, H=W=32 -> L=1024, C=512, G=32, nh=8, d=64
#define Bn 16
#define Ln 1024
#define Cn 512
#define Mn (Bn*Ln)     // 16384
#define N3n 1536

typedef unsigned short u16;
typedef __attribute__((ext_vector_type(8))) short short8;
typedef __attribute__((ext_vector_type(4))) float f32x4;
typedef __attribute__((ext_vector_type(16))) float f32x16;

typedef const __attribute__((address_space(1))) void* gas_p;
typedef __attribute__((address_space(3))) void* las_p;

__device__ inline void gl_lds16(const void* g, void* l) {
  __builtin_amdgcn_global_load_lds((gas_p)g, (las_p)l, 16, 0, 0);
}

__device__ inline u16 f2bf(float f) {
  union { float f; unsigned u; } v; v.f = f;
  unsigned r = v.u + 0x7FFFu + ((v.u >> 16) & 1u);
  return (u16)(r >> 16);
}

// truncation pack: {lo=bf16(a), hi=bf16(b)} by taking high halves (safe, P>0)
__device__ inline unsigned pk2(float a, float b) {
  return (__float_as_uint(a) >> 16) | (__float_as_uint(b) & 0xFFFF0000u);
}

__device__ inline f32x4 mfma16(short8 a, short8 b, f32x4 c) {
  return __builtin_amdgcn_mfma_f32_16x16x32_bf16(a, b, c, 0, 0, 0);
}
__device__ inline f32x16 mfma32(short8 a, short8 b, f32x16 c) {
  return __builtin_amdgcn_mfma_f32_32x32x16_bf16(a, b, c, 0, 0, 0);
}

// ---------------- K1: fused GroupNorm (stats + apply) via LDS staging ----------------
__global__ __launch_bounds__(256) void k_gn(const float* __restrict__ x,
                                            const float* __restrict__ gamma,
                                            const float* __restrict__ beta,
                                            u16* __restrict__ gn) {
  __shared__ __attribute__((aligned(16))) float xs[1024 * 32];  // 128 KB
  __shared__ float red[32];
  __shared__ float stat[4];
  int bid = blockIdx.x;            // b*16 + gp
  int b = bid >> 4, gp = bid & 15;
  const float* base = x + (size_t)b * (Ln * Cn) + gp * 32;
  int tid = threadIdx.x;
  int c = tid & 7;                 // 16B-quad within 32-ch span; group = c>>2
  float s1 = 0.f, s2 = 0.f;
  for (int i = 0; i < 32; ++i) {
    int s = i * 256 + tid;
    int r = s >> 3;
    float4 v = *(const float4*)(base + (size_t)r * Cn + c * 4);
    *(float4*)(xs + (size_t)s * 4) = v;
    s1 += v.x + v.y + v.z + v.w;
    s2 += v.x * v.x + v.y * v.y + v.z * v.z + v.w * v.w;
  }
  s1 += __shfl_xor(s1, 1);  s2 += __shfl_xor(s2, 1);
  s1 += __shfl_xor(s1, 2);  s2 += __shfl_xor(s2, 2);
  s1 += __shfl_xor(s1, 8);  s2 += __shfl_xor(s2, 8);
  s1 += __shfl_xor(s1, 16); s2 += __shfl_xor(s2, 16);
  s1 += __shfl_xor(s1, 32); s2 += __shfl_xor(s2, 32);
  int w = tid >> 6, lane = tid & 63;
  if (lane == 0) { red[w * 2 + 0] = s1; red[16 + w * 2 + 0] = s2; }
  if (lane == 4) { red[w * 2 + 1] = s1; red[16 + w * 2 + 1] = s2; }
  __syncthreads();
  if (tid < 2) {
    float a = red[tid] + red[2 + tid] + red[4 + tid] + red[6 + tid];
    float q = red[16 + tid] + red[18 + tid] + red[20 + tid] + red[22 + tid];
    float mean = a * (1.f / 16384.f);
    float var = q * (1.f / 16384.f) - mean * mean;
    stat[tid * 2] = mean;
    stat[tid * 2 + 1] = rsqrtf(var + 1e-5f);
  }
  __syncthreads();
  float mean = stat[(c >> 2) * 2], rstd = stat[(c >> 2) * 2 + 1];
  float4 gv = *(const float4*)(gamma + gp * 32 + c * 4);
  float4 bv = *(const float4*)(beta + gp * 32 + c * 4);
  u16* gdst = gn + (size_t)b * (Ln * Cn) + gp * 32;
  for (int i = 0; i < 32; ++i) {
    int s = i * 256 + tid;
    int r = s >> 3;
    float4 v = *(const float4*)(xs + (size_t)s * 4);
    ushort4 o;
    o.x = f2bf((v.x - mean) * rstd * gv.x + bv.x);
    o.y = f2bf((v.y - mean) * rstd * gv.y + bv.y);
    o.z = f2bf((v.z - mean) * rstd * gv.z + bv.z);
    o.w = f2bf((v.w - mean) * rstd * gv.w + bv.w);
    *(ushort4*)(gdst + (size_t)r * Cn + c * 4) = o;
  }
}

// ---------------- K3: transpose+cast weights to [N][K] bf16 ----------------
__global__ __launch_bounds__(256) void k_wtrans(const float* __restrict__ wqkv,
                                                const float* __restrict__ wout,
                                                u16* __restrict__ wqkvT,
                                                u16* __restrict__ woutT) {
  int id = blockIdx.x * 256 + threadIdx.x;
  if (id < Cn * N3n) {
    int k = id & 511, n = id >> 9;
    wqkvT[id] = f2bf(wqkv[(size_t)k * N3n + n]);
  } else {
    int id2 = id - Cn * N3n;
    int k = id2 & 511, n = id2 >> 9;
    woutT[id2] = f2bf(wout[(size_t)k * Cn + n]);
  }
}

// ---------------- K4: QKV GEMM, 2-phase dbuf + LDS-transposed vT epilogue ----------------
__global__ __launch_bounds__(256) void k_qkv(const u16* __restrict__ gn,
                                             const u16* __restrict__ wT,
                                             const float* __restrict__ bias,
                                             u16* __restrict__ qb,
                                             u16* __restrict__ kb,
                                             u16* __restrict__ vT) {
  __shared__ __attribute__((aligned(16))) char smem[66560];
  int bid = blockIdx.x;
  int wg = (bid & 7) * 192 + (bid >> 3);
  int tn = wg % 12, tm = wg / 12;
  int m0 = tm * 128, n0 = tn * 128;
  int tid = threadIdx.x;
  int w = tid >> 6, lane = tid & 63, lr = lane & 15, lg = lane >> 4;
  int wr = w >> 1, wc = w & 1;
  const f32x4 fzero = {0.f, 0.f, 0.f, 0.f};
  f32x4 acc[4][4];
#pragma unroll
  for (int mi = 0; mi < 4; ++mi)
#pragma unroll
    for (int ni = 0; ni < 4; ++ni) acc[mi][ni] = fzero;

#pragma unroll
  for (int i = 0; i < 4; ++i) {
    int s = i * 256 + tid;
    int r = s >> 3, c = s & 7;
    gl_lds16(gn + ((size_t)(m0 + r) * 512 + ((c ^ (r & 7)) << 3)),
             smem + ((s & ~63) << 4));
    gl_lds16(wT + ((size_t)(n0 + r) * 512 + ((c ^ (r & 7)) << 3)),
             smem + 32768 + ((s & ~63) << 4));
  }
  __syncthreads();

  for (int kt = 0; kt < 8; ++kt) {
    int cur = kt & 1;
    char* Asb = smem + cur * 16384;
    char* Bsb = smem + 32768 + cur * 16384;
    if (kt < 7) {
      int nb = cur ^ 1, k0n = (kt + 1) * 64;
#pragma unroll
      for (int i = 0; i < 4; ++i) {
        int s = i * 256 + tid;
        int r = s >> 3, c = s & 7;
        gl_lds16(gn + ((size_t)(m0 + r) * 512 + k0n + ((c ^ (r & 7)) << 3)),
                 smem + nb * 16384 + ((s & ~63) << 4));
        gl_lds16(wT + ((size_t)(n0 + r) * 512 + k0n + ((c ^ (r & 7)) << 3)),
                 smem + 32768 + nb * 16384 + ((s & ~63) << 4));
      }
    }
#pragma unroll
    for (int ks = 0; ks < 2; ++ks) {
      short8 af[4], bf[4];
#pragma unroll
      for (int mi = 0; mi < 4; ++mi) {
        int row = wr * 64 + mi * 16 + lr;
        int ck = ks * 4 + lg;
        af[mi] = *(const short8*)(Asb + row * 128 + ((ck ^ (lr & 7)) << 4));
      }
#pragma unroll
      for (int ni = 0; ni < 4; ++ni) {
        int row = wc * 64 + ni * 16 + lr;
        int ck = ks * 4 + lg;
        bf[ni] = *(const short8*)(Bsb + row * 128 + ((ck ^ (lr & 7)) << 4));
      }
#pragma unroll
      for (int mi = 0; mi < 4; ++mi)
#pragma unroll
        for (int ni = 0; ni < 4; ++ni)
          acc[mi][ni] = mfma16(af[mi], bf[ni], acc[mi][ni]);
    }
    __syncthreads();
  }

  if (tn >= 8) {
    float* T = (float*)smem;  // [128 n_local][130]
#pragma unroll
    for (int mi = 0; mi < 4; ++mi)
#pragma unroll
      for (int ni = 0; ni < 4; ++ni) {
        int n_l = wc * 64 + ni * 16 + lr;
        float bn = bias[n0 + n_l];
#pragma unroll
        for (int rr = 0; rr < 4; ++rr) {
          int m_l = wr * 64 + mi * 16 + lg * 4 + rr;
          T[n_l * 130 + m_l] = acc[mi][ni][rr] + bn;
        }
      }
    __syncthreads();
    int n_l = tid >> 1, half = tid & 1;
    int nv = n0 - 1024 + n_l;
    int h = nv >> 6, dd = nv & 63;
    int bb = m0 >> 10, li0 = m0 & 1023;
    u16* dst = vT + ((size_t)(bb * 8 + h) * 64 + dd) * 1024 + li0;
    const float* Tr = T + n_l * 130;
#pragma unroll
    for (int j = 0; j < 8; ++j) {
      int mb = half * 8 + 16 * j;
      uint4 o;
      o.x = (unsigned)f2bf(Tr[mb + 0]) | ((unsigned)f2bf(Tr[mb + 1]) << 16);
      o.y = (unsigned)f2bf(Tr[mb + 2]) | ((unsigned)f2bf(Tr[mb + 3]) << 16);
      o.z = (unsigned)f2bf(Tr[mb + 4]) | ((unsigned)f2bf(Tr[mb + 5]) << 16);
      o.w = (unsigned)f2bf(Tr[mb + 6]) | ((unsigned)f2bf(Tr[mb + 7]) << 16);
      *(uint4*)(dst + mb) = o;
    }
  } else {
#pragma unroll
    for (int mi = 0; mi < 4; ++mi) {
#pragma unroll
      for (int ni = 0; ni < 4; ++ni) {
        int n = n0 + wc * 64 + ni * 16 + lr;
        float bn = bias[n];
        int which = n >> 9, nn = n & 511;
        int h = nn >> 6, dd = nn & 63;
#pragma unroll
        for (int rr = 0; rr < 4; ++rr) {
          int m = m0 + wr * 64 + mi * 16 + lg * 4 + rr;
          float v = acc[mi][ni][rr] + bn;
          int bb = m >> 10, li = m & 1023;
          if (which == 0)
            qb[((size_t)(bb * 8 + h) * 1024 + li) * 64 + dd] = f2bf(v);
          else
            kb[((size_t)(bb * 8 + h) * 1024 + li) * 64 + dd] = f2bf(v);
        }
      }
    }
  }
}

// ---------------- K5: flash attention, 32x32 MFMA, in-register P, tri-buf K/V ----------------
__global__ __launch_bounds__(512, 4) void k_attn(const u16* __restrict__ qb,
                                                 const u16* __restrict__ kb,
                                                 const u16* __restrict__ vT,
                                                 u16* __restrict__ ob) {
  __shared__ __attribute__((aligned(16))) u16 Ks[3 * 64 * 64];  // 24 KB tri-buf
  __shared__ __attribute__((aligned(16))) u16 Vs[3 * 64 * 64];  // 24 KB tri-buf
  int bid = blockIdx.x;
  int xq = bid & 7, kk = bid >> 3;
  int bh = ((kk & 15) << 3) | xq;
  int qt = kk >> 4;
  const u16* qh = qb + (size_t)bh * 65536;
  const u16* kh = kb + (size_t)bh * 65536;
  const u16* vh = vT + (size_t)bh * 65536;
  int tid = threadIdx.x, w = tid >> 6, lane = tid & 63;
  int l31 = lane & 31, lhi = lane >> 5;
  int q0 = qt * 256 + w * 32;
  const float C1 = 0.18033688011112042f;   // 0.125 * log2(e)

  // Q fragments (B-operand of swapped QK^T): lane holds Q[q=l31][d=16ks+8lhi+e]
  short8 qf[4];
#pragma unroll
  for (int ks = 0; ks < 4; ++ks)
    qf[ks] = *(const short8*)(qh + (size_t)(q0 + l31) * 64 + ks * 16 + lhi * 8);

  f32x16 accO[2];
#pragma unroll
  for (int dt = 0; dt < 2; ++dt)
#pragma unroll
    for (int r = 0; r < 16; ++r) accO[dt][r] = 0.f;
  float mst = -1e30f, lst = 0.f, nmc = 0.f;

  int sr = tid >> 3, sc8 = tid & 7;
  size_t koff = (size_t)sr * 64 + ((sc8 ^ (sr & 7)) << 3);
  size_t voff = (size_t)sr * 1024 + ((sc8 ^ (sr & 7)) << 3);
  int ldst = (tid & ~63) << 4;

  // prologue: stage tiles 0,1; wait tile 0 only
  gl_lds16(kh + koff, (char*)Ks + ldst);
  gl_lds16(vh + voff, (char*)Vs + ldst);
  gl_lds16(kh + 4096 + koff, (char*)Ks + 8192 + ldst);
  gl_lds16(vh + 64 + voff, (char*)Vs + 8192 + ldst);
  asm volatile("s_waitcnt vmcnt(2)" ::: "memory");
  __builtin_amdgcn_s_barrier();

#pragma unroll 1
  for (int jt = 0; jt < 16; ++jt) {
    int cb = jt % 3;
    char* Ksb = (char*)Ks + cb * 8192;
    char* Vsb = (char*)Vs + cb * 8192;
    if (jt < 14) {
      int nb = (jt + 2) % 3;
      gl_lds16(kh + (size_t)(jt + 2) * 4096 + koff, (char*)Ks + nb * 8192 + ldst);
      gl_lds16(vh + (size_t)(jt + 2) * 64 + voff, (char*)Vs + nb * 8192 + ldst);
    }

    // S^T = K Q^T via 32x32x16: sc[kt2] col=q(l31), row=k=(reg&3)+8*(reg>>2)+4*lhi+32*kt2
    f32x16 sc0, sc1;
#pragma unroll
    for (int r = 0; r < 16; ++r) { sc0[r] = 0.f; sc1[r] = 0.f; }
#pragma unroll
    for (int ks = 0; ks < 4; ++ks) {
      int row = l31;
      short8 kf = *(const short8*)(Ksb + row * 128 + (((2 * ks + lhi) ^ (row & 7)) << 4));
      sc0 = mfma32(kf, qf[ks], sc0);
    }
#pragma unroll
    for (int ks = 0; ks < 4; ++ks) {
      int row = 32 + l31;
      short8 kf = *(const short8*)(Ksb + row * 128 + (((2 * ks + lhi) ^ (row & 7)) << 4));
      sc1 = mfma32(kf, qf[ks], sc1);
    }

    // softmax: lane owns q = l31; 32 scores (sc0,sc1), partner lane^32 has the rest
    float mloc = sc0[0];
#pragma unroll
    for (int r = 1; r < 16; ++r) mloc = fmaxf(mloc, sc0[r]);
#pragma unroll
    for (int r = 0; r < 16; ++r) mloc = fmaxf(mloc, sc1[r]);
    mloc = fmaxf(mloc, __shfl_xor(mloc, 32));
    if (__any(mloc - mst > 8.f)) {            // defer-max THR=8 (exact math)
      float mn = fmaxf(mst, mloc);
      float al = __builtin_amdgcn_exp2f((mst - mn) * C1);
      mst = mn; nmc = -mn * C1; lst *= al;
#pragma unroll
      for (int reg = 0; reg < 16; ++reg) {
        float ab = __shfl(al, (reg & 3) + 8 * (reg >> 2) + 4 * lhi);
        accO[0][reg] *= ab;
        accO[1][reg] *= ab;
      }
    }
    float rs = 0.f;
#pragma unroll
    for (int r = 0; r < 16; ++r) {
      float p = __builtin_amdgcn_exp2f(__builtin_fmaf(sc0[r], C1, nmc));
      sc0[r] = p; rs += p;
    }
#pragma unroll
    for (int r = 0; r < 16; ++r) {
      float p = __builtin_amdgcn_exp2f(__builtin_fmaf(sc1[r], C1, nmc));
      sc1[r] = p; rs += p;
    }
    lst += rs;   // per-lane partial (q=l31); reduced with lane^32 in epilogue

    // build PV A-fragments in-register: ap[ks2] holds P[q=l31][k=16ks2+8lhi+e]
    short8 ap[4];
#pragma unroll
    for (int kt2 = 0; kt2 < 2; ++kt2) {
#pragma unroll
      for (int hh = 0; hh < 2; ++hh) {
        unsigned A0, A1, B0, B1;
        if (kt2 == 0) {
          A0 = pk2(sc0[8 * hh + 0], sc0[8 * hh + 1]);
          A1 = pk2(sc0[8 * hh + 2], sc0[8 * hh + 3]);
          B0 = pk2(sc0[8 * hh + 4], sc0[8 * hh + 5]);
          B1 = pk2(sc0[8 * hh + 6], sc0[8 * hh + 7]);
        } else {
          A0 = pk2(sc1[8 * hh + 0], sc1[8 * hh + 1]);
          A1 = pk2(sc1[8 * hh + 2], sc1[8 * hh + 3]);
          B0 = pk2(sc1[8 * hh + 4], sc1[8 * hh + 5]);
          B1 = pk2(sc1[8 * hh + 6], sc1[8 * hh + 7]);
        }
        // exchange with lane^32: t = what partner needs from me
        unsigned t0 = lhi ? A0 : B0;
        unsigned t1 = lhi ? A1 : B1;
        unsigned xt0 = __shfl_xor(t0, 32);
        unsigned xt1 = __shfl_xor(t1, 32);
        union { uint4 u; short8 s; } cv;
        cv.u.x = lhi ? xt0 : A0;
        cv.u.y = lhi ? xt1 : A1;
        cv.u.z = lhi ? B0 : xt0;
        cv.u.w = lhi ? B1 : xt1;
        ap[2 * kt2 + hh] = cv.s;
      }
    }

    // O += P @ V : B-operand V[k=16ks2+8lhi+e][d=dt*32+l31] from Vs
#pragma unroll
    for (int ks2 = 0; ks2 < 4; ++ks2) {
#pragma unroll
      for (int dt = 0; dt < 2; ++dt) {
        int row = dt * 32 + l31;
        short8 bv = *(const short8*)(Vsb + row * 128 + (((2 * ks2 + lhi) ^ (row & 7)) << 4));
        accO[dt] = mfma32(ap[ks2], bv, accO[dt]);
      }
    }

    if (jt < 14)
      asm volatile("s_waitcnt vmcnt(2)" ::: "memory");
    else
      asm volatile("s_waitcnt vmcnt(0)" ::: "memory");
    __builtin_amdgcn_s_barrier();
  }

  // epilogue: combine lane^32 partials, O /= l, write bf16 (64B-contiguous rows)
  int b = bh >> 3, h = bh & 7;
  float lt = lst + __shfl_xor(lst, 32);
  float il = 1.f / lt;
#pragma unroll
  for (int reg = 0; reg < 16; ++reg) {
    int qrow = (reg & 3) + 8 * (reg >> 2) + 4 * lhi;
    float ib = __shfl(il, qrow);
    int row = q0 + qrow;
#pragma unroll
    for (int dt = 0; dt < 2; ++dt) {
      int col = h * 64 + dt * 32 + l31;
      ob[(size_t)(b * 1024 + row) * 512 + col] = f2bf(accO[dt][reg] * ib);
    }
  }
}

// ---------------- K6: out-proj GEMM + bias + residual, 2-phase dbuf (fp32 out) ----------------
__global__ __launch_bounds__(256) void k_out(const u16* __restrict__ ob,
                                             const u16* __restrict__ wT,
                                             const float* __restrict__ bias,
                                             const float* __restrict__ x,
                                             float* __restrict__ out) {
  __shared__ __attribute__((aligned(16))) u16 As[2 * 128 * 64];
  __shared__ __attribute__((aligned(16))) u16 Bs[2 * 128 * 64];
  int bid = blockIdx.x;
  int wg = (bid & 7) * 64 + (bid >> 3);
  int tn = wg & 3, tm = wg >> 2;
  int m0 = tm * 128, n0 = tn * 128;
  int tid = threadIdx.x;
  int w = tid >> 6, lane = tid & 63, lr = lane & 15, lg = lane >> 4;
  int wr = w >> 1, wc = w & 1;
  const f32x4 fzero = {0.f, 0.f, 0.f, 0.f};
  f32x4 acc[4][4];
#pragma unroll
  for (int mi = 0; mi < 4; ++mi)
#pragma unroll
    for (int ni = 0; ni < 4; ++ni) acc[mi][ni] = fzero;

#pragma unroll
  for (int i = 0; i < 4; ++i) {
    int s = i * 256 + tid;
    int r = s >> 3, c = s & 7;
    gl_lds16(ob + ((size_t)(m0 + r) * 512 + ((c ^ (r & 7)) << 3)),
             (char*)As + ((s & ~63) << 4));
    gl_lds16(wT + ((size_t)(n0 + r) * 512 + ((c ^ (r & 7)) << 3)),
             (char*)Bs + ((s & ~63) << 4));
  }
  __syncthreads();

  for (int kt = 0; kt < 8; ++kt) {
    int cur = kt & 1;
    char* Asb = (char*)As + cur * 16384;
    char* Bsb = (char*)Bs + cur * 16384;
    if (kt < 7) {
      int nb = cur ^ 1, k0n = (kt + 1) * 64;
#pragma unroll
      for (int i = 0; i < 4; ++i) {
        int s = i * 256 + tid;
        int r = s >> 3, c = s & 7;
        gl_lds16(ob + ((size_t)(m0 + r) * 512 + k0n + ((c ^ (r & 7)) << 3)),
                 (char*)As + nb * 16384 + ((s & ~63) << 4));
        gl_lds16(wT + ((size_t)(n0 + r) * 512 + k0n + ((c ^ (r & 7)) << 3)),
                 (char*)Bs + nb * 16384 + ((s & ~63) << 4));
      }
    }
#pragma unroll
    for (int ks = 0; ks < 2; ++ks) {
      short8 af[4], bf[4];
#pragma unroll
      for (int mi = 0; mi < 4; ++mi) {
        int row = wr * 64 + mi * 16 + lr;
        int ck = ks * 4 + lg;
        af[mi] = *(const short8*)(Asb + row * 128 + ((ck ^ (lr & 7)) << 4));
      }
#pragma unroll
      for (int ni = 0; ni < 4; ++ni) {
        int row = wc * 64 + ni * 16 + lr;
        int ck = ks * 4 + lg;
        bf[ni] = *(const short8*)(Bsb + row * 128 + ((ck ^ (lr & 7)) << 4));
      }
#pragma unroll
      for (int mi = 0; mi < 4; ++mi)
#pragma unroll
        for (int ni = 0; ni < 4; ++ni)
          acc[mi][ni] = mfma16(af[mi], bf[ni], acc[mi][ni]);
    }
    __syncthreads();
  }
#pragma unroll
  for (int mi = 0; mi < 4; ++mi) {
#pragma unroll
    for (int ni = 0; ni < 4; ++ni) {
      int n = n0 + wc * 64 + ni * 16 + lr;
      float bn = bias[n];
#pragma unroll
      for (int rr = 0; rr < 4; ++rr) {
        int m = m0 + wr * 64 + mi * 16 + lg * 4 + rr;
        size_t off = (size_t)m * 512 + n;
        out[off] = x[off] + acc[mi][ni][rr] + bn;
      }
    }
  }
}

extern "C" void kernel_launch(void* const* d_in, const int* in_sizes, int n_in,
                              void* d_out, int out_size, void* d_ws, size_t ws_size,
                              hipStream_t stream) {
  const float* x = (const float*)d_in[0];
  // d_in[1] = timesteps (unused by the reference computation)
  const float* gamma = (const float*)d_in[2];
  const float* beta = (const float*)d_in[3];
  const float* wqkv = (const float*)d_in[4];
  const float* bqkv = (const float*)d_in[5];
  const float* wout = (const float*)d_in[6];
  const float* bout = (const float*)d_in[7];
  float* out = (float*)d_out;

  char* ws = (char*)d_ws;
  u16* gn = (u16*)(ws + 4096);                                 // 16 MB  [M][512]
  u16* wqkvT = (u16*)(ws + 4096 + 16777216);                   // 1.5 MB [1536][512]
  u16* woutT = (u16*)(ws + 4096 + 16777216 + 1572864);         // 0.5 MB [512][512]
  u16* qb = (u16*)(ws + 4096 + 16777216 + 1572864 + 524288);   // 16 MB  [BH][L][64]
  u16* kb = qb + 8388608;                                      // 16 MB  [BH][L][64]
  u16* vT = kb + 8388608;                                      // 16 MB  [BH][64][L]
  u16* ob = vT + 8388608;                                      // 16 MB  [M][512]

  k_gn<<<256, 256, 0, stream>>>(x, gamma, beta, gn);
  k_wtrans<<<4096, 256, 0, stream>>>(wqkv, wout, wqkvT, woutT);
  k_qkv<<<1536, 256, 0, stream>>>(gn, wqkvT, bqkv, qb, kb, vT);
  k_attn<<<512, 512, 0, stream>>>(qb, kb, vT, ob);
  k_out<<<512, 256, 0, stream>>>(ob, woutT, bout, x, out);
}